// Round 8
// baseline (398.227 us; speedup 1.0000x reference)
//
#include <hip/hip_runtime.h>
#include <hip/hip_bf16.h>

typedef __attribute__((ext_vector_type(8))) short short8;
typedef __attribute__((ext_vector_type(4))) float f32x4;
typedef __attribute__((ext_vector_type(16))) float f32x16;
typedef __attribute__((ext_vector_type(4))) int i32x4;
typedef unsigned short u16;

#define S_LEN 2048
#define D_DIM 2048
#define NHEAD 16
#define HDIM 128
#define M_ROWS 4096

#define MFMA(a,b,c) __builtin_amdgcn_mfma_f32_16x16x32_bf16(a,b,c,0,0,0)
#define MFMA32(a,b,c) __builtin_amdgcn_mfma_f32_32x32x16_bf16(a,b,c,0,0,0)

__device__ __forceinline__ u16 f2bf(float f) {
  union { float f; unsigned u; } v; v.f = f;
  unsigned r = v.u + 0x7fffu + ((v.u >> 16) & 1u);
  return (u16)(r >> 16);
}

__device__ __forceinline__ void async16(void* lds, const void* g) {
  __builtin_amdgcn_global_load_lds(
      (const __attribute__((address_space(1))) unsigned*)g,
      (__attribute__((address_space(3))) unsigned*)lds, 16, 0, 0);
}

__device__ __forceinline__ unsigned cvtpk(float lo, float hi) {
  unsigned r;
  asm("v_cvt_pk_bf16_f32 %0, %1, %2" : "=v"(r) : "v"(lo), "v"(hi));
  return r;
}
__device__ __forceinline__ void plswap(unsigned& x, unsigned& y) {
  asm("v_permlane32_swap_b32 %0, %1" : "+v"(x), "+v"(y));
}

// ---------------- x -> bf16 ----------------
__global__ void k_cvt_x(const float* __restrict__ x, u16* __restrict__ xb) {
  int i = blockIdx.x * 256 + threadIdx.x;
  float4 v = reinterpret_cast<const float4*>(x)[i];
  ushort4 o;
  o.x = f2bf(v.x); o.y = f2bf(v.y); o.z = f2bf(v.z); o.w = f2bf(v.w);
  reinterpret_cast<ushort4*>(xb)[i] = o;
}

// -------- W[k][n] f32 -> Wt[n][k] bf16 (transpose+convert) --------
__global__ void k_cvt_wt(const float* __restrict__ W, u16* __restrict__ Wt) {
  __shared__ u16 tile[32][33];
  int n0 = blockIdx.x * 32, k0 = blockIdx.y * 32;
  int tx = threadIdx.x & 31, ty = threadIdx.x >> 5;
#pragma unroll
  for (int i = 0; i < 4; i++)
    tile[ty + i * 8][tx] = f2bf(W[(size_t)(k0 + ty + i * 8) * D_DIM + n0 + tx]);
  __syncthreads();
#pragma unroll
  for (int i = 0; i < 4; i++)
    Wt[(size_t)(n0 + ty + i * 8) * D_DIM + k0 + tx] = tile[tx][ty + i * 8];
}

// -------- V[b,h,s,d] -> Vt[b,h,d,s] (bf16 transpose) --------
__global__ void k_vtrans(const u16* __restrict__ V, u16* __restrict__ Vt) {
  __shared__ u16 tile[32][33];
  int s0 = blockIdx.x * 32, d0 = blockIdx.y * 32, bh = blockIdx.z;
  const u16* Vp = V + (size_t)bh * S_LEN * HDIM;
  u16* Vtp = Vt + (size_t)bh * HDIM * S_LEN;
  int tx = threadIdx.x & 31, ty = threadIdx.x >> 5;
#pragma unroll
  for (int i = 0; i < 4; i++)
    tile[ty + i * 8][tx] = Vp[(size_t)(s0 + ty + i * 8) * HDIM + d0 + tx];
  __syncthreads();
#pragma unroll
  for (int i = 0; i < 4; i++)
    Vtp[(size_t)(d0 + ty + i * 8) * S_LEN + s0 + tx] = tile[tx][ty + i * 8];
}

// ======== 2-phase K-split counted GEMM: C = A[M][K] * Bt[N][K]^T ========
// Tile 256 x BN (BN = NFRAG*64), BK=64 split into 2 K-subs of 32.
// Unit U(t,s) = {A-sub, B-sub} staged cooperatively; per-wave LPU loads/unit,
// identical issue order across waves -> vmcnt(LPU)+barrier guarantees all
// units except the newest are fully LDS-resident for ALL waves (race-free).
// Phase s of tile t: vmcnt(LPU); barrier; stage U(t+1,s) -> nbuf; ds_read
// sub s; 8*NFRAG MFMA (K=32). vmcnt(0) only at the last phase.
// LDS rows are 64B (4 x 16B slots); swizzle slot ^= (row>>1)&3 applied via
// pre-swizzled global source + same XOR on ds_read (involution, rule 21).
// QKV: NFRAG=6 -> grid 16x16 = 256 blocks, zero tail, LDS 160KiB exactly.
// O-proj: NFRAG=4 -> grid 8x16 = 128 blocks, one full round.
template <int NFRAG, int MODE>
__global__ __launch_bounds__(512, 2) void k_gemm2p(const u16* __restrict__ A,
                                                   const u16* __restrict__ Bt,
                                                   void* __restrict__ outp,
                                                   const float* __restrict__ fac) {
  constexpr int BN = NFRAG * 64;
  constexpr int ASUB = 16384;        // 256 rows * 64B
  constexpr int BSUB = BN * 64;
  constexpr int BBASE = 4 * ASUB;
  constexpr int LPU = 2 + NFRAG / 2; // loads per unit per wave
  __shared__ __align__(16) char lds[4 * ASUB + 4 * BSUB];
  const int m0 = blockIdx.y * 256, n0 = blockIdx.x * BN;
  const int t = threadIdx.x;
  const int w = t >> 6, l = t & 63;
  const int wr = (w >> 2) * 128, wc = (w & 3) * (BN / 4);
  const int lr = l & 15, lq = l >> 4;
  const char* Ab = (const char*)A;
  const char* Bb = (const char*)Bt;

  f32x4 acc[8][NFRAG] = {};

  auto stage_unit = [&](int tt, int s, int buf) {
#pragma unroll
    for (int j = 0; j < 2; j++) {  // A-sub: 16KB = 2 x 8KB issues
      const int p = j * 8192 + w * 1024 + l * 16;
      const int row = p >> 6, slot = (p >> 4) & 3;
      async16(lds + buf * 2 * ASUB + s * ASUB + j * 8192 + w * 1024,
              Ab + (size_t)(m0 + row) * 4096 + tt * 128 + s * 64 +
                  ((slot ^ ((row >> 1) & 3)) * 16));
    }
#pragma unroll
    for (int j = 0; j < NFRAG / 2; j++) {  // B-sub
      const int p = j * 8192 + w * 1024 + l * 16;
      const int row = p >> 6, slot = (p >> 4) & 3;
      async16(lds + BBASE + buf * 2 * BSUB + s * BSUB + j * 8192 + w * 1024,
              Bb + (size_t)(n0 + row) * 4096 + tt * 128 + s * 64 +
                  ((slot ^ ((row >> 1) & 3)) * 16));
    }
  };

  auto phase = [&](int buf, int s) {
    const char* Ar = lds + buf * 2 * ASUB + s * ASUB;
    const char* Br = lds + BBASE + buf * 2 * BSUB + s * BSUB;
    short8 af[8], bf[NFRAG];
#pragma unroll
    for (int mi = 0; mi < 8; mi++) {
      const int row = wr + mi * 16 + lr;
      af[mi] = *reinterpret_cast<const short8*>(
          Ar + row * 64 + ((lq ^ ((row >> 1) & 3)) * 16));
    }
#pragma unroll
    for (int ni = 0; ni < NFRAG; ni++) {
      const int row = wc + ni * 16 + lr;
      bf[ni] = *reinterpret_cast<const short8*>(
          Br + row * 64 + ((lq ^ ((row >> 1) & 3)) * 16));
    }
    __builtin_amdgcn_s_setprio(1);
#pragma unroll
    for (int mi = 0; mi < 8; mi++)
#pragma unroll
      for (int ni = 0; ni < NFRAG; ni++)
        acc[mi][ni] = MFMA(af[mi], bf[ni], acc[mi][ni]);
    __builtin_amdgcn_s_setprio(0);
  };

  // prologue: tile 0 both subs -> buf 0
  stage_unit(0, 0, 0);
  stage_unit(0, 1, 0);

  const int NT = D_DIM / 64;  // 32
  for (int tt = 0; tt < NT; tt++) {
    const int buf = tt & 1;
    const bool pf = (tt + 1 < NT);
    // phase 0: need U(t,0); newest-LPU = U(t,1) -> vmcnt(LPU) always safe
    asm volatile("s_waitcnt vmcnt(%0)" :: "n"(LPU) : "memory");
    __builtin_amdgcn_s_barrier();
    asm volatile("" ::: "memory");
    if (pf) stage_unit(tt + 1, 0, buf ^ 1);
    phase(buf, 0);
    // phase 1: need U(t,1); newest-LPU = U(t+1,0) if staged, else drain
    if (pf) asm volatile("s_waitcnt vmcnt(%0)" :: "n"(LPU) : "memory");
    else    asm volatile("s_waitcnt vmcnt(0)" ::: "memory");
    __builtin_amdgcn_s_barrier();
    asm volatile("" ::: "memory");
    if (pf) stage_unit(tt + 1, 1, buf ^ 1);
    phase(buf, 1);
  }

  // epilogue
#pragma unroll
  for (int mi = 0; mi < 8; mi++) {
#pragma unroll
    for (int ni = 0; ni < NFRAG; ni++) {
#pragma unroll
      for (int r = 0; r < 4; r++) {
        const int row = m0 + wr + mi * 16 + lq * 4 + r;
        const int col = n0 + wc + ni * 16 + lr;
        const float v = acc[mi][ni][r];
        if (MODE == 0) {
          const int mat = col >> 11;
          const int hh = (col >> 7) & 15;
          ((u16*)outp)[(size_t)mat * 8388608 +
                       (((size_t)((row >> 11) * NHEAD + hh)) * S_LEN + (row & 2047)) * HDIM +
                       (col & 127)] = f2bf(v);
        } else {
          ((float*)outp)[(size_t)row * D_DIM + col] = v * (1.0f + 0.1f * fac[row]);
        }
      }
    }
  }
}

// -------- phase projections pq/pk = xb @ Wpq / xb @ Wpk --------
__global__ __launch_bounds__(256) void k_phase_proj(const u16* __restrict__ xb,
                                                    const float* __restrict__ Wpq,
                                                    const float* __restrict__ Wpk,
                                                    float* __restrict__ pq,
                                                    float* __restrict__ pk) {
  __shared__ u16 xs[16][136];
  __shared__ float2 ws[128][16];
  const int t = threadIdx.x;
  const int m0 = blockIdx.x * 16;
  const int h = t & 15, r = t >> 4;
  float sq = 0.f, sk = 0.f;
  for (int kc = 0; kc < D_DIM; kc += 128) {
    *reinterpret_cast<short8*>(&xs[t >> 4][(t & 15) * 8]) =
        *reinterpret_cast<const short8*>(
            &xb[(size_t)(m0 + (t >> 4)) * D_DIM + kc + (t & 15) * 8]);
#pragma unroll
    for (int j = 0; j < 8; j++) {
      const int idx = j * 256 + t;
      const int k = idx >> 4, hh = idx & 15;
      ws[k][hh] = make_float2(Wpq[(size_t)(kc + k) * NHEAD + hh],
                              Wpk[(size_t)(kc + k) * NHEAD + hh]);
    }
    __syncthreads();
#pragma unroll
    for (int k8 = 0; k8 < 16; k8++) {
      const short8 x8 = *reinterpret_cast<const short8*>(&xs[r][k8 * 8]);
#pragma unroll
      for (int j = 0; j < 8; j++) {
        union { float f; unsigned u; } c;
        c.u = ((unsigned)(u16)x8[j]) << 16;
        const float2 wv = ws[k8 * 8 + j][h];
        sq += c.f * wv.x;
        sk += c.f * wv.y;
      }
    }
    __syncthreads();
  }
  pq[(size_t)(m0 + r) * NHEAD + h] = sq;
  pk[(size_t)(m0 + r) * NHEAD + h] = sk;
}

__device__ __forceinline__ float wave_sum(float v) {
  v += __shfl_xor(v, 1);  v += __shfl_xor(v, 2);  v += __shfl_xor(v, 4);
  v += __shfl_xor(v, 8);  v += __shfl_xor(v, 16); v += __shfl_xor(v, 32);
  return v;
}

// -------- Ck/Sk = sum_s cos/sin(pk) per (b,h) --------
__global__ void k_phase_ck(const float* __restrict__ pk, float* __restrict__ Ck,
                           float* __restrict__ Sk) {
  int bh = blockIdx.x, b = bh >> 4, h = bh & 15;
  float c = 0.f, s = 0.f;
  for (int ss = threadIdx.x; ss < S_LEN; ss += 256) {
    float v = pk[((size_t)b * S_LEN + ss) * NHEAD + h];
    c += cosf(v); s += sinf(v);
  }
  c = wave_sum(c); s = wave_sum(s);
  __shared__ float rc[4], rs[4];
  int wv = threadIdx.x >> 6;
  if ((threadIdx.x & 63) == 0) { rc[wv] = c; rs[wv] = s; }
  __syncthreads();
  if (threadIdx.x == 0) {
    Ck[bh] = rc[0] + rc[1] + rc[2] + rc[3];
    Sk[bh] = rs[0] + rs[1] + rs[2] + rs[3];
  }
}

// -------- phase_mod[m] --------
__global__ void k_phase_mod(const float* __restrict__ pq, const float* __restrict__ Ck,
                            const float* __restrict__ Sk, float* __restrict__ pm) {
  int m = blockIdx.x * 256 + threadIdx.x;
  int b = m >> 11;
  float a = 0.f;
#pragma unroll
  for (int h = 0; h < NHEAD; h++) {
    float v = pq[(size_t)m * NHEAD + h];
    a += cosf(v) * Ck[b * NHEAD + h] + sinf(v) * Sk[b * NHEAD + h];
  }
  pm[m] = a * (1.0f / (S_LEN * NHEAD));
}

// -------- causal flash attention: 4 warps x 32 q-rows, double-buffered K/V --------
__global__ __launch_bounds__(256, 2) void k_attn(const u16* __restrict__ Q,
                                                 const u16* __restrict__ K,
                                                 const u16* __restrict__ Vt,
                                                 u16* __restrict__ ctx) {
  const int bh = blockIdx.x;
  const int gy = blockIdx.y;
  const int g = (gy < 8) ? (15 - gy) : (gy - 8);  // pair long/short across dispatch
  const int b = bh >> 4, h = bh & 15;
  const int t = threadIdx.x;
  const int w = t >> 6, l = t & 63;
  const int ln = l & 31, hi = l >> 5;
  const int q0w = g * 128 + w * 32;
  const int qq = q0w + ln;
  const float scale = 0.08838834764831845f;

  const u16* Qp = Q + (size_t)bh * S_LEN * HDIM;
  const char* Kg = (const char*)(K + (size_t)bh * S_LEN * HDIM);
  const char* Vg = (const char*)(Vt + (size_t)bh * HDIM * S_LEN);

  __shared__ __align__(16) char Ks[2][16384];
  __shared__ __align__(16) char Vs[2][16384];

  auto stage = [&](int t64, int buf) {
    const int k0 = t64 * 64;
#pragma unroll
    for (int i = 0; i < 4; i++) {
      const int key = i * 16 + w * 4 + (l >> 4);
      async16(Ks[buf] + i * 4096 + w * 1024,
              Kg + (size_t)(k0 + key) * 256 + (((l & 15) * 16) ^ ((key & 15) << 4)));
      const int d = i * 32 + w * 8 + (l >> 3);
      async16(Vs[buf] + i * 4096 + w * 1024,
              Vg + (size_t)d * (S_LEN * 2) + k0 * 2 + (((l & 7) * 16) ^ ((d & 7) << 4)));
    }
  };

  short8 qf[8];
#pragma unroll
  for (int c = 0; c < 8; c++)
    qf[c] = *reinterpret_cast<const short8*>(Qp + (size_t)qq * HDIM + c * 16 + hi * 8);

  f32x16 o[4];
#pragma unroll
  for (int ds = 0; ds < 4; ds++)
#pragma unroll
    for (int r = 0; r < 16; r++) o[ds][r] = 0.f;
  float mrun = -1e30f, lsum = 0.f;

  const int nt = (g + 1) * 2;
  stage(0, 0);
  for (int t64 = 0; t64 < nt; t64++) {
    const int buf = t64 & 1;
    const int k0 = t64 * 64;
    asm volatile("s_waitcnt vmcnt(0)" ::: "memory");
    __syncthreads();
    if (t64 + 1 < nt) stage(t64 + 1, buf ^ 1);
    if (k0 < q0w + 32) {
      f32x16 s[2];
#pragma unroll
      for (int ks = 0; ks < 2; ks++)
#pragma unroll
        for (int r = 0; r < 16; r++) s[ks][r] = 0.f;
      __builtin_amdgcn_s_setprio(1);
#pragma unroll
      for (int ks = 0; ks < 2; ks++) {
        const int key = ks * 32 + ln;
        const char* kb = Ks[buf] + key * 256;
        const unsigned swzk = (unsigned)((key & 15) << 4);
#pragma unroll
        for (int c = 0; c < 8; c++) {
          const short8 kf = *reinterpret_cast<const short8*>(
              kb + (((unsigned)(c * 32 + hi * 16)) ^ swzk));
          s[ks] = MFMA32(kf, qf[c], s[ks]);
        }
      }
      __builtin_amdgcn_s_setprio(0);
      float p[32];
      float mx = -1e30f;
#pragma unroll
      for (int ks = 0; ks < 2; ks++)
#pragma unroll
        for (int r = 0; r < 16; r++) {
          const int key = k0 + ks * 32 + (r & 3) + 8 * (r >> 2) + 4 * hi;
          const float v = (key <= qq) ? s[ks][r] * scale : -1e30f;
          p[ks * 16 + r] = v;
          mx = fmaxf(mx, v);
        }
      mx = fmaxf(mx, __shfl_xor(mx, 32));
      const float nm = fmaxf(mrun, mx);
      const float f = __expf(mrun - nm);
      float rs = 0.f;
#pragma unroll
      for (int i = 0; i < 32; i++) { p[i] = __expf(p[i] - nm); rs += p[i]; }
      rs += __shfl_xor(rs, 32);
      lsum = lsum * f + rs;
      mrun = nm;
#pragma unroll
      for (int ds = 0; ds < 4; ds++)
#pragma unroll
        for (int r = 0; r < 16; r++) o[ds][r] *= f;
      short8 bfr[4];
#pragma unroll
      for (int sub = 0; sub < 2; sub++) {
#pragma unroll
        for (int half = 0; half < 2; half++) {
          const int pb = sub * 16 + half * 8;
          unsigned X1 = cvtpk(p[pb + 0], p[pb + 1]);
          unsigned X2 = cvtpk(p[pb + 2], p[pb + 3]);
          unsigned Y1 = cvtpk(p[pb + 4], p[pb + 5]);
          unsigned Y2 = cvtpk(p[pb + 6], p[pb + 7]);
          plswap(X1, Y1);
          plswap(X2, Y2);
          i32x4 bw;
          bw[0] = (int)X1; bw[1] = (int)X2; bw[2] = (int)Y1; bw[3] = (int)Y2;
          bfr[sub * 2 + half] = __builtin_bit_cast(short8, bw);
        }
      }
      __builtin_amdgcn_s_setprio(1);
#pragma unroll
      for (int ds = 0; ds < 4; ds++) {
        const int d = ds * 32 + ln;
        const char* vb = Vs[buf] + d * 128;
        const unsigned swzv = (unsigned)((d & 7) << 4);
#pragma unroll
        for (int slot = 0; slot < 4; slot++) {
          const short8 vf = *reinterpret_cast<const short8*>(
              vb + (((unsigned)(slot * 32 + hi * 16)) ^ swzv));
          o[ds] = MFMA32(vf, bfr[slot], o[ds]);
        }
      }
      __builtin_amdgcn_s_setprio(0);
    }
  }

  const float rl = 1.0f / lsum;
#pragma unroll
  for (int ds = 0; ds < 4; ds++) {
#pragma unroll
    for (int rq = 0; rq < 4; rq++) {
      const int d = ds * 32 + 8 * rq + 4 * hi;
      ushort4 pk4;
      pk4.x = f2bf(o[ds][rq * 4 + 0] * rl);
      pk4.y = f2bf(o[ds][rq * 4 + 1] * rl);
      pk4.z = f2bf(o[ds][rq * 4 + 2] * rl);
      pk4.w = f2bf(o[ds][rq * 4 + 3] * rl);
      *reinterpret_cast<ushort4*>(ctx + ((size_t)(b * S_LEN + qq)) * D_DIM + h * HDIM + d) = pk4;
    }
  }
}

extern "C" void kernel_launch(void* const* d_in, const int* in_sizes, int n_in,
                              void* d_out, int out_size, void* d_ws, size_t ws_size,
                              hipStream_t stream) {
  const float* x   = (const float*)d_in[0];
  const float* Wq  = (const float*)d_in[1];
  const float* Wk  = (const float*)d_in[2];
  const float* Wv  = (const float*)d_in[3];
  const float* Wo  = (const float*)d_in[4];
  const float* Wpq = (const float*)d_in[5];
  const float* Wpk = (const float*)d_in[6];

  char* ws = (char*)d_ws;
  u16* xb   = (u16*)(ws + 0);            // 16 MB  x bf16 [4096][2048]
  u16* Wqt  = (u16*)(ws + 16777216);     // 8 MB each, transposed bf16 (Wq,Wk,Wv contiguous)
  u16* Wkt  = (u16*)(ws + 25165824);
  u16* Wvt  = (u16*)(ws + 33554432);
  u16* Wot  = (u16*)(ws + 41943040);
  u16* Qb   = (u16*)(ws + 50331648);     // [b,h,s,d] bf16 (Q,K,V contiguous)
  u16* Kb   = (u16*)(ws + 67108864);
  u16* Vb   = (u16*)(ws + 83886080);     // V, later reused as ctx
  u16* Vt   = (u16*)(ws + 100663296);    // [b,h,d,s] bf16
  float* pq = (float*)(ws + 117440512);
  float* pk = (float*)(ws + 117702656);
  float* Ck = (float*)(ws + 117964800);
  float* Sk = (float*)(ws + 117964928);
  float* pm = (float*)(ws + 117965056);

  k_cvt_x<<<dim3(M_ROWS * D_DIM / 1024), 256, 0, stream>>>(x, xb);
  k_cvt_wt<<<dim3(64, 64), 256, 0, stream>>>(Wq, Wqt);
  k_cvt_wt<<<dim3(64, 64), 256, 0, stream>>>(Wk, Wkt);
  k_cvt_wt<<<dim3(64, 64), 256, 0, stream>>>(Wv, Wvt);
  k_cvt_wt<<<dim3(64, 64), 256, 0, stream>>>(Wo, Wot);

  // fused QKV projection: Bt = [Wqt;Wkt;Wvt] = [6144][2048], 256x384 tiles
  // grid 16x16 = 256 blocks -> one full round, zero tail
  k_gemm2p<6, 0><<<dim3(16, 16), 512, 0, stream>>>(xb, Wqt, Qb, nullptr);

  k_vtrans<<<dim3(64, 4, 32), 256, 0, stream>>>(Vb, Vt);

  k_phase_proj<<<dim3(256), 256, 0, stream>>>(xb, Wpq, Wpk, pq, pk);
  k_phase_ck<<<dim3(32), 256, 0, stream>>>(pk, Ck, Sk);
  k_phase_mod<<<dim3(16), 256, 0, stream>>>(pq, Ck, Sk, pm);

  k_attn<<<dim3(32, 16), 256, 0, stream>>>(Qb, Kb, Vt, Vb /*ctx*/);

  // O-proj: 256x256 tiles -> grid 8x16 = 128 blocks, one round
  k_gemm2p<4, 1><<<dim3(8, 16), 512, 0, stream>>>(Vb /*ctx*/, Wot, (void*)d_out, pm);
}

// Round 9
// 351.095 us; speedup vs baseline: 1.1342x; 1.1342x over previous
//
#include <hip/hip_runtime.h>
#include <hip/hip_bf16.h>

typedef __attribute__((ext_vector_type(8))) short short8;
typedef __attribute__((ext_vector_type(4))) float f32x4;
typedef __attribute__((ext_vector_type(16))) float f32x16;
typedef __attribute__((ext_vector_type(4))) int i32x4;
typedef unsigned short u16;

#define S_LEN 2048
#define D_DIM 2048
#define NHEAD 16
#define HDIM 128
#define M_ROWS 4096

#define MFMA(a,b,c) __builtin_amdgcn_mfma_f32_16x16x32_bf16(a,b,c,0,0,0)
#define MFMA32(a,b,c) __builtin_amdgcn_mfma_f32_32x32x16_bf16(a,b,c,0,0,0)

__device__ __forceinline__ u16 f2bf(float f) {
  union { float f; unsigned u; } v; v.f = f;
  unsigned r = v.u + 0x7fffu + ((v.u >> 16) & 1u);
  return (u16)(r >> 16);
}

__device__ __forceinline__ void async16(void* lds, const void* g) {
  __builtin_amdgcn_global_load_lds(
      (const __attribute__((address_space(1))) unsigned*)g,
      (__attribute__((address_space(3))) unsigned*)lds, 16, 0, 0);
}

__device__ __forceinline__ unsigned cvtpk(float lo, float hi) {
  unsigned r;
  asm("v_cvt_pk_bf16_f32 %0, %1, %2" : "=v"(r) : "v"(lo), "v"(hi));
  return r;
}
__device__ __forceinline__ void plswap(unsigned& x, unsigned& y) {
  asm("v_permlane32_swap_b32 %0, %1" : "+v"(x), "+v"(y));
}

// ---------------- x -> bf16 ----------------
__global__ void k_cvt_x(const float* __restrict__ x, u16* __restrict__ xb) {
  int i = blockIdx.x * 256 + threadIdx.x;
  float4 v = reinterpret_cast<const float4*>(x)[i];
  ushort4 o;
  o.x = f2bf(v.x); o.y = f2bf(v.y); o.z = f2bf(v.z); o.w = f2bf(v.w);
  reinterpret_cast<ushort4*>(xb)[i] = o;
}

// -------- W[k][n] f32 -> Wt[n][k] bf16 (transpose+convert) --------
__global__ void k_cvt_wt(const float* __restrict__ W, u16* __restrict__ Wt) {
  __shared__ u16 tile[32][33];
  int n0 = blockIdx.x * 32, k0 = blockIdx.y * 32;
  int tx = threadIdx.x & 31, ty = threadIdx.x >> 5;
#pragma unroll
  for (int i = 0; i < 4; i++)
    tile[ty + i * 8][tx] = f2bf(W[(size_t)(k0 + ty + i * 8) * D_DIM + n0 + tx]);
  __syncthreads();
#pragma unroll
  for (int i = 0; i < 4; i++)
    Wt[(size_t)(n0 + ty + i * 8) * D_DIM + k0 + tx] = tile[tx][ty + i * 8];
}

// -------- V[b,h,s,d] -> Vt[b,h,d,s] (bf16 transpose) --------
__global__ void k_vtrans(const u16* __restrict__ V, u16* __restrict__ Vt) {
  __shared__ u16 tile[32][33];
  int s0 = blockIdx.x * 32, d0 = blockIdx.y * 32, bh = blockIdx.z;
  const u16* Vp = V + (size_t)bh * S_LEN * HDIM;
  u16* Vtp = Vt + (size_t)bh * HDIM * S_LEN;
  int tx = threadIdx.x & 31, ty = threadIdx.x >> 5;
#pragma unroll
  for (int i = 0; i < 4; i++)
    tile[ty + i * 8][tx] = Vp[(size_t)(s0 + ty + i * 8) * HDIM + d0 + tx];
  __syncthreads();
#pragma unroll
  for (int i = 0; i < 4; i++)
    Vtp[(size_t)(d0 + ty + i * 8) * S_LEN + s0 + tx] = tile[tx][ty + i * 8];
}

// ======== 2-phase K-split counted GEMM: C = A[M][K] * Bt[N][K]^T ========
// Tile (MFRAG*32) x (NFRAG*64), BK=64 split into 2 K-subs of 32.
// 8 waves as 2M x 4N; per-wave MFRAG*16 rows x NFRAG*16 cols.
// Unit U(t,s) = {A-sub, B-sub}; per-thread LPU = MFRAG/4 + NFRAG/2 loads/unit,
// identical issue order across waves -> vmcnt(LPU)+barrier guarantees all
// units except the newest are fully LDS-resident for ALL waves (race-free).
// vmcnt(0) only at the last phase. LDS rows 64B (4 x 16B slots); swizzle
// slot ^= (row>>1)&3 via pre-swizzled global source + same XOR on ds_read.
// QKV: <8,4> grid 24x16 (proven 116us). O-proj: <4,4> grid 8x32 = 256 blocks.
template <int MFRAG, int NFRAG, int MODE>
__global__ __launch_bounds__(512, 2) void k_gemm2p(const u16* __restrict__ A,
                                                   const u16* __restrict__ Bt,
                                                   void* __restrict__ outp,
                                                   const float* __restrict__ fac) {
  constexpr int BM = MFRAG * 32;
  constexpr int BN = NFRAG * 64;
  constexpr int ASUB = BM * 64;
  constexpr int BSUB = BN * 64;
  constexpr int BBASE = 4 * ASUB;
  constexpr int LPU = MFRAG / 4 + NFRAG / 2;
  __shared__ __align__(16) char lds[4 * ASUB + 4 * BSUB];
  const int m0 = blockIdx.y * BM, n0 = blockIdx.x * BN;
  const int t = threadIdx.x;
  const int w = t >> 6, l = t & 63;
  const int wr = (w >> 2) * (MFRAG * 16), wc = (w & 3) * (NFRAG * 16);
  const int lr = l & 15, lq = l >> 4;
  const char* Ab = (const char*)A;
  const char* Bb = (const char*)Bt;

  f32x4 acc[MFRAG][NFRAG] = {};

  auto stage_unit = [&](int tt, int s, int buf) {
#pragma unroll
    for (int j = 0; j < MFRAG / 4; j++) {  // A-sub: BM*64B in 8KB issues
      const int p = j * 8192 + w * 1024 + l * 16;
      const int row = p >> 6, slot = (p >> 4) & 3;
      async16(lds + buf * 2 * ASUB + s * ASUB + j * 8192 + w * 1024,
              Ab + (size_t)(m0 + row) * 4096 + tt * 128 + s * 64 +
                  ((slot ^ ((row >> 1) & 3)) * 16));
    }
#pragma unroll
    for (int j = 0; j < NFRAG / 2; j++) {  // B-sub
      const int p = j * 8192 + w * 1024 + l * 16;
      const int row = p >> 6, slot = (p >> 4) & 3;
      async16(lds + BBASE + buf * 2 * BSUB + s * BSUB + j * 8192 + w * 1024,
              Bb + (size_t)(n0 + row) * 4096 + tt * 128 + s * 64 +
                  ((slot ^ ((row >> 1) & 3)) * 16));
    }
  };

  auto phase = [&](int buf, int s) {
    const char* Ar = lds + buf * 2 * ASUB + s * ASUB;
    const char* Br = lds + BBASE + buf * 2 * BSUB + s * BSUB;
    short8 af[MFRAG], bf[NFRAG];
#pragma unroll
    for (int mi = 0; mi < MFRAG; mi++) {
      const int row = wr + mi * 16 + lr;
      af[mi] = *reinterpret_cast<const short8*>(
          Ar + row * 64 + ((lq ^ ((row >> 1) & 3)) * 16));
    }
#pragma unroll
    for (int ni = 0; ni < NFRAG; ni++) {
      const int row = wc + ni * 16 + lr;
      bf[ni] = *reinterpret_cast<const short8*>(
          Br + row * 64 + ((lq ^ ((row >> 1) & 3)) * 16));
    }
    __builtin_amdgcn_s_setprio(1);
#pragma unroll
    for (int mi = 0; mi < MFRAG; mi++)
#pragma unroll
      for (int ni = 0; ni < NFRAG; ni++)
        acc[mi][ni] = MFMA(af[mi], bf[ni], acc[mi][ni]);
    __builtin_amdgcn_s_setprio(0);
  };

  // prologue: tile 0 both subs -> buf 0
  stage_unit(0, 0, 0);
  stage_unit(0, 1, 0);

  const int NT = D_DIM / 64;  // 32
  for (int tt = 0; tt < NT; tt++) {
    const int buf = tt & 1;
    const bool pf = (tt + 1 < NT);
    asm volatile("s_waitcnt vmcnt(%0)" :: "n"(LPU) : "memory");
    __builtin_amdgcn_s_barrier();
    asm volatile("" ::: "memory");
    if (pf) stage_unit(tt + 1, 0, buf ^ 1);
    phase(buf, 0);
    if (pf) asm volatile("s_waitcnt vmcnt(%0)" :: "n"(LPU) : "memory");
    else    asm volatile("s_waitcnt vmcnt(0)" ::: "memory");
    __builtin_amdgcn_s_barrier();
    asm volatile("" ::: "memory");
    if (pf) stage_unit(tt + 1, 1, buf ^ 1);
    phase(buf, 1);
  }

  // epilogue
#pragma unroll
  for (int mi = 0; mi < MFRAG; mi++) {
#pragma unroll
    for (int ni = 0; ni < NFRAG; ni++) {
#pragma unroll
      for (int r = 0; r < 4; r++) {
        const int row = m0 + wr + mi * 16 + lq * 4 + r;
        const int col = n0 + wc + ni * 16 + lr;
        const float v = acc[mi][ni][r];
        if (MODE == 0) {
          const int mat = col >> 11;
          const int hh = (col >> 7) & 15;
          ((u16*)outp)[(size_t)mat * 8388608 +
                       (((size_t)((row >> 11) * NHEAD + hh)) * S_LEN + (row & 2047)) * HDIM +
                       (col & 127)] = f2bf(v);
        } else {
          ((float*)outp)[(size_t)row * D_DIM + col] = v * (1.0f + 0.1f * fac[row]);
        }
      }
    }
  }
}

// -------- phase projections pq/pk = xb @ Wpq / xb @ Wpk --------
__global__ __launch_bounds__(256) void k_phase_proj(const u16* __restrict__ xb,
                                                    const float* __restrict__ Wpq,
                                                    const float* __restrict__ Wpk,
                                                    float* __restrict__ pq,
                                                    float* __restrict__ pk) {
  __shared__ u16 xs[16][136];
  __shared__ float2 ws[128][16];
  const int t = threadIdx.x;
  const int m0 = blockIdx.x * 16;
  const int h = t & 15, r = t >> 4;
  float sq = 0.f, sk = 0.f;
  for (int kc = 0; kc < D_DIM; kc += 128) {
    *reinterpret_cast<short8*>(&xs[t >> 4][(t & 15) * 8]) =
        *reinterpret_cast<const short8*>(
            &xb[(size_t)(m0 + (t >> 4)) * D_DIM + kc + (t & 15) * 8]);
#pragma unroll
    for (int j = 0; j < 8; j++) {
      const int idx = j * 256 + t;
      const int k = idx >> 4, hh = idx & 15;
      ws[k][hh] = make_float2(Wpq[(size_t)(kc + k) * NHEAD + hh],
                              Wpk[(size_t)(kc + k) * NHEAD + hh]);
    }
    __syncthreads();
#pragma unroll
    for (int k8 = 0; k8 < 16; k8++) {
      const short8 x8 = *reinterpret_cast<const short8*>(&xs[r][k8 * 8]);
#pragma unroll
      for (int j = 0; j < 8; j++) {
        union { float f; unsigned u; } c;
        c.u = ((unsigned)(u16)x8[j]) << 16;
        const float2 wv = ws[k8 * 8 + j][h];
        sq += c.f * wv.x;
        sk += c.f * wv.y;
      }
    }
    __syncthreads();
  }
  pq[(size_t)(m0 + r) * NHEAD + h] = sq;
  pk[(size_t)(m0 + r) * NHEAD + h] = sk;
}

__device__ __forceinline__ float wave_sum(float v) {
  v += __shfl_xor(v, 1);  v += __shfl_xor(v, 2);  v += __shfl_xor(v, 4);
  v += __shfl_xor(v, 8);  v += __shfl_xor(v, 16); v += __shfl_xor(v, 32);
  return v;
}

// -------- Ck/Sk = sum_s cos/sin(pk) per (b,h) --------
__global__ void k_phase_ck(const float* __restrict__ pk, float* __restrict__ Ck,
                           float* __restrict__ Sk) {
  int bh = blockIdx.x, b = bh >> 4, h = bh & 15;
  float c = 0.f, s = 0.f;
  for (int ss = threadIdx.x; ss < S_LEN; ss += 256) {
    float v = pk[((size_t)b * S_LEN + ss) * NHEAD + h];
    c += cosf(v); s += sinf(v);
  }
  c = wave_sum(c); s = wave_sum(s);
  __shared__ float rc[4], rs[4];
  int wv = threadIdx.x >> 6;
  if ((threadIdx.x & 63) == 0) { rc[wv] = c; rs[wv] = s; }
  __syncthreads();
  if (threadIdx.x == 0) {
    Ck[bh] = rc[0] + rc[1] + rc[2] + rc[3];
    Sk[bh] = rs[0] + rs[1] + rs[2] + rs[3];
  }
}

// -------- phase_mod[m] --------
__global__ void k_phase_mod(const float* __restrict__ pq, const float* __restrict__ Ck,
                            const float* __restrict__ Sk, float* __restrict__ pm) {
  int m = blockIdx.x * 256 + threadIdx.x;
  int b = m >> 11;
  float a = 0.f;
#pragma unroll
  for (int h = 0; h < NHEAD; h++) {
    float v = pq[(size_t)m * NHEAD + h];
    a += cosf(v) * Ck[b * NHEAD + h] + sinf(v) * Sk[b * NHEAD + h];
  }
  pm[m] = a * (1.0f / (S_LEN * NHEAD));
}

// -------- causal flash attention: 4 warps x 32 q-rows, double-buffered K/V --------
__global__ __launch_bounds__(256, 2) void k_attn(const u16* __restrict__ Q,
                                                 const u16* __restrict__ K,
                                                 const u16* __restrict__ Vt,
                                                 u16* __restrict__ ctx) {
  const int bh = blockIdx.x;
  const int gy = blockIdx.y;
  const int g = (gy < 8) ? (15 - gy) : (gy - 8);  // pair long/short across dispatch
  const int b = bh >> 4, h = bh & 15;
  const int t = threadIdx.x;
  const int w = t >> 6, l = t & 63;
  const int ln = l & 31, hi = l >> 5;
  const int q0w = g * 128 + w * 32;
  const int qq = q0w + ln;
  const float scale = 0.08838834764831845f;

  const u16* Qp = Q + (size_t)bh * S_LEN * HDIM;
  const char* Kg = (const char*)(K + (size_t)bh * S_LEN * HDIM);
  const char* Vg = (const char*)(Vt + (size_t)bh * HDIM * S_LEN);

  __shared__ __align__(16) char Ks[2][16384];
  __shared__ __align__(16) char Vs[2][16384];

  auto stage = [&](int t64, int buf) {
    const int k0 = t64 * 64;
#pragma unroll
    for (int i = 0; i < 4; i++) {
      const int key = i * 16 + w * 4 + (l >> 4);
      async16(Ks[buf] + i * 4096 + w * 1024,
              Kg + (size_t)(k0 + key) * 256 + (((l & 15) * 16) ^ ((key & 15) << 4)));
      const int d = i * 32 + w * 8 + (l >> 3);
      async16(Vs[buf] + i * 4096 + w * 1024,
              Vg + (size_t)d * (S_LEN * 2) + k0 * 2 + (((l & 7) * 16) ^ ((d & 7) << 4)));
    }
  };

  short8 qf[8];
#pragma unroll
  for (int c = 0; c < 8; c++)
    qf[c] = *reinterpret_cast<const short8*>(Qp + (size_t)qq * HDIM + c * 16 + hi * 8);

  f32x16 o[4];
#pragma unroll
  for (int ds = 0; ds < 4; ds++)
#pragma unroll
    for (int r = 0; r < 16; r++) o[ds][r] = 0.f;
  float mrun = -1e30f, lsum = 0.f;

  const int nt = (g + 1) * 2;
  stage(0, 0);
  for (int t64 = 0; t64 < nt; t64++) {
    const int buf = t64 & 1;
    const int k0 = t64 * 64;
    asm volatile("s_waitcnt vmcnt(0)" ::: "memory");
    __syncthreads();
    if (t64 + 1 < nt) stage(t64 + 1, buf ^ 1);
    if (k0 < q0w + 32) {
      f32x16 s[2];
#pragma unroll
      for (int ks = 0; ks < 2; ks++)
#pragma unroll
        for (int r = 0; r < 16; r++) s[ks][r] = 0.f;
      __builtin_amdgcn_s_setprio(1);
#pragma unroll
      for (int ks = 0; ks < 2; ks++) {
        const int key = ks * 32 + ln;
        const char* kb = Ks[buf] + key * 256;
        const unsigned swzk = (unsigned)((key & 15) << 4);
#pragma unroll
        for (int c = 0; c < 8; c++) {
          const short8 kf = *reinterpret_cast<const short8*>(
              kb + (((unsigned)(c * 32 + hi * 16)) ^ swzk));
          s[ks] = MFMA32(kf, qf[c], s[ks]);
        }
      }
      __builtin_amdgcn_s_setprio(0);
      float p[32];
      float mx = -1e30f;
#pragma unroll
      for (int ks = 0; ks < 2; ks++)
#pragma unroll
        for (int r = 0; r < 16; r++) {
          const int key = k0 + ks * 32 + (r & 3) + 8 * (r >> 2) + 4 * hi;
          const float v = (key <= qq) ? s[ks][r] * scale : -1e30f;
          p[ks * 16 + r] = v;
          mx = fmaxf(mx, v);
        }
      mx = fmaxf(mx, __shfl_xor(mx, 32));
      const float nm = fmaxf(mrun, mx);
      const float f = __expf(mrun - nm);
      float rs = 0.f;
#pragma unroll
      for (int i = 0; i < 32; i++) { p[i] = __expf(p[i] - nm); rs += p[i]; }
      rs += __shfl_xor(rs, 32);
      lsum = lsum * f + rs;
      mrun = nm;
#pragma unroll
      for (int ds = 0; ds < 4; ds++)
#pragma unroll
        for (int r = 0; r < 16; r++) o[ds][r] *= f;
      short8 bfr[4];
#pragma unroll
      for (int sub = 0; sub < 2; sub++) {
#pragma unroll
        for (int half = 0; half < 2; half++) {
          const int pb = sub * 16 + half * 8;
          unsigned X1 = cvtpk(p[pb + 0], p[pb + 1]);
          unsigned X2 = cvtpk(p[pb + 2], p[pb + 3]);
          unsigned Y1 = cvtpk(p[pb + 4], p[pb + 5]);
          unsigned Y2 = cvtpk(p[pb + 6], p[pb + 7]);
          plswap(X1, Y1);
          plswap(X2, Y2);
          i32x4 bw;
          bw[0] = (int)X1; bw[1] = (int)X2; bw[2] = (int)Y1; bw[3] = (int)Y2;
          bfr[sub * 2 + half] = __builtin_bit_cast(short8, bw);
        }
      }
      __builtin_amdgcn_s_setprio(1);
#pragma unroll
      for (int ds = 0; ds < 4; ds++) {
        const int d = ds * 32 + ln;
        const char* vb = Vs[buf] + d * 128;
        const unsigned swzv = (unsigned)((d & 7) << 4);
#pragma unroll
        for (int slot = 0; slot < 4; slot++) {
          const short8 vf = *reinterpret_cast<const short8*>(
              vb + (((unsigned)(slot * 32 + hi * 16)) ^ swzv));
          o[ds] = MFMA32(vf, bfr[slot], o[ds]);
        }
      }
      __builtin_amdgcn_s_setprio(0);
    }
  }

  const float rl = 1.0f / lsum;
#pragma unroll
  for (int ds = 0; ds < 4; ds++) {
#pragma unroll
    for (int rq = 0; rq < 4; rq++) {
      const int d = ds * 32 + 8 * rq + 4 * hi;
      ushort4 pk4;
      pk4.x = f2bf(o[ds][rq * 4 + 0] * rl);
      pk4.y = f2bf(o[ds][rq * 4 + 1] * rl);
      pk4.z = f2bf(o[ds][rq * 4 + 2] * rl);
      pk4.w = f2bf(o[ds][rq * 4 + 3] * rl);
      *reinterpret_cast<ushort4*>(ctx + ((size_t)(b * S_LEN + qq)) * D_DIM + h * HDIM + d) = pk4;
    }
  }
}

extern "C" void kernel_launch(void* const* d_in, const int* in_sizes, int n_in,
                              void* d_out, int out_size, void* d_ws, size_t ws_size,
                              hipStream_t stream) {
  const float* x   = (const float*)d_in[0];
  const float* Wq  = (const float*)d_in[1];
  const float* Wk  = (const float*)d_in[2];
  const float* Wv  = (const float*)d_in[3];
  const float* Wo  = (const float*)d_in[4];
  const float* Wpq = (const float*)d_in[5];
  const float* Wpk = (const float*)d_in[6];

  char* ws = (char*)d_ws;
  u16* xb   = (u16*)(ws + 0);            // 16 MB  x bf16 [4096][2048]
  u16* Wqt  = (u16*)(ws + 16777216);     // 8 MB each, transposed bf16 (Wq,Wk,Wv contiguous)
  u16* Wkt  = (u16*)(ws + 25165824);
  u16* Wvt  = (u16*)(ws + 33554432);
  u16* Wot  = (u16*)(ws + 41943040);
  u16* Qb   = (u16*)(ws + 50331648);     // [b,h,s,d] bf16 (Q,K,V contiguous)
  u16* Kb   = (u16*)(ws + 67108864);
  u16* Vb   = (u16*)(ws + 83886080);     // V, later reused as ctx
  u16* Vt   = (u16*)(ws + 100663296);    // [b,h,d,s] bf16
  float* pq = (float*)(ws + 117440512);
  float* pk = (float*)(ws + 117702656);
  float* Ck = (float*)(ws + 117964800);
  float* Sk = (float*)(ws + 117964928);
  float* pm = (float*)(ws + 117965056);

  k_cvt_x<<<dim3(M_ROWS * D_DIM / 1024), 256, 0, stream>>>(x, xb);
  k_cvt_wt<<<dim3(64, 64), 256, 0, stream>>>(Wq, Wqt);
  k_cvt_wt<<<dim3(64, 64), 256, 0, stream>>>(Wk, Wkt);
  k_cvt_wt<<<dim3(64, 64), 256, 0, stream>>>(Wv, Wvt);
  k_cvt_wt<<<dim3(64, 64), 256, 0, stream>>>(Wo, Wot);

  // fused QKV projection: Bt = [Wqt;Wkt;Wvt] = [6144][2048], 256x256 tiles
  // (proven R5 config: 116us, MfmaUtil 37%)
  k_gemm2p<8, 4, 0><<<dim3(24, 16), 512, 0, stream>>>(xb, Wqt, Qb, nullptr);

  k_vtrans<<<dim3(64, 4, 32), 256, 0, stream>>>(Vb, Vt);

  k_phase_proj<<<dim3(256), 256, 0, stream>>>(xb, Wpq, Wpk, pq, pk);
  k_phase_ck<<<dim3(32), 256, 0, stream>>>(pk, Ck, Sk);
  k_phase_mod<<<dim3(16), 256, 0, stream>>>(pq, Ck, Sk, pm);

  k_attn<<<dim3(32, 16), 256, 0, stream>>>(Qb, Kb, Vt, Vb /*ctx*/);

  // O-proj: 128x256 tiles -> grid 8x32 = 256 blocks, one full round
  k_gemm2p<4, 4, 1><<<dim3(8, 32), 512, 0, stream>>>(Vb /*ctx*/, Wot, (void*)d_out, pm);
}

// Round 10
// 335.793 us; speedup vs baseline: 1.1859x; 1.0456x over previous
//
#include <hip/hip_runtime.h>
#include <hip/hip_bf16.h>

typedef __attribute__((ext_vector_type(8))) short short8;
typedef __attribute__((ext_vector_type(4))) float f32x4;
typedef __attribute__((ext_vector_type(16))) float f32x16;
typedef __attribute__((ext_vector_type(4))) int i32x4;
typedef unsigned short u16;

#define S_LEN 2048
#define D_DIM 2048
#define NHEAD 16
#define HDIM 128
#define M_ROWS 4096

#define MFMA(a,b,c) __builtin_amdgcn_mfma_f32_16x16x32_bf16(a,b,c,0,0,0)
#define MFMA32(a,b,c) __builtin_amdgcn_mfma_f32_32x32x16_bf16(a,b,c,0,0,0)

__device__ __forceinline__ u16 f2bf(float f) {
  union { float f; unsigned u; } v; v.f = f;
  unsigned r = v.u + 0x7fffu + ((v.u >> 16) & 1u);
  return (u16)(r >> 16);
}

__device__ __forceinline__ void async16(void* lds, const void* g) {
  __builtin_amdgcn_global_load_lds(
      (const __attribute__((address_space(1))) unsigned*)g,
      (__attribute__((address_space(3))) unsigned*)lds, 16, 0, 0);
}

__device__ __forceinline__ unsigned cvtpk(float lo, float hi) {
  unsigned r;
  asm("v_cvt_pk_bf16_f32 %0, %1, %2" : "=v"(r) : "v"(lo), "v"(hi));
  return r;
}
__device__ __forceinline__ void plswap(unsigned& x, unsigned& y) {
  asm("v_permlane32_swap_b32 %0, %1" : "+v"(x), "+v"(y));
}

// ---------------- x -> bf16 ----------------
__global__ void k_cvt_x(const float* __restrict__ x, u16* __restrict__ xb) {
  int i = blockIdx.x * 256 + threadIdx.x;
  float4 v = reinterpret_cast<const float4*>(x)[i];
  ushort4 o;
  o.x = f2bf(v.x); o.y = f2bf(v.y); o.z = f2bf(v.z); o.w = f2bf(v.w);
  reinterpret_cast<ushort4*>(xb)[i] = o;
}

// -------- W[k][n] f32 -> Wt[n][k] bf16 (transpose+convert) --------
__global__ void k_cvt_wt(const float* __restrict__ W, u16* __restrict__ Wt) {
  __shared__ u16 tile[32][33];
  int n0 = blockIdx.x * 32, k0 = blockIdx.y * 32;
  int tx = threadIdx.x & 31, ty = threadIdx.x >> 5;
#pragma unroll
  for (int i = 0; i < 4; i++)
    tile[ty + i * 8][tx] = f2bf(W[(size_t)(k0 + ty + i * 8) * D_DIM + n0 + tx]);
  __syncthreads();
#pragma unroll
  for (int i = 0; i < 4; i++)
    Wt[(size_t)(n0 + ty + i * 8) * D_DIM + k0 + tx] = tile[tx][ty + i * 8];
}

// -------- V[b,h,s,d] -> Vt[b,h,d,s] (bf16 transpose) --------
__global__ void k_vtrans(const u16* __restrict__ V, u16* __restrict__ Vt) {
  __shared__ u16 tile[32][33];
  int s0 = blockIdx.x * 32, d0 = blockIdx.y * 32, bh = blockIdx.z;
  const u16* Vp = V + (size_t)bh * S_LEN * HDIM;
  u16* Vtp = Vt + (size_t)bh * HDIM * S_LEN;
  int tx = threadIdx.x & 31, ty = threadIdx.x >> 5;
#pragma unroll
  for (int i = 0; i < 4; i++)
    tile[ty + i * 8][tx] = Vp[(size_t)(s0 + ty + i * 8) * HDIM + d0 + tx];
  __syncthreads();
#pragma unroll
  for (int i = 0; i < 4; i++)
    Vtp[(size_t)(d0 + ty + i * 8) * S_LEN + s0 + tx] = tile[tx][ty + i * 8];
}

// ======== 4-phase/K-tile interleaved GEMM (m201-style): C = A * Bt^T ========
// Tile 128x256, BK=64 (2 K-subs of 32), 8 waves (2M x 4N), wave tile 64x64.
// Phases = C-quadrants in order (0,0),(1,0),(1,1),(0,1): 8 MFMA + <=8 ds_read
// + one staging unit per phase. Units by first-need: u0 = A-mh0 + B-nh0
// (3 loads/thread), u1 = A-mh1 (1), u2 = B-nh1 (2), u3 = none.
// In-order vmcnt retirement + identical per-wave issue order: unit needed at
// phase p was issued exactly {3,5,4,-} loads ago (steady) / {3,2,0,-} (tail)
// -> counted vmcnt at each phase top + barrier = race-free (R5 proof).
// Both af-halves stay in registers; phase 3 is pure MFMA. LDS rows 64B with
// slot ^= (row>>1)&3 swizzle via pre-swizzled global source (rule 21).
template <int MODE>
__global__ __launch_bounds__(512, 1) void k_gemm8p(const u16* __restrict__ A,
                                                   const u16* __restrict__ Bt,
                                                   void* __restrict__ outp,
                                                   const float* __restrict__ fac) {
  constexpr int BUFSZ = 49152;  // A 2x8KB + B 2x16KB
  __shared__ __align__(16) char lds[2 * BUFSZ];
  const int m0 = blockIdx.y * 128, n0 = blockIdx.x * 256;
  const int t = threadIdx.x;
  const int w = t >> 6, l = t & 63;
  const int wr = (w >> 2) * 64, wc = (w & 3) * 64;
  const int lr = l & 15, lq = l >> 4;
  const char* Ab = (const char*)A;
  const char* Bb = (const char*)Bt;

  f32x4 acc[4][4] = {};

  const int sub = w >> 2, ww = w & 3;
  const int abase = (ww & 1) * 16 + (ww >> 1) * 64;  // A issue row base (mh0)
  const int bbase = (w >> 1) * 64 + (w & 1) * 16;    // B issue row base (nh0)
  const int rr = l >> 2, sl = l & 3;

  auto stageA = [&](int tt, int nb, int mh) {  // 1 load
    const int base = abase + mh * 32;
    const int row = base + rr;
    async16(lds + nb * BUFSZ + sub * 8192 + base * 64,
            Ab + (size_t)(m0 + row) * 4096 + tt * 128 + sub * 64 +
                ((sl ^ ((row >> 1) & 3)) * 16));
  };
  auto stageB = [&](int tt, int nb, int nh) {  // 2 loads
    const int base = bbase + nh * 32;
    const int row = base + rr;
#pragma unroll
    for (int j = 0; j < 2; j++)
      async16(lds + nb * BUFSZ + 16384 + j * 16384 + base * 64,
              Bb + (size_t)(n0 + row) * 4096 + tt * 128 + j * 64 +
                  ((sl ^ ((row >> 1) & 3)) * 16));
  };

  auto readA = [&](short8 af[2][2], int buf, int mh) {
#pragma unroll
    for (int mi = 0; mi < 2; mi++)
#pragma unroll
      for (int ks = 0; ks < 2; ks++) {
        const int row = wr + mh * 32 + mi * 16 + lr;
        af[mi][ks] = *reinterpret_cast<const short8*>(
            lds + buf * BUFSZ + ks * 8192 + row * 64 +
            ((lq ^ ((row >> 1) & 3)) * 16));
      }
  };
  auto readB = [&](short8 bf[2][2], int buf, int nh) {
#pragma unroll
    for (int ni = 0; ni < 2; ni++)
#pragma unroll
      for (int ks = 0; ks < 2; ks++) {
        const int row = wc + nh * 32 + ni * 16 + lr;
        bf[ni][ks] = *reinterpret_cast<const short8*>(
            lds + buf * BUFSZ + 16384 + ks * 16384 + row * 64 +
            ((lq ^ ((row >> 1) & 3)) * 16));
      }
  };

#define QUAD(AF, BF, MH, NH)                                                \
  {                                                                         \
    __builtin_amdgcn_s_setprio(1);                                          \
    _Pragma("unroll") for (int mi = 0; mi < 2; mi++)                        \
    _Pragma("unroll") for (int ni = 0; ni < 2; ni++)                        \
    _Pragma("unroll") for (int ks = 0; ks < 2; ks++)                        \
      acc[(MH)*2 + mi][(NH)*2 + ni] =                                       \
          MFMA(AF[mi][ks], BF[ni][ks], acc[(MH)*2 + mi][(NH)*2 + ni]);      \
    __builtin_amdgcn_s_setprio(0);                                          \
  }
#define VMW(N) asm volatile("s_waitcnt vmcnt(" #N ")" ::: "memory")
#define BAR()                         \
  do {                                \
    __builtin_amdgcn_s_barrier();     \
    asm volatile("" ::: "memory");    \
  } while (0)

  // prologue: u0, u1, u2 of tile 0 -> buf 0 (6 loads)
  stageA(0, 0, 0); stageB(0, 0, 0);
  stageA(0, 0, 1);
  stageB(0, 0, 1);

  short8 af0[2][2], af1[2][2], bfr[2][2];
  const int NT = D_DIM / 64;  // 32
  for (int tt = 0; tt < NT; tt++) {
    const int buf = tt & 1, nb = buf ^ 1;
    const bool pf = (tt + 1 < NT);
    // phase 0: quadrant (0,0); needs u0(t); stage u0(t+1)
    VMW(3); BAR();
    if (pf) { stageA(tt + 1, nb, 0); stageB(tt + 1, nb, 0); }
    readA(af0, buf, 0); readB(bfr, buf, 0);
    QUAD(af0, bfr, 0, 0);
    // phase 1: quadrant (1,0); needs u1(t); stage u1(t+1)
    if (pf) VMW(5); else VMW(2);
    BAR();
    if (pf) stageA(tt + 1, nb, 1);
    readA(af1, buf, 1);
    QUAD(af1, bfr, 1, 0);
    // phase 2: quadrant (1,1); needs u2(t); stage u2(t+1)
    if (pf) VMW(4); else VMW(0);
    BAR();
    if (pf) stageB(tt + 1, nb, 1);
    readB(bfr, buf, 1);
    QUAD(af1, bfr, 1, 1);
    // phase 3: quadrant (0,1); pure MFMA (af0, bfr both resident)
    BAR();
    QUAD(af0, bfr, 0, 1);
  }
#undef QUAD
#undef VMW
#undef BAR

  // epilogue
#pragma unroll
  for (int gm = 0; gm < 4; gm++) {
#pragma unroll
    for (int gn = 0; gn < 4; gn++) {
#pragma unroll
      for (int r = 0; r < 4; r++) {
        const int row = m0 + wr + gm * 16 + lq * 4 + r;
        const int col = n0 + wc + gn * 16 + lr;
        const float v = acc[gm][gn][r];
        if (MODE == 0) {
          const int mat = col >> 11;
          const int hh = (col >> 7) & 15;
          ((u16*)outp)[(size_t)mat * 8388608 +
                       (((size_t)((row >> 11) * NHEAD + hh)) * S_LEN + (row & 2047)) * HDIM +
                       (col & 127)] = f2bf(v);
        } else {
          ((float*)outp)[(size_t)row * D_DIM + col] = v * (1.0f + 0.1f * fac[row]);
        }
      }
    }
  }
}

// -------- phase projections pq/pk = xb @ Wpq / xb @ Wpk --------
__global__ __launch_bounds__(256) void k_phase_proj(const u16* __restrict__ xb,
                                                    const float* __restrict__ Wpq,
                                                    const float* __restrict__ Wpk,
                                                    float* __restrict__ pq,
                                                    float* __restrict__ pk) {
  __shared__ u16 xs[16][136];
  __shared__ float2 ws[128][16];
  const int t = threadIdx.x;
  const int m0 = blockIdx.x * 16;
  const int h = t & 15, r = t >> 4;
  float sq = 0.f, sk = 0.f;
  for (int kc = 0; kc < D_DIM; kc += 128) {
    *reinterpret_cast<short8*>(&xs[t >> 4][(t & 15) * 8]) =
        *reinterpret_cast<const short8*>(
            &xb[(size_t)(m0 + (t >> 4)) * D_DIM + kc + (t & 15) * 8]);
#pragma unroll
    for (int j = 0; j < 8; j++) {
      const int idx = j * 256 + t;
      const int k = idx >> 4, hh = idx & 15;
      ws[k][hh] = make_float2(Wpq[(size_t)(kc + k) * NHEAD + hh],
                              Wpk[(size_t)(kc + k) * NHEAD + hh]);
    }
    __syncthreads();
#pragma unroll
    for (int k8 = 0; k8 < 16; k8++) {
      const short8 x8 = *reinterpret_cast<const short8*>(&xs[r][k8 * 8]);
#pragma unroll
      for (int j = 0; j < 8; j++) {
        union { float f; unsigned u; } c;
        c.u = ((unsigned)(u16)x8[j]) << 16;
        const float2 wv = ws[k8 * 8 + j][h];
        sq += c.f * wv.x;
        sk += c.f * wv.y;
      }
    }
    __syncthreads();
  }
  pq[(size_t)(m0 + r) * NHEAD + h] = sq;
  pk[(size_t)(m0 + r) * NHEAD + h] = sk;
}

__device__ __forceinline__ float wave_sum(float v) {
  v += __shfl_xor(v, 1);  v += __shfl_xor(v, 2);  v += __shfl_xor(v, 4);
  v += __shfl_xor(v, 8);  v += __shfl_xor(v, 16); v += __shfl_xor(v, 32);
  return v;
}

// -------- Ck/Sk = sum_s cos/sin(pk) per (b,h) --------
__global__ void k_phase_ck(const float* __restrict__ pk, float* __restrict__ Ck,
                           float* __restrict__ Sk) {
  int bh = blockIdx.x, b = bh >> 4, h = bh & 15;
  float c = 0.f, s = 0.f;
  for (int ss = threadIdx.x; ss < S_LEN; ss += 256) {
    float v = pk[((size_t)b * S_LEN + ss) * NHEAD + h];
    c += cosf(v); s += sinf(v);
  }
  c = wave_sum(c); s = wave_sum(s);
  __shared__ float rc[4], rs[4];
  int wv = threadIdx.x >> 6;
  if ((threadIdx.x & 63) == 0) { rc[wv] = c; rs[wv] = s; }
  __syncthreads();
  if (threadIdx.x == 0) {
    Ck[bh] = rc[0] + rc[1] + rc[2] + rc[3];
    Sk[bh] = rs[0] + rs[1] + rs[2] + rs[3];
  }
}

// -------- phase_mod[m] --------
__global__ void k_phase_mod(const float* __restrict__ pq, const float* __restrict__ Ck,
                            const float* __restrict__ Sk, float* __restrict__ pm) {
  int m = blockIdx.x * 256 + threadIdx.x;
  int b = m >> 11;
  float a = 0.f;
#pragma unroll
  for (int h = 0; h < NHEAD; h++) {
    float v = pq[(size_t)m * NHEAD + h];
    a += cosf(v) * Ck[b * NHEAD + h] + sinf(v) * Sk[b * NHEAD + h];
  }
  pm[m] = a * (1.0f / (S_LEN * NHEAD));
}

// -------- causal flash attention: 4 warps x 32 q-rows, double-buffered K/V --------
__global__ __launch_bounds__(256, 2) void k_attn(const u16* __restrict__ Q,
                                                 const u16* __restrict__ K,
                                                 const u16* __restrict__ Vt,
                                                 u16* __restrict__ ctx) {
  const int bh = blockIdx.x;
  const int gy = blockIdx.y;
  const int g = (gy < 8) ? (15 - gy) : (gy - 8);  // pair long/short across dispatch
  const int b = bh >> 4, h = bh & 15;
  const int t = threadIdx.x;
  const int w = t >> 6, l = t & 63;
  const int ln = l & 31, hi = l >> 5;
  const int q0w = g * 128 + w * 32;
  const int qq = q0w + ln;
  const float scale = 0.08838834764831845f;

  const u16* Qp = Q + (size_t)bh * S_LEN * HDIM;
  const char* Kg = (const char*)(K + (size_t)bh * S_LEN * HDIM);
  const char* Vg = (const char*)(Vt + (size_t)bh * HDIM * S_LEN);

  __shared__ __align__(16) char Ks[2][16384];
  __shared__ __align__(16) char Vs[2][16384];

  auto stage = [&](int t64, int buf) {
    const int k0 = t64 * 64;
#pragma unroll
    for (int i = 0; i < 4; i++) {
      const int key = i * 16 + w * 4 + (l >> 4);
      async16(Ks[buf] + i * 4096 + w * 1024,
              Kg + (size_t)(k0 + key) * 256 + (((l & 15) * 16) ^ ((key & 15) << 4)));
      const int d = i * 32 + w * 8 + (l >> 3);
      async16(Vs[buf] + i * 4096 + w * 1024,
              Vg + (size_t)d * (S_LEN * 2) + k0 * 2 + (((l & 7) * 16) ^ ((d & 7) << 4)));
    }
  };

  short8 qf[8];
#pragma unroll
  for (int c = 0; c < 8; c++)
    qf[c] = *reinterpret_cast<const short8*>(Qp + (size_t)qq * HDIM + c * 16 + hi * 8);

  f32x16 o[4];
#pragma unroll
  for (int ds = 0; ds < 4; ds++)
#pragma unroll
    for (int r = 0; r < 16; r++) o[ds][r] = 0.f;
  float mrun = -1e30f, lsum = 0.f;

  const int nt = (g + 1) * 2;
  stage(0, 0);
  for (int t64 = 0; t64 < nt; t64++) {
    const int buf = t64 & 1;
    const int k0 = t64 * 64;
    asm volatile("s_waitcnt vmcnt(0)" ::: "memory");
    __syncthreads();
    if (t64 + 1 < nt) stage(t64 + 1, buf ^ 1);
    if (k0 < q0w + 32) {
      f32x16 s[2];
#pragma unroll
      for (int ks = 0; ks < 2; ks++)
#pragma unroll
        for (int r = 0; r < 16; r++) s[ks][r] = 0.f;
      __builtin_amdgcn_s_setprio(1);
#pragma unroll
      for (int ks = 0; ks < 2; ks++) {
        const int key = ks * 32 + ln;
        const char* kb = Ks[buf] + key * 256;
        const unsigned swzk = (unsigned)((key & 15) << 4);
#pragma unroll
        for (int c = 0; c < 8; c++) {
          const short8 kf = *reinterpret_cast<const short8*>(
              kb + (((unsigned)(c * 32 + hi * 16)) ^ swzk));
          s[ks] = MFMA32(kf, qf[c], s[ks]);
        }
      }
      __builtin_amdgcn_s_setprio(0);
      float p[32];
      float mx = -1e30f;
#pragma unroll
      for (int ks = 0; ks < 2; ks++)
#pragma unroll
        for (int r = 0; r < 16; r++) {
          const int key = k0 + ks * 32 + (r & 3) + 8 * (r >> 2) + 4 * hi;
          const float v = (key <= qq) ? s[ks][r] * scale : -1e30f;
          p[ks * 16 + r] = v;
          mx = fmaxf(mx, v);
        }
      mx = fmaxf(mx, __shfl_xor(mx, 32));
      const float nm = fmaxf(mrun, mx);
      const float f = __expf(mrun - nm);
      float rs = 0.f;
#pragma unroll
      for (int i = 0; i < 32; i++) { p[i] = __expf(p[i] - nm); rs += p[i]; }
      rs += __shfl_xor(rs, 32);
      lsum = lsum * f + rs;
      mrun = nm;
#pragma unroll
      for (int ds = 0; ds < 4; ds++)
#pragma unroll
        for (int r = 0; r < 16; r++) o[ds][r] *= f;
      short8 bfr[4];
#pragma unroll
      for (int sub = 0; sub < 2; sub++) {
#pragma unroll
        for (int half = 0; half < 2; half++) {
          const int pb = sub * 16 + half * 8;
          unsigned X1 = cvtpk(p[pb + 0], p[pb + 1]);
          unsigned X2 = cvtpk(p[pb + 2], p[pb + 3]);
          unsigned Y1 = cvtpk(p[pb + 4], p[pb + 5]);
          unsigned Y2 = cvtpk(p[pb + 6], p[pb + 7]);
          plswap(X1, Y1);
          plswap(X2, Y2);
          i32x4 bw;
          bw[0] = (int)X1; bw[1] = (int)X2; bw[2] = (int)Y1; bw[3] = (int)Y2;
          bfr[sub * 2 + half] = __builtin_bit_cast(short8, bw);
        }
      }
      __builtin_amdgcn_s_setprio(1);
#pragma unroll
      for (int ds = 0; ds < 4; ds++) {
        const int d = ds * 32 + ln;
        const char* vb = Vs[buf] + d * 128;
        const unsigned swzv = (unsigned)((d & 7) << 4);
#pragma unroll
        for (int slot = 0; slot < 4; slot++) {
          const short8 vf = *reinterpret_cast<const short8*>(
              vb + (((unsigned)(slot * 32 + hi * 16)) ^ swzv));
          o[ds] = MFMA32(vf, bfr[slot], o[ds]);
        }
      }
      __builtin_amdgcn_s_setprio(0);
    }
  }

  const float rl = 1.0f / lsum;
#pragma unroll
  for (int ds = 0; ds < 4; ds++) {
#pragma unroll
    for (int rq = 0; rq < 4; rq++) {
      const int d = ds * 32 + 8 * rq + 4 * hi;
      ushort4 pk4;
      pk4.x = f2bf(o[ds][rq * 4 + 0] * rl);
      pk4.y = f2bf(o[ds][rq * 4 + 1] * rl);
      pk4.z = f2bf(o[ds][rq * 4 + 2] * rl);
      pk4.w = f2bf(o[ds][rq * 4 + 3] * rl);
      *reinterpret_cast<ushort4*>(ctx + ((size_t)(b * S_LEN + qq)) * D_DIM + h * HDIM + d) = pk4;
    }
  }
}

extern "C" void kernel_launch(void* const* d_in, const int* in_sizes, int n_in,
                              void* d_out, int out_size, void* d_ws, size_t ws_size,
                              hipStream_t stream) {
  const float* x   = (const float*)d_in[0];
  const float* Wq  = (const float*)d_in[1];
  const float* Wk  = (const float*)d_in[2];
  const float* Wv  = (const float*)d_in[3];
  const float* Wo  = (const float*)d_in[4];
  const float* Wpq = (const float*)d_in[5];
  const float* Wpk = (const float*)d_in[6];

  char* ws = (char*)d_ws;
  u16* xb   = (u16*)(ws + 0);            // 16 MB  x bf16 [4096][2048]
  u16* Wqt  = (u16*)(ws + 16777216);     // 8 MB each, transposed bf16 (Wq,Wk,Wv contiguous)
  u16* Wkt  = (u16*)(ws + 25165824);
  u16* Wvt  = (u16*)(ws + 33554432);
  u16* Wot  = (u16*)(ws + 41943040);
  u16* Qb   = (u16*)(ws + 50331648);     // [b,h,s,d] bf16 (Q,K,V contiguous)
  u16* Kb   = (u16*)(ws + 67108864);
  u16* Vb   = (u16*)(ws + 83886080);     // V, later reused as ctx
  u16* Vt   = (u16*)(ws + 100663296);    // [b,h,d,s] bf16
  float* pq = (float*)(ws + 117440512);
  float* pk = (float*)(ws + 117702656);
  float* Ck = (float*)(ws + 117964800);
  float* Sk = (float*)(ws + 117964928);
  float* pm = (float*)(ws + 117965056);

  k_cvt_x<<<dim3(M_ROWS * D_DIM / 1024), 256, 0, stream>>>(x, xb);
  k_cvt_wt<<<dim3(64, 64), 256, 0, stream>>>(Wq, Wqt);
  k_cvt_wt<<<dim3(64, 64), 256, 0, stream>>>(Wk, Wkt);
  k_cvt_wt<<<dim3(64, 64), 256, 0, stream>>>(Wv, Wvt);
  k_cvt_wt<<<dim3(64, 64), 256, 0, stream>>>(Wo, Wot);

  // fused QKV: Bt = [Wqt;Wkt;Wvt] = [6144][2048], 128x256 tiles
  // grid 24x32 = 768 blocks -> 3 clean rounds at 1 block/CU
  k_gemm8p<0><<<dim3(24, 32), 512, 0, stream>>>(xb, Wqt, Qb, nullptr);

  k_vtrans<<<dim3(64, 4, 32), 256, 0, stream>>>(Vb, Vt);

  k_phase_proj<<<dim3(256), 256, 0, stream>>>(xb, Wpq, Wpk, pq, pk);
  k_phase_ck<<<dim3(32), 256, 0, stream>>>(pk, Ck, Sk);
  k_phase_mod<<<dim3(16), 256, 0, stream>>>(pq, Ck, Sk, pm);

  k_attn<<<dim3(32, 16), 256, 0, stream>>>(Qb, Kb, Vt, Vb /*ctx*/);

  // O-proj: 128x256 tiles -> grid 8x32 = 256 blocks, one full round
  k_gemm8p<1><<<dim3(8, 32), 512, 0, stream>>>(Vb /*ctx*/, Wot, (void*)d_out, pm);
}

// Round 11
// 331.446 us; speedup vs baseline: 1.2015x; 1.0131x over previous
//
#include <hip/hip_runtime.h>
#include <hip/hip_bf16.h>

typedef __attribute__((ext_vector_type(8))) short short8;
typedef __attribute__((ext_vector_type(4))) float f32x4;
typedef __attribute__((ext_vector_type(16))) float f32x16;
typedef __attribute__((ext_vector_type(4))) int i32x4;
typedef unsigned short u16;

#define S_LEN 2048
#define D_DIM 2048
#define NHEAD 16
#define HDIM 128
#define M_ROWS 4096

#define MFMA(a,b,c) __builtin_amdgcn_mfma_f32_16x16x32_bf16(a,b,c,0,0,0)
#define MFMA32(a,b,c) __builtin_amdgcn_mfma_f32_32x32x16_bf16(a,b,c,0,0,0)

__device__ __forceinline__ u16 f2bf(float f) {
  union { float f; unsigned u; } v; v.f = f;
  unsigned r = v.u + 0x7fffu + ((v.u >> 16) & 1u);
  return (u16)(r >> 16);
}

__device__ __forceinline__ void async16(void* lds, const void* g) {
  __builtin_amdgcn_global_load_lds(
      (const __attribute__((address_space(1))) unsigned*)g,
      (__attribute__((address_space(3))) unsigned*)lds, 16, 0, 0);
}

__device__ __forceinline__ unsigned cvtpk(float lo, float hi) {
  unsigned r;
  asm("v_cvt_pk_bf16_f32 %0, %1, %2" : "=v"(r) : "v"(lo), "v"(hi));
  return r;
}
__device__ __forceinline__ void plswap(unsigned& x, unsigned& y) {
  asm("v_permlane32_swap_b32 %0, %1" : "+v"(x), "+v"(y));
}

// ---------------- x -> bf16 ----------------
__global__ void k_cvt_x(const float* __restrict__ x, u16* __restrict__ xb) {
  int i = blockIdx.x * 256 + threadIdx.x;
  float4 v = reinterpret_cast<const float4*>(x)[i];
  ushort4 o;
  o.x = f2bf(v.x); o.y = f2bf(v.y); o.z = f2bf(v.z); o.w = f2bf(v.w);
  reinterpret_cast<ushort4*>(xb)[i] = o;
}

// -------- 4x W[k][n] f32 -> Wt[n][k] bf16 (transpose+convert, fused) --------
__global__ void k_cvt_wt4(const float* __restrict__ W0, const float* __restrict__ W1,
                          const float* __restrict__ W2, const float* __restrict__ W3,
                          u16* __restrict__ T0, u16* __restrict__ T1,
                          u16* __restrict__ T2, u16* __restrict__ T3) {
  __shared__ u16 tile[32][33];
  const int z = blockIdx.z;
  const float* W = (z == 0) ? W0 : (z == 1) ? W1 : (z == 2) ? W2 : W3;
  u16* Wt = (z == 0) ? T0 : (z == 1) ? T1 : (z == 2) ? T2 : T3;
  int n0 = blockIdx.x * 32, k0 = blockIdx.y * 32;
  int tx = threadIdx.x & 31, ty = threadIdx.x >> 5;
#pragma unroll
  for (int i = 0; i < 4; i++)
    tile[ty + i * 8][tx] = f2bf(W[(size_t)(k0 + ty + i * 8) * D_DIM + n0 + tx]);
  __syncthreads();
#pragma unroll
  for (int i = 0; i < 4; i++)
    Wt[(size_t)(n0 + ty + i * 8) * D_DIM + k0 + tx] = tile[tx][ty + i * 8];
}

// -------- V[b,h,s,d] -> Vt[b,h,d,s] (bf16 transpose) --------
__global__ void k_vtrans(const u16* __restrict__ V, u16* __restrict__ Vt) {
  __shared__ u16 tile[32][33];
  int s0 = blockIdx.x * 32, d0 = blockIdx.y * 32, bh = blockIdx.z;
  const u16* Vp = V + (size_t)bh * S_LEN * HDIM;
  u16* Vtp = Vt + (size_t)bh * HDIM * S_LEN;
  int tx = threadIdx.x & 31, ty = threadIdx.x >> 5;
#pragma unroll
  for (int i = 0; i < 4; i++)
    tile[ty + i * 8][tx] = Vp[(size_t)(s0 + ty + i * 8) * HDIM + d0 + tx];
  __syncthreads();
#pragma unroll
  for (int i = 0; i < 4; i++)
    Vtp[(size_t)(d0 + ty + i * 8) * S_LEN + s0 + tx] = tile[tx][ty + i * 8];
}

// ======== 4-phase ring-3 GEMM: C = A[M][K] * Bt[N][K]^T ========
// Tile 128x256, BK=64 (2 K-subs), 8 waves (2M x 4N), wave tile 64x64.
// Phases = C-quadrants (0,0),(1,0),(1,1),(0,1). Staging units of tile T:
// u0 = A-mh0 + B-nh0 (3 loads/thread), u1 = A-mh1 (1), u2 = B-nh1 (2).
// RING-3 LDS (147KB), prefetch distance 2: phase k of tile t stages
// u_k(t+2) into buf (t+2)%3. In-order vmcnt retirement + identical
// per-wave issue order gives EXACT counted waits:
//   steady (tt < NT-2): {9, 11, 10}   (issued-after-target counts)
//   tt == NT-2:         {9,  8,  6}
//   tt == NT-1:         {3,  2,  0}
// Buffer safety: writes go to (t+2)%3, reads from t%3; (t+2)%3 was last
// read at tile t-1, finished before phase0(t)'s barrier. LDS rows 64B
// (4 x 16B slots); swizzle slot ^= (row>>1)&3 via pre-swizzled global
// source + same XOR on ds_read (involution).
template <int MODE>
__device__ __forceinline__ void gemm_body(const u16* __restrict__ A,
                                          const u16* __restrict__ Bt,
                                          void* __restrict__ outp,
                                          const float* __restrict__ fac,
                                          char* lds) {
  constexpr int BUFSZ = 49152;  // A 2x8KB + B 2x16KB
  const int m0 = blockIdx.y * 128, n0 = blockIdx.x * 256;
  const int t = threadIdx.x;
  const int w = t >> 6, l = t & 63;
  const int wr = (w >> 2) * 64, wc = (w & 3) * 64;
  const int lr = l & 15, lq = l >> 4;
  const char* Ab = (const char*)A;
  const char* Bb = (const char*)Bt;

  f32x4 acc[4][4] = {};

  const int sub = w >> 2, ww = w & 3;
  const int abase = (ww & 1) * 16 + (ww >> 1) * 64;  // A issue row base (mh0)
  const int bbase = (w >> 1) * 64 + (w & 1) * 16;    // B issue row base (nh0)
  const int rr = l >> 2, sl = l & 3;

  auto stageA = [&](int tt, int nb, int mh) {  // 1 load/thread
    const int base = abase + mh * 32;
    const int row = base + rr;
    async16(lds + nb * BUFSZ + sub * 8192 + base * 64,
            Ab + (size_t)(m0 + row) * 4096 + tt * 128 + sub * 64 +
                ((sl ^ ((row >> 1) & 3)) * 16));
  };
  auto stageB = [&](int tt, int nb, int nh) {  // 2 loads/thread
    const int base = bbase + nh * 32;
    const int row = base + rr;
#pragma unroll
    for (int j = 0; j < 2; j++)
      async16(lds + nb * BUFSZ + 16384 + j * 16384 + base * 64,
              Bb + (size_t)(n0 + row) * 4096 + tt * 128 + j * 64 +
                  ((sl ^ ((row >> 1) & 3)) * 16));
  };

  auto readA = [&](short8 af[2][2], int buf, int mh) {
#pragma unroll
    for (int mi = 0; mi < 2; mi++)
#pragma unroll
      for (int ks = 0; ks < 2; ks++) {
        const int row = wr + mh * 32 + mi * 16 + lr;
        af[mi][ks] = *reinterpret_cast<const short8*>(
            lds + buf * BUFSZ + ks * 8192 + row * 64 +
            ((lq ^ ((row >> 1) & 3)) * 16));
      }
  };
  auto readB = [&](short8 bf[2][2], int buf, int nh) {
#pragma unroll
    for (int ni = 0; ni < 2; ni++)
#pragma unroll
      for (int ks = 0; ks < 2; ks++) {
        const int row = wc + nh * 32 + ni * 16 + lr;
        bf[ni][ks] = *reinterpret_cast<const short8*>(
            lds + buf * BUFSZ + 16384 + ks * 16384 + row * 64 +
            ((lq ^ ((row >> 1) & 3)) * 16));
      }
  };

#define QUAD(AF, BF, MH, NH)                                                \
  {                                                                         \
    __builtin_amdgcn_s_setprio(1);                                          \
    _Pragma("unroll") for (int mi = 0; mi < 2; mi++)                        \
    _Pragma("unroll") for (int ni = 0; ni < 2; ni++)                        \
    _Pragma("unroll") for (int ks = 0; ks < 2; ks++)                        \
      acc[(MH)*2 + mi][(NH)*2 + ni] =                                       \
          MFMA(AF[mi][ks], BF[ni][ks], acc[(MH)*2 + mi][(NH)*2 + ni]);      \
    __builtin_amdgcn_s_setprio(0);                                          \
  }
#define VMW(N) asm volatile("s_waitcnt vmcnt(" #N ")" ::: "memory")
#define BAR()                         \
  do {                                \
    __builtin_amdgcn_s_barrier();     \
    asm volatile("" ::: "memory");    \
  } while (0)

  // prologue: tiles 0 and 1 fully staged (u0,u1,u2 each) -> bufs 0,1
  stageA(0, 0, 0); stageB(0, 0, 0);
  stageA(0, 0, 1);
  stageB(0, 0, 1);
  stageA(1, 1, 0); stageB(1, 1, 0);
  stageA(1, 1, 1);
  stageB(1, 1, 1);

  short8 af0[2][2], af1[2][2], bfr[2][2];
  const int NT = D_DIM / 64;  // 32
  for (int tt = 0; tt < NT; tt++) {
    const int buf = tt % 3;
    const int sb = (tt + 2) % 3;
    const bool pf2 = (tt + 2 < NT);
    // phase 0: quadrant (0,0); needs u0(t); stage u0(t+2)
    if (tt < NT - 1) VMW(9); else VMW(3);
    BAR();
    if (pf2) { stageA(tt + 2, sb, 0); stageB(tt + 2, sb, 0); }
    readA(af0, buf, 0); readB(bfr, buf, 0);
    QUAD(af0, bfr, 0, 0);
    // phase 1: quadrant (1,0); needs u1(t); stage u1(t+2)
    if (tt < NT - 2) VMW(11); else if (tt == NT - 2) VMW(8); else VMW(2);
    BAR();
    if (pf2) stageA(tt + 2, sb, 1);
    readA(af1, buf, 1);
    QUAD(af1, bfr, 1, 0);
    // phase 2: quadrant (1,1); needs u2(t); stage u2(t+2)
    if (tt < NT - 2) VMW(10); else if (tt == NT - 2) VMW(6); else VMW(0);
    BAR();
    if (pf2) stageB(tt + 2, sb, 1);
    readB(bfr, buf, 1);
    QUAD(af1, bfr, 1, 1);
    // phase 3: quadrant (0,1); pure MFMA (af0, bfr resident)
    BAR();
    QUAD(af0, bfr, 0, 1);
  }
#undef QUAD
#undef VMW
#undef BAR

  // epilogue
#pragma unroll
  for (int gm = 0; gm < 4; gm++) {
#pragma unroll
    for (int gn = 0; gn < 4; gn++) {
#pragma unroll
      for (int r = 0; r < 4; r++) {
        const int row = m0 + wr + gm * 16 + lq * 4 + r;
        const int col = n0 + wc + gn * 16 + lr;
        const float v = acc[gm][gn][r];
        if (MODE == 0) {
          const int mat = col >> 11;
          const int hh = (col >> 7) & 15;
          ((u16*)outp)[(size_t)mat * 8388608 +
                       (((size_t)((row >> 11) * NHEAD + hh)) * S_LEN + (row & 2047)) * HDIM +
                       (col & 127)] = f2bf(v);
        } else {
          ((float*)outp)[(size_t)row * D_DIM + col] = v * (1.0f + 0.1f * fac[row]);
        }
      }
    }
  }
}

__global__ __launch_bounds__(512, 1) void k_qkv(const u16* __restrict__ A,
                                                const u16* __restrict__ Bt,
                                                void* __restrict__ outp) {
  __shared__ __align__(16) char lds[3 * 49152];
  gemm_body<0>(A, Bt, outp, nullptr, lds);
}

__global__ __launch_bounds__(512, 1) void k_oproj(const u16* __restrict__ A,
                                                  const u16* __restrict__ Bt,
                                                  void* __restrict__ outp,
                                                  const float* __restrict__ fac) {
  __shared__ __align__(16) char lds[3 * 49152];
  gemm_body<1>(A, Bt, outp, fac, lds);
}

// -------- phase projections pq/pk = xb @ Wpq / xb @ Wpk --------
__global__ __launch_bounds__(256) void k_phase_proj(const u16* __restrict__ xb,
                                                    const float* __restrict__ Wpq,
                                                    const float* __restrict__ Wpk,
                                                    float* __restrict__ pq,
                                                    float* __restrict__ pk) {
  __shared__ u16 xs[16][136];
  __shared__ float2 ws[128][16];
  const int t = threadIdx.x;
  const int m0 = blockIdx.x * 16;
  const int h = t & 15, r = t >> 4;
  float sq = 0.f, sk = 0.f;
  for (int kc = 0; kc < D_DIM; kc += 128) {
    *reinterpret_cast<short8*>(&xs[t >> 4][(t & 15) * 8]) =
        *reinterpret_cast<const short8*>(
            &xb[(size_t)(m0 + (t >> 4)) * D_DIM + kc + (t & 15) * 8]);
#pragma unroll
    for (int j = 0; j < 8; j++) {
      const int idx = j * 256 + t;
      const int k = idx >> 4, hh = idx & 15;
      ws[k][hh] = make_float2(Wpq[(size_t)(kc + k) * NHEAD + hh],
                              Wpk[(size_t)(kc + k) * NHEAD + hh]);
    }
    __syncthreads();
#pragma unroll
    for (int k8 = 0; k8 < 16; k8++) {
      const short8 x8 = *reinterpret_cast<const short8*>(&xs[r][k8 * 8]);
#pragma unroll
      for (int j = 0; j < 8; j++) {
        union { float f; unsigned u; } c;
        c.u = ((unsigned)(u16)x8[j]) << 16;
        const float2 wv = ws[k8 * 8 + j][h];
        sq += c.f * wv.x;
        sk += c.f * wv.y;
      }
    }
    __syncthreads();
  }
  pq[(size_t)(m0 + r) * NHEAD + h] = sq;
  pk[(size_t)(m0 + r) * NHEAD + h] = sk;
}

__device__ __forceinline__ float wave_sum(float v) {
  v += __shfl_xor(v, 1);  v += __shfl_xor(v, 2);  v += __shfl_xor(v, 4);
  v += __shfl_xor(v, 8);  v += __shfl_xor(v, 16); v += __shfl_xor(v, 32);
  return v;
}

// -------- Ck/Sk = sum_s cos/sin(pk) per (b,h) --------
__global__ void k_phase_ck(const float* __restrict__ pk, float* __restrict__ Ck,
                           float* __restrict__ Sk) {
  int bh = blockIdx.x, b = bh >> 4, h = bh & 15;
  float c = 0.f, s = 0.f;
  for (int ss = threadIdx.x; ss < S_LEN; ss += 256) {
    float v = pk[((size_t)b * S_LEN + ss) * NHEAD + h];
    c += cosf(v); s += sinf(v);
  }
  c = wave_sum(c); s = wave_sum(s);
  __shared__ float rc[4], rs[4];
  int wv = threadIdx.x >> 6;
  if ((threadIdx.x & 63) == 0) { rc[wv] = c; rs[wv] = s; }
  __syncthreads();
  if (threadIdx.x == 0) {
    Ck[bh] = rc[0] + rc[1] + rc[2] + rc[3];
    Sk[bh] = rs[0] + rs[1] + rs[2] + rs[3];
  }
}

// -------- phase_mod[m] --------
__global__ void k_phase_mod(const float* __restrict__ pq, const float* __restrict__ Ck,
                            const float* __restrict__ Sk, float* __restrict__ pm) {
  int m = blockIdx.x * 256 + threadIdx.x;
  int b = m >> 11;
  float a = 0.f;
#pragma unroll
  for (int h = 0; h < NHEAD; h++) {
    float v = pq[(size_t)m * NHEAD + h];
    a += cosf(v) * Ck[b * NHEAD + h] + sinf(v) * Sk[b * NHEAD + h];
  }
  pm[m] = a * (1.0f / (S_LEN * NHEAD));
}

// -------- causal flash attention: 4 warps x 32 q-rows, double-buffered K/V --------
__global__ __launch_bounds__(256, 2) void k_attn(const u16* __restrict__ Q,
                                                 const u16* __restrict__ K,
                                                 const u16* __restrict__ Vt,
                                                 u16* __restrict__ ctx) {
  const int bh = blockIdx.x;
  const int gy = blockIdx.y;
  const int g = (gy < 8) ? (15 - gy) : (gy - 8);  // pair long/short across dispatch
  const int b = bh >> 4, h = bh & 15;
  const int t = threadIdx.x;
  const int w = t >> 6, l = t & 63;
  const int ln = l & 31, hi = l >> 5;
  const int q0w = g * 128 + w * 32;
  const int qq = q0w + ln;
  const float scale = 0.08838834764831845f;

  const u16* Qp = Q + (size_t)bh * S_LEN * HDIM;
  const char* Kg = (const char*)(K + (size_t)bh * S_LEN * HDIM);
  const char* Vg = (const char*)(Vt + (size_t)bh * HDIM * S_LEN);

  __shared__ __align__(16) char Ks[2][16384];
  __shared__ __align__(16) char Vs[2][16384];

  auto stage = [&](int t64, int buf) {
    const int k0 = t64 * 64;
#pragma unroll
    for (int i = 0; i < 4; i++) {
      const int key = i * 16 + w * 4 + (l >> 4);
      async16(Ks[buf] + i * 4096 + w * 1024,
              Kg + (size_t)(k0 + key) * 256 + (((l & 15) * 16) ^ ((key & 15) << 4)));
      const int d = i * 32 + w * 8 + (l >> 3);
      async16(Vs[buf] + i * 4096 + w * 1024,
              Vg + (size_t)d * (S_LEN * 2) + k0 * 2 + (((l & 7) * 16) ^ ((d & 7) << 4)));
    }
  };

  short8 qf[8];
#pragma unroll
  for (int c = 0; c < 8; c++)
    qf[c] = *reinterpret_cast<const short8*>(Qp + (size_t)qq * HDIM + c * 16 + hi * 8);

  f32x16 o[4];
#pragma unroll
  for (int ds = 0; ds < 4; ds++)
#pragma unroll
    for (int r = 0; r < 16; r++) o[ds][r] = 0.f;
  float mrun = -1e30f, lsum = 0.f;

  const int nt = (g + 1) * 2;
  stage(0, 0);
  for (int t64 = 0; t64 < nt; t64++) {
    const int buf = t64 & 1;
    const int k0 = t64 * 64;
    asm volatile("s_waitcnt vmcnt(0)" ::: "memory");
    __syncthreads();
    if (t64 + 1 < nt) stage(t64 + 1, buf ^ 1);
    if (k0 < q0w + 32) {
      f32x16 s[2];
#pragma unroll
      for (int ks = 0; ks < 2; ks++)
#pragma unroll
        for (int r = 0; r < 16; r++) s[ks][r] = 0.f;
      __builtin_amdgcn_s_setprio(1);
#pragma unroll
      for (int ks = 0; ks < 2; ks++) {
        const int key = ks * 32 + ln;
        const char* kb = Ks[buf] + key * 256;
        const unsigned swzk = (unsigned)((key & 15) << 4);
#pragma unroll
        for (int c = 0; c < 8; c++) {
          const short8 kf = *reinterpret_cast<const short8*>(
              kb + (((unsigned)(c * 32 + hi * 16)) ^ swzk));
          s[ks] = MFMA32(kf, qf[c], s[ks]);
        }
      }
      __builtin_amdgcn_s_setprio(0);
      float p[32];
      float mx = -1e30f;
#pragma unroll
      for (int ks = 0; ks < 2; ks++)
#pragma unroll
        for (int r = 0; r < 16; r++) {
          const int key = k0 + ks * 32 + (r & 3) + 8 * (r >> 2) + 4 * hi;
          const float v = (key <= qq) ? s[ks][r] * scale : -1e30f;
          p[ks * 16 + r] = v;
          mx = fmaxf(mx, v);
        }
      mx = fmaxf(mx, __shfl_xor(mx, 32));
      const float nm = fmaxf(mrun, mx);
      const float f = __expf(mrun - nm);
      float rs = 0.f;
#pragma unroll
      for (int i = 0; i < 32; i++) { p[i] = __expf(p[i] - nm); rs += p[i]; }
      rs += __shfl_xor(rs, 32);
      lsum = lsum * f + rs;
      mrun = nm;
#pragma unroll
      for (int ds = 0; ds < 4; ds++)
#pragma unroll
        for (int r = 0; r < 16; r++) o[ds][r] *= f;
      short8 bfr[4];
#pragma unroll
      for (int sub = 0; sub < 2; sub++) {
#pragma unroll
        for (int half = 0; half < 2; half++) {
          const int pb = sub * 16 + half * 8;
          unsigned X1 = cvtpk(p[pb + 0], p[pb + 1]);
          unsigned X2 = cvtpk(p[pb + 2], p[pb + 3]);
          unsigned Y1 = cvtpk(p[pb + 4], p[pb + 5]);
          unsigned Y2 = cvtpk(p[pb + 6], p[pb + 7]);
          plswap(X1, Y1);
          plswap(X2, Y2);
          i32x4 bw;
          bw[0] = (int)X1; bw[1] = (int)X2; bw[2] = (int)Y1; bw[3] = (int)Y2;
          bfr[sub * 2 + half] = __builtin_bit_cast(short8, bw);
        }
      }
      __builtin_amdgcn_s_setprio(1);
#pragma unroll
      for (int ds = 0; ds < 4; ds++) {
        const int d = ds * 32 + ln;
        const char* vb = Vs[buf] + d * 128;
        const unsigned swzv = (unsigned)((d & 7) << 4);
#pragma unroll
        for (int slot = 0; slot < 4; slot++) {
          const short8 vf = *reinterpret_cast<const short8*>(
              vb + (((unsigned)(slot * 32 + hi * 16)) ^ swzv));
          o[ds] = MFMA32(vf, bfr[slot], o[ds]);
        }
      }
      __builtin_amdgcn_s_setprio(0);
    }
  }

  const float rl = 1.0f / lsum;
#pragma unroll
  for (int ds = 0; ds < 4; ds++) {
#pragma unroll
    for (int rq = 0; rq < 4; rq++) {
      const int d = ds * 32 + 8 * rq + 4 * hi;
      ushort4 pk4;
      pk4.x = f2bf(o[ds][rq * 4 + 0] * rl);
      pk4.y = f2bf(o[ds][rq * 4 + 1] * rl);
      pk4.z = f2bf(o[ds][rq * 4 + 2] * rl);
      pk4.w = f2bf(o[ds][rq * 4 + 3] * rl);
      *reinterpret_cast<ushort4*>(ctx + ((size_t)(b * S_LEN + qq)) * D_DIM + h * HDIM + d) = pk4;
    }
  }
}

extern "C" void kernel_launch(void* const* d_in, const int* in_sizes, int n_in,
                              void* d_out, int out_size, void* d_ws, size_t ws_size,
                              hipStream_t stream) {
  const float* x   = (const float*)d_in[0];
  const float* Wq  = (const float*)d_in[1];
  const float* Wk  = (const float*)d_in[2];
  const float* Wv  = (const float*)d_in[3];
  const float* Wo  = (const float*)d_in[4];
  const float* Wpq = (const float*)d_in[5];
  const float* Wpk = (const float*)d_in[6];

  char* ws = (char*)d_ws;
  u16* xb   = (u16*)(ws + 0);            // 16 MB  x bf16 [4096][2048]
  u16* Wqt  = (u16*)(ws + 16777216);     // 8 MB each, transposed bf16 (Wq,Wk,Wv contiguous)
  u16* Wkt  = (u16*)(ws + 25165824);
  u16* Wvt  = (u16*)(ws + 33554432);
  u16* Wot  = (u16*)(ws + 41943040);
  u16* Qb   = (u16*)(ws + 50331648);     // [b,h,s,d] bf16 (Q,K,V contiguous)
  u16* Kb   = (u16*)(ws + 67108864);
  u16* Vb   = (u16*)(ws + 83886080);     // V, later reused as ctx
  u16* Vt   = (u16*)(ws + 100663296);    // [b,h,d,s] bf16
  float* pq = (float*)(ws + 117440512);
  float* pk = (float*)(ws + 117702656);
  float* Ck = (float*)(ws + 117964800);
  float* Sk = (float*)(ws + 117964928);
  float* pm = (float*)(ws + 117965056);

  k_cvt_x<<<dim3(M_ROWS * D_DIM / 1024), 256, 0, stream>>>(x, xb);
  k_cvt_wt4<<<dim3(64, 64, 4), 256, 0, stream>>>(Wq, Wk, Wv, Wo, Wqt, Wkt, Wvt, Wot);

  // fused QKV: Bt = [Wqt;Wkt;Wvt] = [6144][2048], 128x256 tiles
  // grid 24x32 = 768 blocks -> 3 clean rounds at 1 block/CU
  k_qkv<<<dim3(24, 32), 512, 0, stream>>>(xb, Wqt, Qb);

  k_vtrans<<<dim3(64, 4, 32), 256, 0, stream>>>(Vb, Vt);

  k_phase_proj<<<dim3(256), 256, 0, stream>>>(xb, Wpq, Wpk, pq, pk);
  k_phase_ck<<<dim3(32), 256, 0, stream>>>(pk, Ck, Sk);
  k_phase_mod<<<dim3(16), 256, 0, stream>>>(pq, Ck, Sk, pm);

  k_attn<<<dim3(32, 16), 256, 0, stream>>>(Qb, Kb, Vt, Vb /*ctx*/);

  // O-proj: 128x256 tiles -> grid 8x32 = 256 blocks, one full round
  k_oproj<<<dim3(8, 32), 512, 0, stream>>>(Vb /*ctx*/, Wot, (void*)d_out, pm);
}

// Round 12
// 327.380 us; speedup vs baseline: 1.2164x; 1.0124x over previous
//
#include <hip/hip_runtime.h>
#include <hip/hip_bf16.h>

typedef __attribute__((ext_vector_type(8))) short short8;
typedef __attribute__((ext_vector_type(4))) float f32x4;
typedef __attribute__((ext_vector_type(16))) float f32x16;
typedef __attribute__((ext_vector_type(4))) int i32x4;
typedef unsigned short u16;

#define S_LEN 2048
#define D_DIM 2048
#define NHEAD 16
#define HDIM 128
#define M_ROWS 4096

#define MFMA(a,b,c) __builtin_amdgcn_mfma_f32_16x16x32_bf16(a,b,c,0,0,0)
#define MFMA32(a,b,c) __builtin_amdgcn_mfma_f32_32x32x16_bf16(a,b,c,0,0,0)

__device__ __forceinline__ u16 f2bf(float f) {
  union { float f; unsigned u; } v; v.f = f;
  unsigned r = v.u + 0x7fffu + ((v.u >> 16) & 1u);
  return (u16)(r >> 16);
}

__device__ __forceinline__ void async16(void* lds, const void* g) {
  __builtin_amdgcn_global_load_lds(
      (const __attribute__((address_space(1))) unsigned*)g,
      (__attribute__((address_space(3))) unsigned*)lds, 16, 0, 0);
}

__device__ __forceinline__ unsigned cvtpk(float lo, float hi) {
  unsigned r;
  asm("v_cvt_pk_bf16_f32 %0, %1, %2" : "=v"(r) : "v"(lo), "v"(hi));
  return r;
}
__device__ __forceinline__ void plswap(unsigned& x, unsigned& y) {
  asm("v_permlane32_swap_b32 %0, %1" : "+v"(x), "+v"(y));
}

// ---------------- x -> bf16 ----------------
__global__ void k_cvt_x(const float* __restrict__ x, u16* __restrict__ xb) {
  int i = blockIdx.x * 256 + threadIdx.x;
  float4 v = reinterpret_cast<const float4*>(x)[i];
  ushort4 o;
  o.x = f2bf(v.x); o.y = f2bf(v.y); o.z = f2bf(v.z); o.w = f2bf(v.w);
  reinterpret_cast<ushort4*>(xb)[i] = o;
}

// -------- 4x W[k][n] f32 -> Wt[n][k] bf16 (transpose+convert, fused) --------
__global__ void k_cvt_wt4(const float* __restrict__ W0, const float* __restrict__ W1,
                          const float* __restrict__ W2, const float* __restrict__ W3,
                          u16* __restrict__ T0, u16* __restrict__ T1,
                          u16* __restrict__ T2, u16* __restrict__ T3) {
  __shared__ u16 tile[32][33];
  const int z = blockIdx.z;
  const float* W = (z == 0) ? W0 : (z == 1) ? W1 : (z == 2) ? W2 : W3;
  u16* Wt = (z == 0) ? T0 : (z == 1) ? T1 : (z == 2) ? T2 : T3;
  int n0 = blockIdx.x * 32, k0 = blockIdx.y * 32;
  int tx = threadIdx.x & 31, ty = threadIdx.x >> 5;
#pragma unroll
  for (int i = 0; i < 4; i++)
    tile[ty + i * 8][tx] = f2bf(W[(size_t)(k0 + ty + i * 8) * D_DIM + n0 + tx]);
  __syncthreads();
#pragma unroll
  for (int i = 0; i < 4; i++)
    Wt[(size_t)(n0 + ty + i * 8) * D_DIM + k0 + tx] = tile[tx][ty + i * 8];
}

// ======== 4-phase dbuf GEMM (R9-proven): C = A[M][K] * Bt[N][K]^T ========
// Tile 128x256, BK=64 (2 K-subs), 8 waves (2M x 4N), wave tile 64x64.
// Phases = C-quadrants (0,0),(1,0),(1,1),(0,1). Units: u0 = A-mh0 + B-nh0
// (3 loads/thread), u1 = A-mh1 (1), u2 = B-nh1 (2). Double-buffered LDS
// (96KB); counted vmcnt {3,5,4} steady / {3,2,0} tail (in-order retirement
// proof). MODE 0: scatter Q,K bf16 into [b,h,s,hd]; V written DIRECTLY into
// Vt[b,h,d,s] (r-consecutive rows are s-consecutive -> ushort4 store).
// MODE 1: f32 row-major with phase factor.
template <int MODE>
__device__ __forceinline__ void gemm_body(const u16* __restrict__ A,
                                          const u16* __restrict__ Bt,
                                          void* __restrict__ outp,
                                          u16* __restrict__ Vt,
                                          const float* __restrict__ fac,
                                          char* lds) {
  constexpr int BUFSZ = 49152;  // A 2x8KB + B 2x16KB
  const int m0 = blockIdx.y * 128, n0 = blockIdx.x * 256;
  const int t = threadIdx.x;
  const int w = t >> 6, l = t & 63;
  const int wr = (w >> 2) * 64, wc = (w & 3) * 64;
  const int lr = l & 15, lq = l >> 4;
  const char* Ab = (const char*)A;
  const char* Bb = (const char*)Bt;

  f32x4 acc[4][4] = {};

  const int sub = w >> 2, ww = w & 3;
  const int abase = (ww & 1) * 16 + (ww >> 1) * 64;
  const int bbase = (w >> 1) * 64 + (w & 1) * 16;
  const int rr = l >> 2, sl = l & 3;

  auto stageA = [&](int tt, int nb, int mh) {
    const int base = abase + mh * 32;
    const int row = base + rr;
    async16(lds + nb * BUFSZ + sub * 8192 + base * 64,
            Ab + (size_t)(m0 + row) * 4096 + tt * 128 + sub * 64 +
                ((sl ^ ((row >> 1) & 3)) * 16));
  };
  auto stageB = [&](int tt, int nb, int nh) {
    const int base = bbase + nh * 32;
    const int row = base + rr;
#pragma unroll
    for (int j = 0; j < 2; j++)
      async16(lds + nb * BUFSZ + 16384 + j * 16384 + base * 64,
              Bb + (size_t)(n0 + row) * 4096 + tt * 128 + j * 64 +
                  ((sl ^ ((row >> 1) & 3)) * 16));
  };

  auto readA = [&](short8 af[2][2], int buf, int mh) {
#pragma unroll
    for (int mi = 0; mi < 2; mi++)
#pragma unroll
      for (int ks = 0; ks < 2; ks++) {
        const int row = wr + mh * 32 + mi * 16 + lr;
        af[mi][ks] = *reinterpret_cast<const short8*>(
            lds + buf * BUFSZ + ks * 8192 + row * 64 +
            ((lq ^ ((row >> 1) & 3)) * 16));
      }
  };
  auto readB = [&](short8 bf[2][2], int buf, int nh) {
#pragma unroll
    for (int ni = 0; ni < 2; ni++)
#pragma unroll
      for (int ks = 0; ks < 2; ks++) {
        const int row = wc + nh * 32 + ni * 16 + lr;
        bf[ni][ks] = *reinterpret_cast<const short8*>(
            lds + buf * BUFSZ + 16384 + ks * 16384 + row * 64 +
            ((lq ^ ((row >> 1) & 3)) * 16));
      }
  };

#define QUAD(AF, BF, MH, NH)                                                \
  {                                                                         \
    __builtin_amdgcn_s_setprio(1);                                          \
    _Pragma("unroll") for (int mi = 0; mi < 2; mi++)                        \
    _Pragma("unroll") for (int ni = 0; ni < 2; ni++)                        \
    _Pragma("unroll") for (int ks = 0; ks < 2; ks++)                        \
      acc[(MH)*2 + mi][(NH)*2 + ni] =                                       \
          MFMA(AF[mi][ks], BF[ni][ks], acc[(MH)*2 + mi][(NH)*2 + ni]);      \
    __builtin_amdgcn_s_setprio(0);                                          \
  }
#define VMW(N) asm volatile("s_waitcnt vmcnt(" #N ")" ::: "memory")
#define BAR()                         \
  do {                                \
    __builtin_amdgcn_s_barrier();     \
    asm volatile("" ::: "memory");    \
  } while (0)

  // prologue: u0, u1, u2 of tile 0 -> buf 0 (6 loads)
  stageA(0, 0, 0); stageB(0, 0, 0);
  stageA(0, 0, 1);
  stageB(0, 0, 1);

  short8 af0[2][2], af1[2][2], bfr[2][2];
  const int NT = D_DIM / 64;  // 32
  for (int tt = 0; tt < NT; tt++) {
    const int buf = tt & 1, nb = buf ^ 1;
    const bool pf = (tt + 1 < NT);
    // phase 0: (0,0); needs u0(t); stage u0(t+1)
    VMW(3); BAR();
    if (pf) { stageA(tt + 1, nb, 0); stageB(tt + 1, nb, 0); }
    readA(af0, buf, 0); readB(bfr, buf, 0);
    QUAD(af0, bfr, 0, 0);
    // phase 1: (1,0); needs u1(t); stage u1(t+1)
    if (pf) VMW(5); else VMW(2);
    BAR();
    if (pf) stageA(tt + 1, nb, 1);
    readA(af1, buf, 1);
    QUAD(af1, bfr, 1, 0);
    // phase 2: (1,1); needs u2(t); stage u2(t+1)
    if (pf) VMW(4); else VMW(0);
    BAR();
    if (pf) stageB(tt + 1, nb, 1);
    readB(bfr, buf, 1);
    QUAD(af1, bfr, 1, 1);
    // phase 3: (0,1); pure MFMA
    BAR();
    QUAD(af0, bfr, 0, 1);
  }
#undef QUAD
#undef VMW
#undef BAR

  // epilogue
#pragma unroll
  for (int gm = 0; gm < 4; gm++) {
#pragma unroll
    for (int gn = 0; gn < 4; gn++) {
      const int row0 = m0 + wr + gm * 16 + lq * 4;
      const int col = n0 + wc + gn * 16 + lr;
      if (MODE == 0) {
        if (col >= 4096) {  // V -> Vt[b,h,d,s] direct (s-consecutive r's)
          const int d = col & 127, hh = (col >> 7) & 15;
          const int bb = row0 >> 11, s0 = row0 & 2047;
          ushort4 v4;
          v4.x = f2bf(acc[gm][gn][0]);
          v4.y = f2bf(acc[gm][gn][1]);
          v4.z = f2bf(acc[gm][gn][2]);
          v4.w = f2bf(acc[gm][gn][3]);
          *reinterpret_cast<ushort4*>(
              Vt + (((size_t)(bb * NHEAD + hh) * HDIM + d) * S_LEN + s0)) = v4;
        } else {
#pragma unroll
          for (int r = 0; r < 4; r++) {
            const int row = row0 + r;
            const int mat = col >> 11;
            const int hh = (col >> 7) & 15;
            ((u16*)outp)[(size_t)mat * 8388608 +
                         (((size_t)((row >> 11) * NHEAD + hh)) * S_LEN + (row & 2047)) * HDIM +
                         (col & 127)] = f2bf(acc[gm][gn][r]);
          }
        }
      } else {
#pragma unroll
        for (int r = 0; r < 4; r++) {
          const int row = row0 + r;
          ((float*)outp)[(size_t)row * D_DIM + col] =
              acc[gm][gn][r] * (1.0f + 0.1f * fac[row]);
        }
      }
    }
  }
}

__global__ __launch_bounds__(512, 1) void k_qkv(const u16* __restrict__ A,
                                                const u16* __restrict__ Bt,
                                                void* __restrict__ outp,
                                                u16* __restrict__ Vt) {
  __shared__ __align__(16) char lds[2 * 49152];
  gemm_body<0>(A, Bt, outp, Vt, nullptr, lds);
}

__global__ __launch_bounds__(512, 1) void k_oproj(const u16* __restrict__ A,
                                                  const u16* __restrict__ Bt,
                                                  void* __restrict__ outp,
                                                  const float* __restrict__ fac) {
  __shared__ __align__(16) char lds[2 * 49152];
  gemm_body<1>(A, Bt, outp, nullptr, fac, lds);
}

// -------- phase projections pq/pk = xb @ Wpq / xb @ Wpk --------
__global__ __launch_bounds__(256) void k_phase_proj(const u16* __restrict__ xb,
                                                    const float* __restrict__ Wpq,
                                                    const float* __restrict__ Wpk,
                                                    float* __restrict__ pq,
                                                    float* __restrict__ pk) {
  __shared__ u16 xs[16][136];
  __shared__ float2 ws[128][16];
  const int t = threadIdx.x;
  const int m0 = blockIdx.x * 16;
  const int h = t & 15, r = t >> 4;
  float sq = 0.f, sk = 0.f;
  for (int kc = 0; kc < D_DIM; kc += 128) {
    *reinterpret_cast<short8*>(&xs[t >> 4][(t & 15) * 8]) =
        *reinterpret_cast<const short8*>(
            &xb[(size_t)(m0 + (t >> 4)) * D_DIM + kc + (t & 15) * 8]);
#pragma unroll
    for (int j = 0; j < 8; j++) {
      const int idx = j * 256 + t;
      const int k = idx >> 4, hh = idx & 15;
      ws[k][hh] = make_float2(Wpq[(size_t)(kc + k) * NHEAD + hh],
                              Wpk[(size_t)(kc + k) * NHEAD + hh]);
    }
    __syncthreads();
#pragma unroll
    for (int k8 = 0; k8 < 16; k8++) {
      const short8 x8 = *reinterpret_cast<const short8*>(&xs[r][k8 * 8]);
#pragma unroll
      for (int j = 0; j < 8; j++) {
        union { float f; unsigned u; } c;
        c.u = ((unsigned)(u16)x8[j]) << 16;
        const float2 wv = ws[k8 * 8 + j][h];
        sq += c.f * wv.x;
        sk += c.f * wv.y;
      }
    }
    __syncthreads();
  }
  pq[(size_t)(m0 + r) * NHEAD + h] = sq;
  pk[(size_t)(m0 + r) * NHEAD + h] = sk;
}

__device__ __forceinline__ float wave_sum(float v) {
  v += __shfl_xor(v, 1);  v += __shfl_xor(v, 2);  v += __shfl_xor(v, 4);
  v += __shfl_xor(v, 8);  v += __shfl_xor(v, 16); v += __shfl_xor(v, 32);
  return v;
}

// -------- Ck/Sk = sum_s cos/sin(pk) per (b,h) --------
__global__ void k_phase_ck(const float* __restrict__ pk, float* __restrict__ Ck,
                           float* __restrict__ Sk) {
  int bh = blockIdx.x, b = bh >> 4, h = bh & 15;
  float c = 0.f, s = 0.f;
  for (int ss = threadIdx.x; ss < S_LEN; ss += 256) {
    float v = pk[((size_t)b * S_LEN + ss) * NHEAD + h];
    c += cosf(v); s += sinf(v);
  }
  c = wave_sum(c); s = wave_sum(s);
  __shared__ float rc[4], rs[4];
  int wv = threadIdx.x >> 6;
  if ((threadIdx.x & 63) == 0) { rc[wv] = c; rs[wv] = s; }
  __syncthreads();
  if (threadIdx.x == 0) {
    Ck[bh] = rc[0] + rc[1] + rc[2] + rc[3];
    Sk[bh] = rs[0] + rs[1] + rs[2] + rs[3];
  }
}

// -------- phase_mod[m] --------
__global__ void k_phase_mod(const float* __restrict__ pq, const float* __restrict__ Ck,
                            const float* __restrict__ Sk, float* __restrict__ pm) {
  int m = blockIdx.x * 256 + threadIdx.x;
  int b = m >> 11;
  float a = 0.f;
#pragma unroll
  for (int h = 0; h < NHEAD; h++) {
    float v = pq[(size_t)m * NHEAD + h];
    a += cosf(v) * Ck[b * NHEAD + h] + sinf(v) * Sk[b * NHEAD + h];
  }
  pm[m] = a * (1.0f / (S_LEN * NHEAD));
}

// -------- causal flash attention: uniform-work two-pass blocks --------
// Block (bh, gp in 0..7) sequentially processes q-group g = 15-gp, then gp.
// Every block = (16-gp)+(gp+1) = 17 KV tiles -> perfectly uniform work,
// grid 32x8 = 256 blocks = 1/CU, zero tail. 4 warps x 32 q-rows per group.
// K/V double-buffered in LDS (XOR-swizzled); T13 defer-max (THR=8).
__global__ __launch_bounds__(256, 2) void k_attn(const u16* __restrict__ Q,
                                                 const u16* __restrict__ K,
                                                 const u16* __restrict__ Vt,
                                                 u16* __restrict__ ctx) {
  const int bh = blockIdx.x;
  const int gp = blockIdx.y;
  const int b = bh >> 4, h = bh & 15;
  const int t = threadIdx.x;
  const int w = t >> 6, l = t & 63;
  const int ln = l & 31, hi = l >> 5;
  const float scale = 0.08838834764831845f;

  const u16* Qp = Q + (size_t)bh * S_LEN * HDIM;
  const char* Kg = (const char*)(K + (size_t)bh * S_LEN * HDIM);
  const char* Vg = (const char*)(Vt + (size_t)bh * HDIM * S_LEN);

  __shared__ __align__(16) char Ks[2][16384];
  __shared__ __align__(16) char Vs[2][16384];

  auto stage = [&](int t64, int buf) {
    const int k0 = t64 * 64;
#pragma unroll
    for (int i = 0; i < 4; i++) {
      const int key = i * 16 + w * 4 + (l >> 4);
      async16(Ks[buf] + i * 4096 + w * 1024,
              Kg + (size_t)(k0 + key) * 256 + (((l & 15) * 16) ^ ((key & 15) << 4)));
      const int d = i * 32 + w * 8 + (l >> 3);
      async16(Vs[buf] + i * 4096 + w * 1024,
              Vg + (size_t)d * (S_LEN * 2) + k0 * 2 + (((l & 7) * 16) ^ ((d & 7) << 4)));
    }
  };

  for (int pass = 0; pass < 2; pass++) {
    const int g = (pass == 0) ? (15 - gp) : gp;  // heavy first
    const int q0w = g * 128 + w * 32;
    const int qq = q0w + ln;

    short8 qf[8];
#pragma unroll
    for (int c = 0; c < 8; c++)
      qf[c] = *reinterpret_cast<const short8*>(Qp + (size_t)qq * HDIM + c * 16 + hi * 8);

    f32x16 o[4];
#pragma unroll
    for (int ds = 0; ds < 4; ds++)
#pragma unroll
      for (int r = 0; r < 16; r++) o[ds][r] = 0.f;
    float mrun = -1e30f, lsum = 0.f;

    const int nt = (g + 1) * 2;
    stage(0, 0);
    for (int t64 = 0; t64 < nt; t64++) {
      const int buf = t64 & 1;
      const int k0 = t64 * 64;
      asm volatile("s_waitcnt vmcnt(0)" ::: "memory");
      __syncthreads();
      if (t64 + 1 < nt) stage(t64 + 1, buf ^ 1);
      if (k0 < q0w + 32) {
        f32x16 s[2];
#pragma unroll
        for (int ks = 0; ks < 2; ks++)
#pragma unroll
          for (int r = 0; r < 16; r++) s[ks][r] = 0.f;
        __builtin_amdgcn_s_setprio(1);
#pragma unroll
        for (int ks = 0; ks < 2; ks++) {
          const int key = ks * 32 + ln;
          const char* kb = Ks[buf] + key * 256;
          const unsigned swzk = (unsigned)((key & 15) << 4);
#pragma unroll
          for (int c = 0; c < 8; c++) {
            const short8 kf = *reinterpret_cast<const short8*>(
                kb + (((unsigned)(c * 32 + hi * 16)) ^ swzk));
            s[ks] = MFMA32(kf, qf[c], s[ks]);
          }
        }
        __builtin_amdgcn_s_setprio(0);
        float p[32];
        float mx = -1e30f;
#pragma unroll
        for (int ks = 0; ks < 2; ks++)
#pragma unroll
          for (int r = 0; r < 16; r++) {
            const int key = k0 + ks * 32 + (r & 3) + 8 * (r >> 2) + 4 * hi;
            const float v = (key <= qq) ? s[ks][r] * scale : -1e30f;
            p[ks * 16 + r] = v;
            mx = fmaxf(mx, v);
          }
        mx = fmaxf(mx, __shfl_xor(mx, 32));
        // T13 defer-max: only rescale when the tile max escapes the band
        if (!__all(mx <= mrun + 8.f)) {
          const float nm = fmaxf(mrun, mx);
          const float f = __expf(mrun - nm);
          lsum *= f;
#pragma unroll
          for (int ds = 0; ds < 4; ds++)
#pragma unroll
            for (int r = 0; r < 16; r++) o[ds][r] *= f;
          mrun = nm;
        }
        float rs = 0.f;
#pragma unroll
        for (int i = 0; i < 32; i++) { p[i] = __expf(p[i] - mrun); rs += p[i]; }
        rs += __shfl_xor(rs, 32);
        lsum += rs;
        short8 bfr[4];
#pragma unroll
        for (int sub = 0; sub < 2; sub++) {
#pragma unroll
          for (int half = 0; half < 2; half++) {
            const int pb = sub * 16 + half * 8;
            unsigned X1 = cvtpk(p[pb + 0], p[pb + 1]);
            unsigned X2 = cvtpk(p[pb + 2], p[pb + 3]);
            unsigned Y1 = cvtpk(p[pb + 4], p[pb + 5]);
            unsigned Y2 = cvtpk(p[pb + 6], p[pb + 7]);
            plswap(X1, Y1);
            plswap(X2, Y2);
            i32x4 bw;
            bw[0] = (int)X1; bw[1] = (int)X2; bw[2] = (int)Y1; bw[3] = (int)Y2;
            bfr[sub * 2 + half] = __builtin_bit_cast(short8, bw);
          }
        }
        __builtin_amdgcn_s_setprio(1);
#pragma unroll
        for (int ds = 0; ds < 4; ds++) {
          const int d = ds * 32 + ln;
          const char* vb = Vs[buf] + d * 128;
          const unsigned swzv = (unsigned)((d & 7) << 4);
#pragma unroll
          for (int slot = 0; slot < 4; slot++) {
            const short8 vf = *reinterpret_cast<const short8*>(
                vb + (((unsigned)(slot * 32 + hi * 16)) ^ swzv));
            o[ds] = MFMA32(vf, bfr[slot], o[ds]);
          }
        }
        __builtin_amdgcn_s_setprio(0);
      }
    }

    const float rl = 1.0f / lsum;
#pragma unroll
    for (int ds = 0; ds < 4; ds++) {
#pragma unroll
      for (int rq = 0; rq < 4; rq++) {
        const int d = ds * 32 + 8 * rq + 4 * hi;
        ushort4 pk4;
        pk4.x = f2bf(o[ds][rq * 4 + 0] * rl);
        pk4.y = f2bf(o[ds][rq * 4 + 1] * rl);
        pk4.z = f2bf(o[ds][rq * 4 + 2] * rl);
        pk4.w = f2bf(o[ds][rq * 4 + 3] * rl);
        *reinterpret_cast<ushort4*>(ctx + ((size_t)(b * S_LEN + qq)) * D_DIM + h * HDIM + d) = pk4;
      }
    }
    __syncthreads();  // LDS safe before next pass restages
  }
}

extern "C" void kernel_launch(void* const* d_in, const int* in_sizes, int n_in,
                              void* d_out, int out_size, void* d_ws, size_t ws_size,
                              hipStream_t stream) {
  const float* x   = (const float*)d_in[0];
  const float* Wq  = (const float*)d_in[1];
  const float* Wk  = (const float*)d_in[2];
  const float* Wv  = (const float*)d_in[3];
  const float* Wo  = (const float*)d_in[4];
  const float* Wpq = (const float*)d_in[5];
  const float* Wpk = (const float*)d_in[6];

  char* ws = (char*)d_ws;
  u16* xb   = (u16*)(ws + 0);            // 16 MB  x bf16 [4096][2048]
  u16* Wqt  = (u16*)(ws + 16777216);     // 8 MB each, transposed bf16 (Wq,Wk,Wv contiguous)
  u16* Wkt  = (u16*)(ws + 25165824);
  u16* Wvt  = (u16*)(ws + 33554432);
  u16* Wot  = (u16*)(ws + 41943040);
  u16* Qb   = (u16*)(ws + 50331648);     // [b,h,s,d] bf16 (Q,K contiguous)
  u16* Kb   = (u16*)(ws + 67108864);
  u16* Vb   = (u16*)(ws + 83886080);     // ctx buffer
  u16* Vt   = (u16*)(ws + 100663296);    // [b,h,d,s] bf16 (written by k_qkv)
  float* pq = (float*)(ws + 117440512);
  float* pk = (float*)(ws + 117702656);
  float* Ck = (float*)(ws + 117964800);
  float* Sk = (float*)(ws + 117964928);
  float* pm = (float*)(ws + 117965056);

  k_cvt_x<<<dim3(M_ROWS * D_DIM / 1024), 256, 0, stream>>>(x, xb);
  k_cvt_wt4<<<dim3(64, 64, 4), 256, 0, stream>>>(Wq, Wk, Wv, Wo, Wqt, Wkt, Wvt, Wot);

  // fused QKV: Bt = [Wqt;Wkt;Wvt] = [6144][2048], 128x256 tiles
  // grid 24x32 = 768 blocks -> 3 clean rounds; V written straight to Vt
  k_qkv<<<dim3(24, 32), 512, 0, stream>>>(xb, Wqt, Qb, Vt);

  k_phase_proj<<<dim3(256), 256, 0, stream>>>(xb, Wpq, Wpk, pq, pk);
  k_phase_ck<<<dim3(32), 256, 0, stream>>>(pk, Ck, Sk);
  k_phase_mod<<<dim3(16), 256, 0, stream>>>(pq, Ck, Sk, pm);

  // uniform-work attention: 256 blocks, 17 tiles each
  k_attn<<<dim3(32, 8), 256, 0, stream>>>(Qb, Kb, Vt, Vb /*ctx*/);

  // O-proj: 128x256 tiles -> grid 8x32 = 256 blocks, one full round
  k_oproj<<<dim3(8, 32), 512, 0, stream>>>(Vb /*ctx*/, Wot, (void*)d_out, pm);
}

// Round 13
// 326.763 us; speedup vs baseline: 1.2187x; 1.0019x over previous
//
#include <hip/hip_runtime.h>
#include <hip/hip_bf16.h>

typedef __attribute__((ext_vector_type(8))) short short8;
typedef __attribute__((ext_vector_type(4))) float f32x4;
typedef __attribute__((ext_vector_type(16))) float f32x16;
typedef __attribute__((ext_vector_type(4))) int i32x4;
typedef unsigned short u16;

#define S_LEN 2048
#define D_DIM 2048
#define NHEAD 16
#define HDIM 128
#define M_ROWS 4096

#define MFMA(a,b,c) __builtin_amdgcn_mfma_f32_16x16x32_bf16(a,b,c,0,0,0)
#define MFMA32(a,b,c) __builtin_amdgcn_mfma_f32_32x32x16_bf16(a,b,c,0,0,0)

__device__ __forceinline__ u16 f2bf(float f) {
  union { float f; unsigned u; } v; v.f = f;
  unsigned r = v.u + 0x7fffu + ((v.u >> 16) & 1u);
  return (u16)(r >> 16);
}

__device__ __forceinline__ void async16(void* lds, const void* g) {
  __builtin_amdgcn_global_load_lds(
      (const __attribute__((address_space(1))) unsigned*)g,
      (__attribute__((address_space(3))) unsigned*)lds, 16, 0, 0);
}

__device__ __forceinline__ unsigned cvtpk(float lo, float hi) {
  unsigned r;
  asm("v_cvt_pk_bf16_f32 %0, %1, %2" : "=v"(r) : "v"(lo), "v"(hi));
  return r;
}
__device__ __forceinline__ void plswap(unsigned& x, unsigned& y) {
  asm("v_permlane32_swap_b32 %0, %1" : "+v"(x), "+v"(y));
}

// ---------------- x -> bf16 ----------------
__global__ void k_cvt_x(const float* __restrict__ x, u16* __restrict__ xb) {
  int i = blockIdx.x * 256 + threadIdx.x;
  float4 v = reinterpret_cast<const float4*>(x)[i];
  ushort4 o;
  o.x = f2bf(v.x); o.y = f2bf(v.y); o.z = f2bf(v.z); o.w = f2bf(v.w);
  reinterpret_cast<ushort4*>(xb)[i] = o;
}

// -------- 4x W[k][n] f32 -> Wt[n][k] bf16 (transpose+convert, fused) --------
__global__ void k_cvt_wt4(const float* __restrict__ W0, const float* __restrict__ W1,
                          const float* __restrict__ W2, const float* __restrict__ W3,
                          u16* __restrict__ T0, u16* __restrict__ T1,
                          u16* __restrict__ T2, u16* __restrict__ T3) {
  __shared__ u16 tile[32][33];
  const int z = blockIdx.z;
  const float* W = (z == 0) ? W0 : (z == 1) ? W1 : (z == 2) ? W2 : W3;
  u16* Wt = (z == 0) ? T0 : (z == 1) ? T1 : (z == 2) ? T2 : T3;
  int n0 = blockIdx.x * 32, k0 = blockIdx.y * 32;
  int tx = threadIdx.x & 31, ty = threadIdx.x >> 5;
#pragma unroll
  for (int i = 0; i < 4; i++)
    tile[ty + i * 8][tx] = f2bf(W[(size_t)(k0 + ty + i * 8) * D_DIM + n0 + tx]);
  __syncthreads();
#pragma unroll
  for (int i = 0; i < 4; i++)
    Wt[(size_t)(n0 + ty + i * 8) * D_DIM + k0 + tx] = tile[tx][ty + i * 8];
}

// ======== 4-phase dbuf GEMM (R9-proven): C = A[M][K] * Bt[N][K]^T ========
// Tile 128x256, BK=64 (2 K-subs), 8 waves (2M x 4N), wave tile 64x64.
// Counted vmcnt {3,5,4} steady / {3,2,0} tail (in-order retirement proof).
// MODE 0: scatter Q,K bf16 into [b,h,s,hd]; V written DIRECTLY into
// Vt[b,h,d,s]. MODE 1: f32 row-major with phase factor.
template <int MODE>
__device__ __forceinline__ void gemm_body(const u16* __restrict__ A,
                                          const u16* __restrict__ Bt,
                                          void* __restrict__ outp,
                                          u16* __restrict__ Vt,
                                          const float* __restrict__ fac,
                                          char* lds) {
  constexpr int BUFSZ = 49152;  // A 2x8KB + B 2x16KB
  const int m0 = blockIdx.y * 128, n0 = blockIdx.x * 256;
  const int t = threadIdx.x;
  const int w = t >> 6, l = t & 63;
  const int wr = (w >> 2) * 64, wc = (w & 3) * 64;
  const int lr = l & 15, lq = l >> 4;
  const char* Ab = (const char*)A;
  const char* Bb = (const char*)Bt;

  f32x4 acc[4][4] = {};

  const int sub = w >> 2, ww = w & 3;
  const int abase = (ww & 1) * 16 + (ww >> 1) * 64;
  const int bbase = (w >> 1) * 64 + (w & 1) * 16;
  const int rr = l >> 2, sl = l & 3;

  auto stageA = [&](int tt, int nb, int mh) {
    const int base = abase + mh * 32;
    const int row = base + rr;
    async16(lds + nb * BUFSZ + sub * 8192 + base * 64,
            Ab + (size_t)(m0 + row) * 4096 + tt * 128 + sub * 64 +
                ((sl ^ ((row >> 1) & 3)) * 16));
  };
  auto stageB = [&](int tt, int nb, int nh) {
    const int base = bbase + nh * 32;
    const int row = base + rr;
#pragma unroll
    for (int j = 0; j < 2; j++)
      async16(lds + nb * BUFSZ + 16384 + j * 16384 + base * 64,
              Bb + (size_t)(n0 + row) * 4096 + tt * 128 + j * 64 +
                  ((sl ^ ((row >> 1) & 3)) * 16));
  };

  auto readA = [&](short8 af[2][2], int buf, int mh) {
#pragma unroll
    for (int mi = 0; mi < 2; mi++)
#pragma unroll
      for (int ks = 0; ks < 2; ks++) {
        const int row = wr + mh * 32 + mi * 16 + lr;
        af[mi][ks] = *reinterpret_cast<const short8*>(
            lds + buf * BUFSZ + ks * 8192 + row * 64 +
            ((lq ^ ((row >> 1) & 3)) * 16));
      }
  };
  auto readB = [&](short8 bf[2][2], int buf, int nh) {
#pragma unroll
    for (int ni = 0; ni < 2; ni++)
#pragma unroll
      for (int ks = 0; ks < 2; ks++) {
        const int row = wc + nh * 32 + ni * 16 + lr;
        bf[ni][ks] = *reinterpret_cast<const short8*>(
            lds + buf * BUFSZ + 16384 + ks * 16384 + row * 64 +
            ((lq ^ ((row >> 1) & 3)) * 16));
      }
  };

#define QUAD(AF, BF, MH, NH)                                                \
  {                                                                         \
    __builtin_amdgcn_s_setprio(1);                                          \
    _Pragma("unroll") for (int mi = 0; mi < 2; mi++)                        \
    _Pragma("unroll") for (int ni = 0; ni < 2; ni++)                        \
    _Pragma("unroll") for (int ks = 0; ks < 2; ks++)                        \
      acc[(MH)*2 + mi][(NH)*2 + ni] =                                       \
          MFMA(AF[mi][ks], BF[ni][ks], acc[(MH)*2 + mi][(NH)*2 + ni]);      \
    __builtin_amdgcn_s_setprio(0);                                          \
  }
#define VMW(N) asm volatile("s_waitcnt vmcnt(" #N ")" ::: "memory")
#define BAR()                         \
  do {                                \
    __builtin_amdgcn_s_barrier();     \
    asm volatile("" ::: "memory");    \
  } while (0)

  // prologue: u0, u1, u2 of tile 0 -> buf 0 (6 loads)
  stageA(0, 0, 0); stageB(0, 0, 0);
  stageA(0, 0, 1);
  stageB(0, 0, 1);

  short8 af0[2][2], af1[2][2], bfr[2][2];
  const int NT = D_DIM / 64;  // 32
  for (int tt = 0; tt < NT; tt++) {
    const int buf = tt & 1, nb = buf ^ 1;
    const bool pf = (tt + 1 < NT);
    // phase 0: (0,0); needs u0(t); stage u0(t+1)
    VMW(3); BAR();
    if (pf) { stageA(tt + 1, nb, 0); stageB(tt + 1, nb, 0); }
    readA(af0, buf, 0); readB(bfr, buf, 0);
    QUAD(af0, bfr, 0, 0);
    // phase 1: (1,0); needs u1(t); stage u1(t+1)
    if (pf) VMW(5); else VMW(2);
    BAR();
    if (pf) stageA(tt + 1, nb, 1);
    readA(af1, buf, 1);
    QUAD(af1, bfr, 1, 0);
    // phase 2: (1,1); needs u2(t); stage u2(t+1)
    if (pf) VMW(4); else VMW(0);
    BAR();
    if (pf) stageB(tt + 1, nb, 1);
    readB(bfr, buf, 1);
    QUAD(af1, bfr, 1, 1);
    // phase 3: (0,1); pure MFMA
    BAR();
    QUAD(af0, bfr, 0, 1);
  }
#undef QUAD
#undef VMW
#undef BAR

  // epilogue
#pragma unroll
  for (int gm = 0; gm < 4; gm++) {
#pragma unroll
    for (int gn = 0; gn < 4; gn++) {
      const int row0 = m0 + wr + gm * 16 + lq * 4;
      const int col = n0 + wc + gn * 16 + lr;
      if (MODE == 0) {
        if (col >= 4096) {  // V -> Vt[b,h,d,s] direct (s-consecutive r's)
          const int d = col & 127, hh = (col >> 7) & 15;
          const int bb = row0 >> 11, s0 = row0 & 2047;
          ushort4 v4;
          v4.x = f2bf(acc[gm][gn][0]);
          v4.y = f2bf(acc[gm][gn][1]);
          v4.z = f2bf(acc[gm][gn][2]);
          v4.w = f2bf(acc[gm][gn][3]);
          *reinterpret_cast<ushort4*>(
              Vt + (((size_t)(bb * NHEAD + hh) * HDIM + d) * S_LEN + s0)) = v4;
        } else {
#pragma unroll
          for (int r = 0; r < 4; r++) {
            const int row = row0 + r;
            const int mat = col >> 11;
            const int hh = (col >> 7) & 15;
            ((u16*)outp)[(size_t)mat * 8388608 +
                         (((size_t)((row >> 11) * NHEAD + hh)) * S_LEN + (row & 2047)) * HDIM +
                         (col & 127)] = f2bf(acc[gm][gn][r]);
          }
        }
      } else {
#pragma unroll
        for (int r = 0; r < 4; r++) {
          const int row = row0 + r;
          ((float*)outp)[(size_t)row * D_DIM + col] =
              acc[gm][gn][r] * (1.0f + 0.1f * fac[row]);
        }
      }
    }
  }
}

__global__ __launch_bounds__(512, 1) void k_qkv(const u16* __restrict__ A,
                                                const u16* __restrict__ Bt,
                                                void* __restrict__ outp,
                                                u16* __restrict__ Vt) {
  __shared__ __align__(16) char lds[2 * 49152];
  gemm_body<0>(A, Bt, outp, Vt, nullptr, lds);
}

__global__ __launch_bounds__(512, 1) void k_oproj(const u16* __restrict__ A,
                                                  const u16* __restrict__ Bt,
                                                  void* __restrict__ outp,
                                                  const float* __restrict__ fac) {
  __shared__ __align__(16) char lds[2 * 49152];
  gemm_body<1>(A, Bt, outp, nullptr, fac, lds);
}

// -------- phase projections pq/pk = xb @ Wpq / xb @ Wpk --------
__global__ __launch_bounds__(256) void k_phase_proj(const u16* __restrict__ xb,
                                                    const float* __restrict__ Wpq,
                                                    const float* __restrict__ Wpk,
                                                    float* __restrict__ pq,
                                                    float* __restrict__ pk) {
  __shared__ u16 xs[16][136];
  __shared__ float2 ws[128][16];
  const int t = threadIdx.x;
  const int m0 = blockIdx.x * 16;
  const int h = t & 15, r = t >> 4;
  float sq = 0.f, sk = 0.f;
  for (int kc = 0; kc < D_DIM; kc += 128) {
    *reinterpret_cast<short8*>(&xs[t >> 4][(t & 15) * 8]) =
        *reinterpret_cast<const short8*>(
            &xb[(size_t)(m0 + (t >> 4)) * D_DIM + kc + (t & 15) * 8]);
#pragma unroll
    for (int j = 0; j < 8; j++) {
      const int idx = j * 256 + t;
      const int k = idx >> 4, hh = idx & 15;
      ws[k][hh] = make_float2(Wpq[(size_t)(kc + k) * NHEAD + hh],
                              Wpk[(size_t)(kc + k) * NHEAD + hh]);
    }
    __syncthreads();
#pragma unroll
    for (int k8 = 0; k8 < 16; k8++) {
      const short8 x8 = *reinterpret_cast<const short8*>(&xs[r][k8 * 8]);
#pragma unroll
      for (int j = 0; j < 8; j++) {
        union { float f; unsigned u; } c;
        c.u = ((unsigned)(u16)x8[j]) << 16;
        const float2 wv = ws[k8 * 8 + j][h];
        sq += c.f * wv.x;
        sk += c.f * wv.y;
      }
    }
    __syncthreads();
  }
  pq[(size_t)(m0 + r) * NHEAD + h] = sq;
  pk[(size_t)(m0 + r) * NHEAD + h] = sk;
}

__device__ __forceinline__ float wave_sum(float v) {
  v += __shfl_xor(v, 1);  v += __shfl_xor(v, 2);  v += __shfl_xor(v, 4);
  v += __shfl_xor(v, 8);  v += __shfl_xor(v, 16); v += __shfl_xor(v, 32);
  return v;
}

// -------- Ck/Sk = sum_s cos/sin(pk) per (b,h) --------
__global__ void k_phase_ck(const float* __restrict__ pk, float* __restrict__ Ck,
                           float* __restrict__ Sk) {
  int bh = blockIdx.x, b = bh >> 4, h = bh & 15;
  float c = 0.f, s = 0.f;
  for (int ss = threadIdx.x; ss < S_LEN; ss += 256) {
    float v = pk[((size_t)b * S_LEN + ss) * NHEAD + h];
    c += cosf(v); s += sinf(v);
  }
  c = wave_sum(c); s = wave_sum(s);
  __shared__ float rc[4], rs[4];
  int wv = threadIdx.x >> 6;
  if ((threadIdx.x & 63) == 0) { rc[wv] = c; rs[wv] = s; }
  __syncthreads();
  if (threadIdx.x == 0) {
    Ck[bh] = rc[0] + rc[1] + rc[2] + rc[3];
    Sk[bh] = rs[0] + rs[1] + rs[2] + rs[3];
  }
}

// -------- phase_mod[m] --------
__global__ void k_phase_mod(const float* __restrict__ pq, const float* __restrict__ Ck,
                            const float* __restrict__ Sk, float* __restrict__ pm) {
  int m = blockIdx.x * 256 + threadIdx.x;
  int b = m >> 11;
  float a = 0.f;
#pragma unroll
  for (int h = 0; h < NHEAD; h++) {
    float v = pq[(size_t)m * NHEAD + h];
    a += cosf(v) * Ck[b * NHEAD + h] + sinf(v) * Sk[b * NHEAD + h];
  }
  pm[m] = a * (1.0f / (S_LEN * NHEAD));
}

// -------- causal flash attention: 4 warps x 32 q-rows, double-buffered K/V --------
// 512 blocks (32x16), pairing g = gy<8 ? 15-gy : gy-8: blocks c and c+256
// co-reside on one CU with g-sum 15 -> per-CU work uniform (17 tiles), 2
// blocks/CU = 8 waves/CU. exp2-domain softmax (scale folded with log2e);
// T13 defer-max band 11.0 (log2 units, = e^7.6); interior tiles skip masking.
__global__ __launch_bounds__(256, 2) void k_attn(const u16* __restrict__ Q,
                                                 const u16* __restrict__ K,
                                                 const u16* __restrict__ Vt,
                                                 u16* __restrict__ ctx) {
  const int bh = blockIdx.x;
  const int gy = blockIdx.y;
  const int g = (gy < 8) ? (15 - gy) : (gy - 8);
  const int b = bh >> 4, h = bh & 15;
  const int t = threadIdx.x;
  const int w = t >> 6, l = t & 63;
  const int ln = l & 31, hi = l >> 5;
  const int q0w = g * 128 + w * 32;
  const int qq = q0w + ln;
  const float sc2 = 0.08838834764831845f * 1.4426950408889634f;  // scale*log2e

  const u16* Qp = Q + (size_t)bh * S_LEN * HDIM;
  const char* Kg = (const char*)(K + (size_t)bh * S_LEN * HDIM);
  const char* Vg = (const char*)(Vt + (size_t)bh * HDIM * S_LEN);

  __shared__ __align__(16) char Ks[2][16384];
  __shared__ __align__(16) char Vs[2][16384];

  auto stage = [&](int t64, int buf) {
    const int k0 = t64 * 64;
#pragma unroll
    for (int i = 0; i < 4; i++) {
      const int key = i * 16 + w * 4 + (l >> 4);
      async16(Ks[buf] + i * 4096 + w * 1024,
              Kg + (size_t)(k0 + key) * 256 + (((l & 15) * 16) ^ ((key & 15) << 4)));
      const int d = i * 32 + w * 8 + (l >> 3);
      async16(Vs[buf] + i * 4096 + w * 1024,
              Vg + (size_t)d * (S_LEN * 2) + k0 * 2 + (((l & 7) * 16) ^ ((d & 7) << 4)));
    }
  };

  short8 qf[8];
#pragma unroll
  for (int c = 0; c < 8; c++)
    qf[c] = *reinterpret_cast<const short8*>(Qp + (size_t)qq * HDIM + c * 16 + hi * 8);

  f32x16 o[4];
#pragma unroll
  for (int ds = 0; ds < 4; ds++)
#pragma unroll
    for (int r = 0; r < 16; r++) o[ds][r] = 0.f;
  float mrun = -1e30f, lsum = 0.f;

  const int nt = (g + 1) * 2;
  stage(0, 0);
  for (int t64 = 0; t64 < nt; t64++) {
    const int buf = t64 & 1;
    const int k0 = t64 * 64;
    asm volatile("s_waitcnt vmcnt(0)" ::: "memory");
    __syncthreads();
    if (t64 + 1 < nt) stage(t64 + 1, buf ^ 1);
    if (k0 < q0w + 32) {
      f32x16 s[2];
#pragma unroll
      for (int ks = 0; ks < 2; ks++)
#pragma unroll
        for (int r = 0; r < 16; r++) s[ks][r] = 0.f;
      __builtin_amdgcn_s_setprio(1);
#pragma unroll
      for (int ks = 0; ks < 2; ks++) {
        const int key = ks * 32 + ln;
        const char* kb = Ks[buf] + key * 256;
        const unsigned swzk = (unsigned)((key & 15) << 4);
#pragma unroll
        for (int c = 0; c < 8; c++) {
          const short8 kf = *reinterpret_cast<const short8*>(
              kb + (((unsigned)(c * 32 + hi * 16)) ^ swzk));
          s[ks] = MFMA32(kf, qf[c], s[ks]);
        }
      }
      __builtin_amdgcn_s_setprio(0);
      float p[32];
      float mx = -1e30f;
      const bool interior = (k0 + 64 <= q0w + 1);  // all keys unmasked for warp
      if (interior) {
#pragma unroll
        for (int ks = 0; ks < 2; ks++)
#pragma unroll
          for (int r = 0; r < 16; r++) {
            const float v = s[ks][r] * sc2;
            p[ks * 16 + r] = v;
            mx = fmaxf(mx, v);
          }
      } else {
#pragma unroll
        for (int ks = 0; ks < 2; ks++)
#pragma unroll
          for (int r = 0; r < 16; r++) {
            const int key = k0 + ks * 32 + (r & 3) + 8 * (r >> 2) + 4 * hi;
            const float v = (key <= qq) ? s[ks][r] * sc2 : -1e30f;
            p[ks * 16 + r] = v;
            mx = fmaxf(mx, v);
          }
      }
      mx = fmaxf(mx, __shfl_xor(mx, 32));
      // T13 defer-max (log2 domain, band 11.0 ~ e^7.6)
      if (!__all(mx <= mrun + 11.0f)) {
        const float nm = fmaxf(mrun, mx);
        const float f = exp2f(mrun - nm);
        lsum *= f;
#pragma unroll
        for (int ds = 0; ds < 4; ds++)
#pragma unroll
          for (int r = 0; r < 16; r++) o[ds][r] *= f;
        mrun = nm;
      }
      float rs = 0.f;
#pragma unroll
      for (int i = 0; i < 32; i++) { p[i] = exp2f(p[i] - mrun); rs += p[i]; }
      rs += __shfl_xor(rs, 32);
      lsum += rs;
      short8 bfr[4];
#pragma unroll
      for (int sub = 0; sub < 2; sub++) {
#pragma unroll
        for (int half = 0; half < 2; half++) {
          const int pb = sub * 16 + half * 8;
          unsigned X1 = cvtpk(p[pb + 0], p[pb + 1]);
          unsigned X2 = cvtpk(p[pb + 2], p[pb + 3]);
          unsigned Y1 = cvtpk(p[pb + 4], p[pb + 5]);
          unsigned Y2 = cvtpk(p[pb + 6], p[pb + 7]);
          plswap(X1, Y1);
          plswap(X2, Y2);
          i32x4 bw;
          bw[0] = (int)X1; bw[1] = (int)X2; bw[2] = (int)Y1; bw[3] = (int)Y2;
          bfr[sub * 2 + half] = __builtin_bit_cast(short8, bw);
        }
      }
      __builtin_amdgcn_s_setprio(1);
#pragma unroll
      for (int ds = 0; ds < 4; ds++) {
        const int d = ds * 32 + ln;
        const char* vb = Vs[buf] + d * 128;
        const unsigned swzv = (unsigned)((d & 7) << 4);
#pragma unroll
        for (int slot = 0; slot < 4; slot++) {
          const short8 vf = *reinterpret_cast<const short8*>(
              vb + (((unsigned)(slot * 32 + hi * 16)) ^ swzv));
          o[ds] = MFMA32(vf, bfr[slot], o[ds]);
        }
      }
      __builtin_amdgcn_s_setprio(0);
    }
  }

  const float rl = 1.0f / lsum;
#pragma unroll
  for (int ds = 0; ds < 4; ds++) {
#pragma unroll
    for (int rq = 0; rq < 4; rq++) {
      const int d = ds * 32 + 8 * rq + 4 * hi;
      ushort4 pk4;
      pk4.x = f2bf(o[ds][rq * 4 + 0] * rl);
      pk4.y = f2bf(o[ds][rq * 4 + 1] * rl);
      pk4.z = f2bf(o[ds][rq * 4 + 2] * rl);
      pk4.w = f2bf(o[ds][rq * 4 + 3] * rl);
      *reinterpret_cast<ushort4*>(ctx + ((size_t)(b * S_LEN + qq)) * D_DIM + h * HDIM + d) = pk4;
    }
  }
}

extern "C" void kernel_launch(void* const* d_in, const int* in_sizes, int n_in,
                              void* d_out, int out_size, void* d_ws, size_t ws_size,
                              hipStream_t stream) {
  const float* x   = (const float*)d_in[0];
  const float* Wq  = (const float*)d_in[1];
  const float* Wk  = (const float*)d_in[2];
  const float* Wv  = (const float*)d_in[3];
  const float* Wo  = (const float*)d_in[4];
  const float* Wpq = (const float*)d_in[5];
  const float* Wpk = (const float*)d_in[6];

  char* ws = (char*)d_ws;
  u16* xb   = (u16*)(ws + 0);            // 16 MB  x bf16 [4096][2048]
  u16* Wqt  = (u16*)(ws + 16777216);     // 8 MB each, transposed bf16 (Wq,Wk,Wv contiguous)
  u16* Wkt  = (u16*)(ws + 25165824);
  u16* Wvt  = (u16*)(ws + 33554432);
  u16* Wot  = (u16*)(ws + 41943040);
  u16* Qb   = (u16*)(ws + 50331648);     // [b,h,s,d] bf16 (Q,K contiguous)
  u16* Kb   = (u16*)(ws + 67108864);
  u16* Vb   = (u16*)(ws + 83886080);     // ctx buffer
  u16* Vt   = (u16*)(ws + 100663296);    // [b,h,d,s] bf16 (written by k_qkv)
  float* pq = (float*)(ws + 117440512);
  float* pk = (float*)(ws + 117702656);
  float* Ck = (float*)(ws + 117964800);
  float* Sk = (float*)(ws + 117964928);
  float* pm = (float*)(ws + 117965056);

  k_cvt_x<<<dim3(M_ROWS * D_DIM / 1024), 256, 0, stream>>>(x, xb);
  k_cvt_wt4<<<dim3(64, 64, 4), 256, 0, stream>>>(Wq, Wk, Wv, Wo, Wqt, Wkt, Wvt, Wot);

  // fused QKV: Bt = [Wqt;Wkt;Wvt] = [6144][2048], 128x256 tiles
  // grid 24x32 = 768 blocks -> 3 clean rounds; V written straight to Vt
  k_qkv<<<dim3(24, 32), 512, 0, stream>>>(xb, Wqt, Qb, Vt);

  k_phase_proj<<<dim3(256), 256, 0, stream>>>(xb, Wpq, Wpk, pq, pk);
  k_phase_ck<<<dim3(32), 256, 0, stream>>>(pk, Ck, Sk);
  k_phase_mod<<<dim3(16), 256, 0, stream>>>(pq, Ck, Sk, pm);

  // attention: 512 blocks, per-CU-paired uniform work, 2 blocks/CU
  k_attn<<<dim3(32, 16), 256, 0, stream>>>(Qb, Kb, Vt, Vb /*ctx*/);

  // O-proj: 128x256 tiles -> grid 8x32 = 256 blocks, one full round
  k_oproj<<<dim3(8, 32), 512, 0, stream>>>(Vb /*ctx*/, Wot, (void*)d_out, pm);
}

// Round 14
// 325.659 us; speedup vs baseline: 1.2228x; 1.0034x over previous
//
#include <hip/hip_runtime.h>
#include <hip/hip_bf16.h>

typedef __attribute__((ext_vector_type(8))) short short8;
typedef __attribute__((ext_vector_type(4))) float f32x4;
typedef __attribute__((ext_vector_type(16))) float f32x16;
typedef __attribute__((ext_vector_type(4))) int i32x4;
typedef unsigned short u16;

#define S_LEN 2048
#define D_DIM 2048
#define NHEAD 16
#define HDIM 128
#define M_ROWS 4096

#define MFMA(a,b,c) __builtin_amdgcn_mfma_f32_16x16x32_bf16(a,b,c,0,0,0)
#define MFMA32(a,b,c) __builtin_amdgcn_mfma_f32_32x32x16_bf16(a,b,c,0,0,0)

__device__ __forceinline__ u16 f2bf(float f) {
  union { float f; unsigned u; } v; v.f = f;
  unsigned r = v.u + 0x7fffu + ((v.u >> 16) & 1u);
  return (u16)(r >> 16);
}

__device__ __forceinline__ void async16(void* lds, const void* g) {
  __builtin_amdgcn_global_load_lds(
      (const __attribute__((address_space(1))) unsigned*)g,
      (__attribute__((address_space(3))) unsigned*)lds, 16, 0, 0);
}

__device__ __forceinline__ unsigned cvtpk(float lo, float hi) {
  unsigned r;
  asm("v_cvt_pk_bf16_f32 %0, %1, %2" : "=v"(r) : "v"(lo), "v"(hi));
  return r;
}
__device__ __forceinline__ void plswap(unsigned& x, unsigned& y) {
  asm("v_permlane32_swap_b32 %0, %1" : "+v"(x), "+v"(y));
}

// ---- fused prep: z<4 -> transpose+convert W_z; z=4,5 -> convert x ----
__global__ __launch_bounds__(256) void k_prep(const float* __restrict__ W0,
                                              const float* __restrict__ W1,
                                              const float* __restrict__ W2,
                                              const float* __restrict__ W3,
                                              u16* __restrict__ T0, u16* __restrict__ T1,
                                              u16* __restrict__ T2, u16* __restrict__ T3,
                                              const float* __restrict__ x,
                                              u16* __restrict__ xb) {
  const int z = blockIdx.z;
  if (z < 4) {
    __shared__ u16 tile[32][33];
    const float* W = (z == 0) ? W0 : (z == 1) ? W1 : (z == 2) ? W2 : W3;
    u16* Wt = (z == 0) ? T0 : (z == 1) ? T1 : (z == 2) ? T2 : T3;
    int n0 = blockIdx.x * 32, k0 = blockIdx.y * 32;
    int tx = threadIdx.x & 31, ty = threadIdx.x >> 5;
#pragma unroll
    for (int i = 0; i < 4; i++)
      tile[ty + i * 8][tx] = f2bf(W[(size_t)(k0 + ty + i * 8) * D_DIM + n0 + tx]);
    __syncthreads();
#pragma unroll
    for (int i = 0; i < 4; i++)
      Wt[(size_t)(n0 + ty + i * 8) * D_DIM + k0 + tx] = tile[tx][ty + i * 8];
  } else {
    const int row0 = (z - 4) * 2048 + blockIdx.y * 32;
    const int col0 = blockIdx.x * 32;
    const int r = threadIdx.x >> 3, c4 = threadIdx.x & 7;
    const float4 v = *reinterpret_cast<const float4*>(
        &x[(size_t)(row0 + r) * D_DIM + col0 + c4 * 4]);
    ushort4 o;
    o.x = f2bf(v.x); o.y = f2bf(v.y); o.z = f2bf(v.z); o.w = f2bf(v.w);
    *reinterpret_cast<ushort4*>(&xb[(size_t)(row0 + r) * D_DIM + col0 + c4 * 4]) = o;
  }
}

// ======== 4-phase dbuf GEMM (R9-proven): C = A[M][K] * Bt[N][K]^T ========
// Tile 128x256, BK=64 (2 K-subs), 8 waves (2M x 4N), wave tile 64x64.
// Counted vmcnt {3,5,4} steady / {3,2,0} tail (in-order retirement proof).
// MODE 0: scatter Q,K bf16 into [b,h,s,hd]; V written DIRECTLY into
// Vt[b,h,d,s]. MODE 1: f32 row-major with phase factor.
template <int MODE>
__device__ __forceinline__ void gemm_body(const u16* __restrict__ A,
                                          const u16* __restrict__ Bt,
                                          void* __restrict__ outp,
                                          u16* __restrict__ Vt,
                                          const float* __restrict__ fac,
                                          char* lds) {
  constexpr int BUFSZ = 49152;  // A 2x8KB + B 2x16KB
  const int m0 = blockIdx.y * 128, n0 = blockIdx.x * 256;
  const int t = threadIdx.x;
  const int w = t >> 6, l = t & 63;
  const int wr = (w >> 2) * 64, wc = (w & 3) * 64;
  const int lr = l & 15, lq = l >> 4;
  const char* Ab = (const char*)A;
  const char* Bb = (const char*)Bt;

  f32x4 acc[4][4] = {};

  const int sub = w >> 2, ww = w & 3;
  const int abase = (ww & 1) * 16 + (ww >> 1) * 64;
  const int bbase = (w >> 1) * 64 + (w & 1) * 16;
  const int rr = l >> 2, sl = l & 3;

  auto stageA = [&](int tt, int nb, int mh) {
    const int base = abase + mh * 32;
    const int row = base + rr;
    async16(lds + nb * BUFSZ + sub * 8192 + base * 64,
            Ab + (size_t)(m0 + row) * 4096 + tt * 128 + sub * 64 +
                ((sl ^ ((row >> 1) & 3)) * 16));
  };
  auto stageB = [&](int tt, int nb, int nh) {
    const int base = bbase + nh * 32;
    const int row = base + rr;
#pragma unroll
    for (int j = 0; j < 2; j++)
      async16(lds + nb * BUFSZ + 16384 + j * 16384 + base * 64,
              Bb + (size_t)(n0 + row) * 4096 + tt * 128 + j * 64 +
                  ((sl ^ ((row >> 1) & 3)) * 16));
  };

  auto readA = [&](short8 af[2][2], int buf, int mh) {
#pragma unroll
    for (int mi = 0; mi < 2; mi++)
#pragma unroll
      for (int ks = 0; ks < 2; ks++) {
        const int row = wr + mh * 32 + mi * 16 + lr;
        af[mi][ks] = *reinterpret_cast<const short8*>(
            lds + buf * BUFSZ + ks * 8192 + row * 64 +
            ((lq ^ ((row >> 1) & 3)) * 16));
      }
  };
  auto readB = [&](short8 bf[2][2], int buf, int nh) {
#pragma unroll
    for (int ni = 0; ni < 2; ni++)
#pragma unroll
      for (int ks = 0; ks < 2; ks++) {
        const int row = wc + nh * 32 + ni * 16 + lr;
        bf[ni][ks] = *reinterpret_cast<const short8*>(
            lds + buf * BUFSZ + 16384 + ks * 16384 + row * 64 +
            ((lq ^ ((row >> 1) & 3)) * 16));
      }
  };

#define QUAD(AF, BF, MH, NH)                                                \
  {                                                                         \
    __builtin_amdgcn_s_setprio(1);                                          \
    _Pragma("unroll") for (int mi = 0; mi < 2; mi++)                        \
    _Pragma("unroll") for (int ni = 0; ni < 2; ni++)                        \
    _Pragma("unroll") for (int ks = 0; ks < 2; ks++)                        \
      acc[(MH)*2 + mi][(NH)*2 + ni] =                                       \
          MFMA(AF[mi][ks], BF[ni][ks], acc[(MH)*2 + mi][(NH)*2 + ni]);      \
    __builtin_amdgcn_s_setprio(0);                                          \
  }
#define VMW(N) asm volatile("s_waitcnt vmcnt(" #N ")" ::: "memory")
#define BAR()                         \
  do {                                \
    __builtin_amdgcn_s_barrier();     \
    asm volatile("" ::: "memory");    \
  } while (0)

  // prologue: u0, u1, u2 of tile 0 -> buf 0 (6 loads)
  stageA(0, 0, 0); stageB(0, 0, 0);
  stageA(0, 0, 1);
  stageB(0, 0, 1);

  short8 af0[2][2], af1[2][2], bfr[2][2];
  const int NT = D_DIM / 64;  // 32
  for (int tt = 0; tt < NT; tt++) {
    const int buf = tt & 1, nb = buf ^ 1;
    const bool pf = (tt + 1 < NT);
    // phase 0: (0,0); needs u0(t); stage u0(t+1)
    VMW(3); BAR();
    if (pf) { stageA(tt + 1, nb, 0); stageB(tt + 1, nb, 0); }
    readA(af0, buf, 0); readB(bfr, buf, 0);
    QUAD(af0, bfr, 0, 0);
    // phase 1: (1,0); needs u1(t); stage u1(t+1)
    if (pf) VMW(5); else VMW(2);
    BAR();
    if (pf) stageA(tt + 1, nb, 1);
    readA(af1, buf, 1);
    QUAD(af1, bfr, 1, 0);
    // phase 2: (1,1); needs u2(t); stage u2(t+1)
    if (pf) VMW(4); else VMW(0);
    BAR();
    if (pf) stageB(tt + 1, nb, 1);
    readB(bfr, buf, 1);
    QUAD(af1, bfr, 1, 1);
    // phase 3: (0,1); pure MFMA
    BAR();
    QUAD(af0, bfr, 0, 1);
  }
#undef QUAD
#undef VMW
#undef BAR

  // epilogue
#pragma unroll
  for (int gm = 0; gm < 4; gm++) {
#pragma unroll
    for (int gn = 0; gn < 4; gn++) {
      const int row0 = m0 + wr + gm * 16 + lq * 4;
      const int col = n0 + wc + gn * 16 + lr;
      if (MODE == 0) {
        if (col >= 4096) {  // V -> Vt[b,h,d,s] direct (s-consecutive r's)
          const int d = col & 127, hh = (col >> 7) & 15;
          const int bb = row0 >> 11, s0 = row0 & 2047;
          ushort4 v4;
          v4.x = f2bf(acc[gm][gn][0]);
          v4.y = f2bf(acc[gm][gn][1]);
          v4.z = f2bf(acc[gm][gn][2]);
          v4.w = f2bf(acc[gm][gn][3]);
          *reinterpret_cast<ushort4*>(
              Vt + (((size_t)(bb * NHEAD + hh) * HDIM + d) * S_LEN + s0)) = v4;
        } else {
#pragma unroll
          for (int r = 0; r < 4; r++) {
            const int row = row0 + r;
            const int mat = col >> 11;
            const int hh = (col >> 7) & 15;
            ((u16*)outp)[(size_t)mat * 8388608 +
                         (((size_t)((row >> 11) * NHEAD + hh)) * S_LEN + (row & 2047)) * HDIM +
                         (col & 127)] = f2bf(acc[gm][gn][r]);
          }
        }
      } else {
#pragma unroll
        for (int r = 0; r < 4; r++) {
          const int row = row0 + r;
          ((float*)outp)[(size_t)row * D_DIM + col] =
              acc[gm][gn][r] * (1.0f + 0.1f * fac[row]);
        }
      }
    }
  }
}

__global__ __launch_bounds__(512, 1) void k_qkv(const u16* __restrict__ A,
                                                const u16* __restrict__ Bt,
                                                void* __restrict__ outp,
                                                u16* __restrict__ Vt) {
  __shared__ __align__(16) char lds[2 * 49152];
  gemm_body<0>(A, Bt, outp, Vt, nullptr, lds);
}

__global__ __launch_bounds__(512, 1) void k_oproj(const u16* __restrict__ A,
                                                  const u16* __restrict__ Bt,
                                                  void* __restrict__ outp,
                                                  const float* __restrict__ fac) {
  __shared__ __align__(16) char lds[2 * 49152];
  gemm_body<1>(A, Bt, outp, nullptr, fac, lds);
}

// -------- phase projections pq/pk = xb @ Wpq / xb @ Wpk --------
__global__ __launch_bounds__(256) void k_phase_proj(const u16* __restrict__ xb,
                                                    const float* __restrict__ Wpq,
                                                    const float* __restrict__ Wpk,
                                                    float* __restrict__ pq,
                                                    float* __restrict__ pk) {
  __shared__ u16 xs[16][136];
  __shared__ float2 ws[128][16];
  const int t = threadIdx.x;
  const int m0 = blockIdx.x * 16;
  const int h = t & 15, r = t >> 4;
  float sq = 0.f, sk = 0.f;
  for (int kc = 0; kc < D_DIM; kc += 128) {
    *reinterpret_cast<short8*>(&xs[t >> 4][(t & 15) * 8]) =
        *reinterpret_cast<const short8*>(
            &xb[(size_t)(m0 + (t >> 4)) * D_DIM + kc + (t & 15) * 8]);
#pragma unroll
    for (int j = 0; j < 8; j++) {
      const int idx = j * 256 + t;
      const int k = idx >> 4, hh = idx & 15;
      ws[k][hh] = make_float2(Wpq[(size_t)(kc + k) * NHEAD + hh],
                              Wpk[(size_t)(kc + k) * NHEAD + hh]);
    }
    __syncthreads();
#pragma unroll
    for (int k8 = 0; k8 < 16; k8++) {
      const short8 x8 = *reinterpret_cast<const short8*>(&xs[r][k8 * 8]);
#pragma unroll
      for (int j = 0; j < 8; j++) {
        union { float f; unsigned u; } c;
        c.u = ((unsigned)(u16)x8[j]) << 16;
        const float2 wv = ws[k8 * 8 + j][h];
        sq += c.f * wv.x;
        sk += c.f * wv.y;
      }
    }
    __syncthreads();
  }
  pq[(size_t)(m0 + r) * NHEAD + h] = sq;
  pk[(size_t)(m0 + r) * NHEAD + h] = sk;
}

__device__ __forceinline__ float wave_sum(float v) {
  v += __shfl_xor(v, 1);  v += __shfl_xor(v, 2);  v += __shfl_xor(v, 4);
  v += __shfl_xor(v, 8);  v += __shfl_xor(v, 16); v += __shfl_xor(v, 32);
  return v;
}

// -------- Ck/Sk = sum_s cos/sin(pk) per (b,h) --------
__global__ void k_phase_ck(const float* __restrict__ pk, float* __restrict__ Ck,
                           float* __restrict__ Sk) {
  int bh = blockIdx.x, b = bh >> 4, h = bh & 15;
  float c = 0.f, s = 0.f;
  for (int ss = threadIdx.x; ss < S_LEN; ss += 256) {
    float v = pk[((size_t)b * S_LEN + ss) * NHEAD + h];
    c += cosf(v); s += sinf(v);
  }
  c = wave_sum(c); s = wave_sum(s);
  __shared__ float rc[4], rs[4];
  int wv = threadIdx.x >> 6;
  if ((threadIdx.x & 63) == 0) { rc[wv] = c; rs[wv] = s; }
  __syncthreads();
  if (threadIdx.x == 0) {
    Ck[bh] = rc[0] + rc[1] + rc[2] + rc[3];
    Sk[bh] = rs[0] + rs[1] + rs[2] + rs[3];
  }
}

// -------- phase_mod[m] --------
__global__ void k_phase_mod(const float* __restrict__ pq, const float* __restrict__ Ck,
                            const float* __restrict__ Sk, float* __restrict__ pm) {
  int m = blockIdx.x * 256 + threadIdx.x;
  int b = m >> 11;
  float a = 0.f;
#pragma unroll
  for (int h = 0; h < NHEAD; h++) {
    float v = pq[(size_t)m * NHEAD + h];
    a += cosf(v) * Ck[b * NHEAD + h] + sinf(v) * Sk[b * NHEAD + h];
  }
  pm[m] = a * (1.0f / (S_LEN * NHEAD));
}

// -------- causal flash attention: merged-pair 8-warp blocks --------
// Grid 32 x 8, 512 threads. Warps 0-3 own q-group gHi = 15-gp; warps 4-7 own
// gLo = gp (per-warp 32 q-rows). ONE shared K/V double-buffer staged once for
// the union range (nt = (16-gp)*2 tiles) -- previously the paired 4-warp
// blocks staged the same bh's tiles twice. Low warps early-out per-warp.
// exp2-domain softmax, T13 defer-max (band 11.0 log2), interior fast path.
__global__ __launch_bounds__(512, 1) void k_attn(const u16* __restrict__ Q,
                                                 const u16* __restrict__ K,
                                                 const u16* __restrict__ Vt,
                                                 u16* __restrict__ ctx) {
  const int bh = blockIdx.x;
  const int gp = blockIdx.y;
  const int b = bh >> 4, h = bh & 15;
  const int t = threadIdx.x;
  const int w8 = t >> 6, l = t & 63;
  const int wl = w8 & 3;
  const int g = (w8 < 4) ? (15 - gp) : gp;
  const int ln = l & 31, hi = l >> 5;
  const int q0w = g * 128 + wl * 32;
  const int qq = q0w + ln;
  const float sc2 = 0.08838834764831845f * 1.4426950408889634f;  // scale*log2e

  const u16* Qp = Q + (size_t)bh * S_LEN * HDIM;
  const char* Kg = (const char*)(K + (size_t)bh * S_LEN * HDIM);
  const char* Vg = (const char*)(Vt + (size_t)bh * HDIM * S_LEN);

  __shared__ __align__(16) char Ks[2][16384];
  __shared__ __align__(16) char Vs[2][16384];

  // 8-warp staging: K key = i*32 + w8*4 + (l>>4); V d = i*64 + w8*8 + (l>>3)
  auto stage = [&](int t64, int buf) {
    const int k0 = t64 * 64;
#pragma unroll
    for (int i = 0; i < 2; i++) {
      const int key = i * 32 + w8 * 4 + (l >> 4);
      async16(Ks[buf] + i * 8192 + w8 * 1024,
              Kg + (size_t)(k0 + key) * 256 + (((l & 15) * 16) ^ ((key & 15) << 4)));
      const int d = i * 64 + w8 * 8 + (l >> 3);
      async16(Vs[buf] + i * 8192 + w8 * 1024,
              Vg + (size_t)d * (S_LEN * 2) + k0 * 2 + (((l & 7) * 16) ^ ((d & 7) << 4)));
    }
  };

  short8 qf[8];
#pragma unroll
  for (int c = 0; c < 8; c++)
    qf[c] = *reinterpret_cast<const short8*>(Qp + (size_t)qq * HDIM + c * 16 + hi * 8);

  f32x16 o[4];
#pragma unroll
  for (int ds = 0; ds < 4; ds++)
#pragma unroll
    for (int r = 0; r < 16; r++) o[ds][r] = 0.f;
  float mrun = -1e30f, lsum = 0.f;

  const int nt = (16 - gp) * 2;  // union range (= high group's need)
  stage(0, 0);
  for (int t64 = 0; t64 < nt; t64++) {
    const int buf = t64 & 1;
    const int k0 = t64 * 64;
    asm volatile("s_waitcnt vmcnt(0)" ::: "memory");
    __syncthreads();
    if (t64 + 1 < nt) stage(t64 + 1, buf ^ 1);
    if (k0 < q0w + 32) {
      f32x16 s[2];
#pragma unroll
      for (int ks = 0; ks < 2; ks++)
#pragma unroll
        for (int r = 0; r < 16; r++) s[ks][r] = 0.f;
      __builtin_amdgcn_s_setprio(1);
#pragma unroll
      for (int ks = 0; ks < 2; ks++) {
        const int key = ks * 32 + ln;
        const char* kb = Ks[buf] + key * 256;
        const unsigned swzk = (unsigned)((key & 15) << 4);
#pragma unroll
        for (int c = 0; c < 8; c++) {
          const short8 kf = *reinterpret_cast<const short8*>(
              kb + (((unsigned)(c * 32 + hi * 16)) ^ swzk));
          s[ks] = MFMA32(kf, qf[c], s[ks]);
        }
      }
      __builtin_amdgcn_s_setprio(0);
      float p[32];
      float mx = -1e30f;
      const bool interior = (k0 + 64 <= q0w + 1);
      if (interior) {
#pragma unroll
        for (int ks = 0; ks < 2; ks++)
#pragma unroll
          for (int r = 0; r < 16; r++) {
            const float v = s[ks][r] * sc2;
            p[ks * 16 + r] = v;
            mx = fmaxf(mx, v);
          }
      } else {
#pragma unroll
        for (int ks = 0; ks < 2; ks++)
#pragma unroll
          for (int r = 0; r < 16; r++) {
            const int key = k0 + ks * 32 + (r & 3) + 8 * (r >> 2) + 4 * hi;
            const float v = (key <= qq) ? s[ks][r] * sc2 : -1e30f;
            p[ks * 16 + r] = v;
            mx = fmaxf(mx, v);
          }
      }
      mx = fmaxf(mx, __shfl_xor(mx, 32));
      if (!__all(mx <= mrun + 11.0f)) {
        const float nm = fmaxf(mrun, mx);
        const float f = exp2f(mrun - nm);
        lsum *= f;
#pragma unroll
        for (int ds = 0; ds < 4; ds++)
#pragma unroll
          for (int r = 0; r < 16; r++) o[ds][r] *= f;
        mrun = nm;
      }
      float rs = 0.f;
#pragma unroll
      for (int i = 0; i < 32; i++) { p[i] = exp2f(p[i] - mrun); rs += p[i]; }
      rs += __shfl_xor(rs, 32);
      lsum += rs;
      short8 bfr[4];
#pragma unroll
      for (int sub = 0; sub < 2; sub++) {
#pragma unroll
        for (int half = 0; half < 2; half++) {
          const int pb = sub * 16 + half * 8;
          unsigned X1 = cvtpk(p[pb + 0], p[pb + 1]);
          unsigned X2 = cvtpk(p[pb + 2], p[pb + 3]);
          unsigned Y1 = cvtpk(p[pb + 4], p[pb + 5]);
          unsigned Y2 = cvtpk(p[pb + 6], p[pb + 7]);
          plswap(X1, Y1);
          plswap(X2, Y2);
          i32x4 bw;
          bw[0] = (int)X1; bw[1] = (int)X2; bw[2] = (int)Y1; bw[3] = (int)Y2;
          bfr[sub * 2 + half] = __builtin_bit_cast(short8, bw);
        }
      }
      __builtin_amdgcn_s_setprio(1);
#pragma unroll
      for (int ds = 0; ds < 4; ds++) {
        const int d = ds * 32 + ln;
        const char* vb = Vs[buf] + d * 128;
        const unsigned swzv = (unsigned)((d & 7) << 4);
#pragma unroll
        for (int slot = 0; slot < 4; slot++) {
          const short8 vf = *reinterpret_cast<const short8*>(
              vb + (((unsigned)(slot * 32 + hi * 16)) ^ swzv));
          o[ds] = MFMA32(vf, bfr[slot], o[ds]);
        }
      }
      __builtin_amdgcn_s_setprio(0);
    }
  }

  const float rl = 1.0f / lsum;
#pragma unroll
  for (int ds = 0; ds < 4; ds++) {
#pragma unroll
    for (int rq = 0; rq < 4; rq++) {
      const int d = ds * 32 + 8 * rq + 4 * hi;
      ushort4 pk4;
      pk4.x = f2bf(o[ds][rq * 4 + 0] * rl);
      pk4.y = f2bf(o[ds][rq * 4 + 1] * rl);
      pk4.z = f2bf(o[ds][rq * 4 + 2] * rl);
      pk4.w = f2bf(o[ds][rq * 4 + 3] * rl);
      *reinterpret_cast<ushort4*>(ctx + ((size_t)(b * S_LEN + qq)) * D_DIM + h * HDIM + d) = pk4;
    }
  }
}

extern "C" void kernel_launch(void* const* d_in, const int* in_sizes, int n_in,
                              void* d_out, int out_size, void* d_ws, size_t ws_size,
                              hipStream_t stream) {
  const float* x   = (const float*)d_in[0];
  const float* Wq  = (const float*)d_in[1];
  const float* Wk  = (const float*)d_in[2];
  const float* Wv  = (const float*)d_in[3];
  const float* Wo  = (const float*)d_in[4];
  const float* Wpq = (const float*)d_in[5];
  const float* Wpk = (const float*)d_in[6];

  char* ws = (char*)d_ws;
  u16* xb   = (u16*)(ws + 0);            // 16 MB  x bf16 [4096][2048]
  u16* Wqt  = (u16*)(ws + 16777216);     // 8 MB each, transposed bf16 (Wq,Wk,Wv contiguous)
  u16* Wkt  = (u16*)(ws + 25165824);
  u16* Wvt  = (u16*)(ws + 33554432);
  u16* Wot  = (u16*)(ws + 41943040);
  u16* Qb   = (u16*)(ws + 50331648);     // [b,h,s,d] bf16 (Q,K contiguous)
  u16* Kb   = (u16*)(ws + 67108864);
  u16* Vb   = (u16*)(ws + 83886080);     // ctx buffer
  u16* Vt   = (u16*)(ws + 100663296);    // [b,h,d,s] bf16 (written by k_qkv)
  float* pq = (float*)(ws + 117440512);
  float* pk = (float*)(ws + 117702656);
  float* Ck = (float*)(ws + 117964800);
  float* Sk = (float*)(ws + 117964928);
  float* pm = (float*)(ws + 117965056);

  // fused prep: 4 weight transposes + x convert in one launch
  k_prep<<<dim3(64, 64, 6), 256, 0, stream>>>(Wq, Wk, Wv, Wo, Wqt, Wkt, Wvt, Wot, x, xb);

  // fused QKV: Bt = [Wqt;Wkt;Wvt] = [6144][2048], 128x256 tiles
  // grid 24x32 = 768 blocks -> 3 clean rounds; V written straight to Vt
  k_qkv<<<dim3(24, 32), 512, 0, stream>>>(xb, Wqt, Qb, Vt);

  k_phase_proj<<<dim3(256), 256, 0, stream>>>(xb, Wpq, Wpk, pq, pk);
  k_phase_ck<<<dim3(32), 256, 0, stream>>>(pk, Ck, Sk);
  k_phase_mod<<<dim3(16), 256, 0, stream>>>(pq, Ck, Sk, pm);

  // merged-pair attention: 256 blocks x 8 warps, shared staging
  k_attn<<<dim3(32, 8), 512, 0, stream>>>(Qb, Kb, Vt, Vb /*ctx*/);

  // O-proj: 128x256 tiles -> grid 8x32 = 256 blocks, one full round
  k_oproj<<<dim3(8, 32), 512, 0, stream>>>(Vb /*ctx*/, Wot, (void*)d_out, pm);
}

// Round 15
// 321.961 us; speedup vs baseline: 1.2369x; 1.0115x over previous
//
#include <hip/hip_runtime.h>
#include <hip/hip_bf16.h>

typedef __attribute__((ext_vector_type(8))) short short8;
typedef __attribute__((ext_vector_type(4))) float f32x4;
typedef __attribute__((ext_vector_type(16))) float f32x16;
typedef __attribute__((ext_vector_type(4))) int i32x4;
typedef unsigned short u16;

#define S_LEN 2048
#define D_DIM 2048
#define NHEAD 16
#define HDIM 128
#define M_ROWS 4096

#define MFMA(a,b,c) __builtin_amdgcn_mfma_f32_16x16x32_bf16(a,b,c,0,0,0)
#define MFMA32(a,b,c) __builtin_amdgcn_mfma_f32_32x32x16_bf16(a,b,c,0,0,0)

__device__ __forceinline__ u16 f2bf(float f) {
  union { float f; unsigned u; } v; v.f = f;
  unsigned r = v.u + 0x7fffu + ((v.u >> 16) & 1u);
  return (u16)(r >> 16);
}

__device__ __forceinline__ void async16(void* lds, const void* g) {
  __builtin_amdgcn_global_load_lds(
      (const __attribute__((address_space(1))) unsigned*)g,
      (__attribute__((address_space(3))) unsigned*)lds, 16, 0, 0);
}

__device__ __forceinline__ unsigned cvtpk(float lo, float hi) {
  unsigned r;
  asm("v_cvt_pk_bf16_f32 %0, %1, %2" : "=v"(r) : "v"(lo), "v"(hi));
  return r;
}
__device__ __forceinline__ void plswap(unsigned& x, unsigned& y) {
  asm("v_permlane32_swap_b32 %0, %1" : "+v"(x), "+v"(y));
}

// ---- fused prep: z<4 -> transpose+convert W_z; z=4,5 -> convert x ----
__global__ __launch_bounds__(256) void k_prep(const float* __restrict__ W0,
                                              const float* __restrict__ W1,
                                              const float* __restrict__ W2,
                                              const float* __restrict__ W3,
                                              u16* __restrict__ T0, u16* __restrict__ T1,
                                              u16* __restrict__ T2, u16* __restrict__ T3,
                                              const float* __restrict__ x,
                                              u16* __restrict__ xb) {
  const int z = blockIdx.z;
  if (z < 4) {
    __shared__ u16 tile[32][33];
    const float* W = (z == 0) ? W0 : (z == 1) ? W1 : (z == 2) ? W2 : W3;
    u16* Wt = (z == 0) ? T0 : (z == 1) ? T1 : (z == 2) ? T2 : T3;
    int n0 = blockIdx.x * 32, k0 = blockIdx.y * 32;
    int tx = threadIdx.x & 31, ty = threadIdx.x >> 5;
#pragma unroll
    for (int i = 0; i < 4; i++)
      tile[ty + i * 8][tx] = f2bf(W[(size_t)(k0 + ty + i * 8) * D_DIM + n0 + tx]);
    __syncthreads();
#pragma unroll
    for (int i = 0; i < 4; i++)
      Wt[(size_t)(n0 + ty + i * 8) * D_DIM + k0 + tx] = tile[tx][ty + i * 8];
  } else {
    const int row0 = (z - 4) * 2048 + blockIdx.y * 32;
    const int col0 = blockIdx.x * 32;
    const int r = threadIdx.x >> 3, c4 = threadIdx.x & 7;
    const float4 v = *reinterpret_cast<const float4*>(
        &x[(size_t)(row0 + r) * D_DIM + col0 + c4 * 4]);
    ushort4 o;
    o.x = f2bf(v.x); o.y = f2bf(v.y); o.z = f2bf(v.z); o.w = f2bf(v.w);
    *reinterpret_cast<ushort4*>(&xb[(size_t)(row0 + r) * D_DIM + col0 + c4 * 4]) = o;
  }
}

// ======== 4-phase dbuf GEMM (R9-proven): C = A[M][K] * Bt[N][K]^T ========
// Tile 128x256, BK=64 (2 K-subs), 8 waves (2M x 4N), wave tile 64x64.
// Counted vmcnt {3,5,4} steady / {3,2,0} tail (in-order retirement proof).
// MODE 0: scatter Q,K bf16 into [b,h,s,hd]; V written DIRECTLY into
// Vt[b,h,d,s]. MODE 1: f32 row-major with phase factor.
template <int MODE>
__device__ __forceinline__ void gemm_body(const u16* __restrict__ A,
                                          const u16* __restrict__ Bt,
                                          void* __restrict__ outp,
                                          u16* __restrict__ Vt,
                                          const float* __restrict__ fac,
                                          char* lds) {
  constexpr int BUFSZ = 49152;  // A 2x8KB + B 2x16KB
  const int m0 = blockIdx.y * 128, n0 = blockIdx.x * 256;
  const int t = threadIdx.x;
  const int w = t >> 6, l = t & 63;
  const int wr = (w >> 2) * 64, wc = (w & 3) * 64;
  const int lr = l & 15, lq = l >> 4;
  const char* Ab = (const char*)A;
  const char* Bb = (const char*)Bt;

  f32x4 acc[4][4] = {};

  const int sub = w >> 2, ww = w & 3;
  const int abase = (ww & 1) * 16 + (ww >> 1) * 64;
  const int bbase = (w >> 1) * 64 + (w & 1) * 16;
  const int rr = l >> 2, sl = l & 3;

  auto stageA = [&](int tt, int nb, int mh) {
    const int base = abase + mh * 32;
    const int row = base + rr;
    async16(lds + nb * BUFSZ + sub * 8192 + base * 64,
            Ab + (size_t)(m0 + row) * 4096 + tt * 128 + sub * 64 +
                ((sl ^ ((row >> 1) & 3)) * 16));
  };
  auto stageB = [&](int tt, int nb, int nh) {
    const int base = bbase + nh * 32;
    const int row = base + rr;
#pragma unroll
    for (int j = 0; j < 2; j++)
      async16(lds + nb * BUFSZ + 16384 + j * 16384 + base * 64,
              Bb + (size_t)(n0 + row) * 4096 + tt * 128 + j * 64 +
                  ((sl ^ ((row >> 1) & 3)) * 16));
  };

  auto readA = [&](short8 af[2][2], int buf, int mh) {
#pragma unroll
    for (int mi = 0; mi < 2; mi++)
#pragma unroll
      for (int ks = 0; ks < 2; ks++) {
        const int row = wr + mh * 32 + mi * 16 + lr;
        af[mi][ks] = *reinterpret_cast<const short8*>(
            lds + buf * BUFSZ + ks * 8192 + row * 64 +
            ((lq ^ ((row >> 1) & 3)) * 16));
      }
  };
  auto readB = [&](short8 bf[2][2], int buf, int nh) {
#pragma unroll
    for (int ni = 0; ni < 2; ni++)
#pragma unroll
      for (int ks = 0; ks < 2; ks++) {
        const int row = wc + nh * 32 + ni * 16 + lr;
        bf[ni][ks] = *reinterpret_cast<const short8*>(
            lds + buf * BUFSZ + 16384 + ks * 16384 + row * 64 +
            ((lq ^ ((row >> 1) & 3)) * 16));
      }
  };

#define QUAD(AF, BF, MH, NH)                                                \
  {                                                                         \
    __builtin_amdgcn_s_setprio(1);                                          \
    _Pragma("unroll") for (int mi = 0; mi < 2; mi++)                        \
    _Pragma("unroll") for (int ni = 0; ni < 2; ni++)                        \
    _Pragma("unroll") for (int ks = 0; ks < 2; ks++)                        \
      acc[(MH)*2 + mi][(NH)*2 + ni] =                                       \
          MFMA(AF[mi][ks], BF[ni][ks], acc[(MH)*2 + mi][(NH)*2 + ni]);      \
    __builtin_amdgcn_s_setprio(0);                                          \
  }
#define VMW(N) asm volatile("s_waitcnt vmcnt(" #N ")" ::: "memory")
#define BAR()                         \
  do {                                \
    __builtin_amdgcn_s_barrier();     \
    asm volatile("" ::: "memory");    \
  } while (0)

  // prologue: u0, u1, u2 of tile 0 -> buf 0 (6 loads)
  stageA(0, 0, 0); stageB(0, 0, 0);
  stageA(0, 0, 1);
  stageB(0, 0, 1);

  short8 af0[2][2], af1[2][2], bfr[2][2];
  const int NT = D_DIM / 64;  // 32
  for (int tt = 0; tt < NT; tt++) {
    const int buf = tt & 1, nb = buf ^ 1;
    const bool pf = (tt + 1 < NT);
    // phase 0: (0,0); needs u0(t); stage u0(t+1)
    VMW(3); BAR();
    if (pf) { stageA(tt + 1, nb, 0); stageB(tt + 1, nb, 0); }
    readA(af0, buf, 0); readB(bfr, buf, 0);
    QUAD(af0, bfr, 0, 0);
    // phase 1: (1,0); needs u1(t); stage u1(t+1)
    if (pf) VMW(5); else VMW(2);
    BAR();
    if (pf) stageA(tt + 1, nb, 1);
    readA(af1, buf, 1);
    QUAD(af1, bfr, 1, 0);
    // phase 2: (1,1); needs u2(t); stage u2(t+1)
    if (pf) VMW(4); else VMW(0);
    BAR();
    if (pf) stageB(tt + 1, nb, 1);
    readB(bfr, buf, 1);
    QUAD(af1, bfr, 1, 1);
    // phase 3: (0,1); pure MFMA
    BAR();
    QUAD(af0, bfr, 0, 1);
  }
#undef QUAD
#undef VMW
#undef BAR

  // epilogue
#pragma unroll
  for (int gm = 0; gm < 4; gm++) {
#pragma unroll
    for (int gn = 0; gn < 4; gn++) {
      const int row0 = m0 + wr + gm * 16 + lq * 4;
      const int col = n0 + wc + gn * 16 + lr;
      if (MODE == 0) {
        if (col >= 4096) {  // V -> Vt[b,h,d,s] direct (s-consecutive r's)
          const int d = col & 127, hh = (col >> 7) & 15;
          const int bb = row0 >> 11, s0 = row0 & 2047;
          ushort4 v4;
          v4.x = f2bf(acc[gm][gn][0]);
          v4.y = f2bf(acc[gm][gn][1]);
          v4.z = f2bf(acc[gm][gn][2]);
          v4.w = f2bf(acc[gm][gn][3]);
          *reinterpret_cast<ushort4*>(
              Vt + (((size_t)(bb * NHEAD + hh) * HDIM + d) * S_LEN + s0)) = v4;
        } else {
#pragma unroll
          for (int r = 0; r < 4; r++) {
            const int row = row0 + r;
            const int mat = col >> 11;
            const int hh = (col >> 7) & 15;
            ((u16*)outp)[(size_t)mat * 8388608 +
                         (((size_t)((row >> 11) * NHEAD + hh)) * S_LEN + (row & 2047)) * HDIM +
                         (col & 127)] = f2bf(acc[gm][gn][r]);
          }
        }
      } else {
#pragma unroll
        for (int r = 0; r < 4; r++) {
          const int row = row0 + r;
          ((float*)outp)[(size_t)row * D_DIM + col] =
              acc[gm][gn][r] * (1.0f + 0.1f * fac[row]);
        }
      }
    }
  }
}

__global__ __launch_bounds__(512, 1) void k_qkv(const u16* __restrict__ A,
                                                const u16* __restrict__ Bt,
                                                void* __restrict__ outp,
                                                u16* __restrict__ Vt) {
  __shared__ __align__(16) char lds[2 * 49152];
  gemm_body<0>(A, Bt, outp, Vt, nullptr, lds);
}

__global__ __launch_bounds__(512, 1) void k_oproj(const u16* __restrict__ A,
                                                  const u16* __restrict__ Bt,
                                                  void* __restrict__ outp,
                                                  const float* __restrict__ fac) {
  __shared__ __align__(16) char lds[2 * 49152];
  gemm_body<1>(A, Bt, outp, nullptr, fac, lds);
}

// -------- phase projections pq/pk = xb @ Wpq / xb @ Wpk --------
__global__ __launch_bounds__(256) void k_phase_proj(const u16* __restrict__ xb,
                                                    const float* __restrict__ Wpq,
                                                    const float* __restrict__ Wpk,
                                                    float* __restrict__ pq,
                                                    float* __restrict__ pk) {
  __shared__ u16 xs[16][136];
  __shared__ float2 ws[128][16];
  const int t = threadIdx.x;
  const int m0 = blockIdx.x * 16;
  const int h = t & 15, r = t >> 4;
  float sq = 0.f, sk = 0.f;
  for (int kc = 0; kc < D_DIM; kc += 128) {
    *reinterpret_cast<short8*>(&xs[t >> 4][(t & 15) * 8]) =
        *reinterpret_cast<const short8*>(
            &xb[(size_t)(m0 + (t >> 4)) * D_DIM + kc + (t & 15) * 8]);
#pragma unroll
    for (int j = 0; j < 8; j++) {
      const int idx = j * 256 + t;
      const int k = idx >> 4, hh = idx & 15;
      ws[k][hh] = make_float2(Wpq[(size_t)(kc + k) * NHEAD + hh],
                              Wpk[(size_t)(kc + k) * NHEAD + hh]);
    }
    __syncthreads();
#pragma unroll
    for (int k8 = 0; k8 < 16; k8++) {
      const short8 x8 = *reinterpret_cast<const short8*>(&xs[r][k8 * 8]);
#pragma unroll
      for (int j = 0; j < 8; j++) {
        union { float f; unsigned u; } c;
        c.u = ((unsigned)(u16)x8[j]) << 16;
        const float2 wv = ws[k8 * 8 + j][h];
        sq += c.f * wv.x;
        sk += c.f * wv.y;
      }
    }
    __syncthreads();
  }
  pq[(size_t)(m0 + r) * NHEAD + h] = sq;
  pk[(size_t)(m0 + r) * NHEAD + h] = sk;
}

__device__ __forceinline__ float wave_sum(float v) {
  v += __shfl_xor(v, 1);  v += __shfl_xor(v, 2);  v += __shfl_xor(v, 4);
  v += __shfl_xor(v, 8);  v += __shfl_xor(v, 16); v += __shfl_xor(v, 32);
  return v;
}

// -------- Ck/Sk = sum_s cos/sin(pk) per (b,h) --------
__global__ void k_phase_ck(const float* __restrict__ pk, float* __restrict__ Ck,
                           float* __restrict__ Sk) {
  int bh = blockIdx.x, b = bh >> 4, h = bh & 15;
  float c = 0.f, s = 0.f;
  for (int ss = threadIdx.x; ss < S_LEN; ss += 256) {
    float v = pk[((size_t)b * S_LEN + ss) * NHEAD + h];
    c += cosf(v); s += sinf(v);
  }
  c = wave_sum(c); s = wave_sum(s);
  __shared__ float rc[4], rs[4];
  int wv = threadIdx.x >> 6;
  if ((threadIdx.x & 63) == 0) { rc[wv] = c; rs[wv] = s; }
  __syncthreads();
  if (threadIdx.x == 0) {
    Ck[bh] = rc[0] + rc[1] + rc[2] + rc[3];
    Sk[bh] = rs[0] + rs[1] + rs[2] + rs[3];
  }
}

// -------- phase_mod[m] --------
__global__ void k_phase_mod(const float* __restrict__ pq, const float* __restrict__ Ck,
                            const float* __restrict__ Sk, float* __restrict__ pm) {
  int m = blockIdx.x * 256 + threadIdx.x;
  int b = m >> 11;
  float a = 0.f;
#pragma unroll
  for (int h = 0; h < NHEAD; h++) {
    float v = pq[(size_t)m * NHEAD + h];
    a += cosf(v) * Ck[b * NHEAD + h] + sinf(v) * Sk[b * NHEAD + h];
  }
  pm[m] = a * (1.0f / (S_LEN * NHEAD));
}

// -------- causal flash attention: R5-proven serial-staged loop --------
// 512 blocks (32x16), pairing g = gy<8 ? 15-gy : gy-8 (per-CU work uniform),
// 4 warps x 32 q-rows, 2 blocks/CU. Single 32KB K/V buffer; per tile:
// stage -> __syncthreads (implicit vmcnt drain) -> compute -> __syncthreads.
// exp2-domain softmax, T13 defer-max (band 11.0 log2), interior fast path.
__global__ __launch_bounds__(256, 2) void k_attn(const u16* __restrict__ Q,
                                                 const u16* __restrict__ K,
                                                 const u16* __restrict__ Vt,
                                                 u16* __restrict__ ctx) {
  const int bh = blockIdx.x;
  const int gy = blockIdx.y;
  const int g = (gy < 8) ? (15 - gy) : (gy - 8);
  const int b = bh >> 4, h = bh & 15;
  const int t = threadIdx.x;
  const int w = t >> 6, l = t & 63;
  const int ln = l & 31, hi = l >> 5;
  const int q0w = g * 128 + w * 32;
  const int qq = q0w + ln;
  const float sc2 = 0.08838834764831845f * 1.4426950408889634f;  // scale*log2e

  const u16* Qp = Q + (size_t)bh * S_LEN * HDIM;
  const char* Kg = (const char*)(K + (size_t)bh * S_LEN * HDIM);
  const char* Vg = (const char*)(Vt + (size_t)bh * HDIM * S_LEN);

  __shared__ __align__(16) char Ks[16384];
  __shared__ __align__(16) char Vs[16384];

  auto stage = [&](int t64) {
    const int k0 = t64 * 64;
#pragma unroll
    for (int i = 0; i < 4; i++) {
      const int key = i * 16 + w * 4 + (l >> 4);
      async16(Ks + i * 4096 + w * 1024,
              Kg + (size_t)(k0 + key) * 256 + (((l & 15) * 16) ^ ((key & 15) << 4)));
      const int d = i * 32 + w * 8 + (l >> 3);
      async16(Vs + i * 4096 + w * 1024,
              Vg + (size_t)d * (S_LEN * 2) + k0 * 2 + (((l & 7) * 16) ^ ((d & 7) << 4)));
    }
  };

  short8 qf[8];
#pragma unroll
  for (int c = 0; c < 8; c++)
    qf[c] = *reinterpret_cast<const short8*>(Qp + (size_t)qq * HDIM + c * 16 + hi * 8);

  f32x16 o[4];
#pragma unroll
  for (int ds = 0; ds < 4; ds++)
#pragma unroll
    for (int r = 0; r < 16; r++) o[ds][r] = 0.f;
  float mrun = -1e30f, lsum = 0.f;

  const int nt = (g + 1) * 2;
  for (int t64 = 0; t64 < nt; t64++) {
    const int k0 = t64 * 64;
    stage(t64);
    __syncthreads();  // compiler-inserted vmcnt(0) drains DMA
    if (k0 < q0w + 32) {
      f32x16 s[2];
#pragma unroll
      for (int ks = 0; ks < 2; ks++)
#pragma unroll
        for (int r = 0; r < 16; r++) s[ks][r] = 0.f;
      __builtin_amdgcn_s_setprio(1);
#pragma unroll
      for (int ks = 0; ks < 2; ks++) {
        const int key = ks * 32 + ln;
        const char* kb = Ks + key * 256;
        const unsigned swzk = (unsigned)((key & 15) << 4);
#pragma unroll
        for (int c = 0; c < 8; c++) {
          const short8 kf = *reinterpret_cast<const short8*>(
              kb + (((unsigned)(c * 32 + hi * 16)) ^ swzk));
          s[ks] = MFMA32(kf, qf[c], s[ks]);
        }
      }
      __builtin_amdgcn_s_setprio(0);
      float p[32];
      float mx = -1e30f;
      const bool interior = (k0 + 64 <= q0w + 1);
      if (interior) {
#pragma unroll
        for (int ks = 0; ks < 2; ks++)
#pragma unroll
          for (int r = 0; r < 16; r++) {
            const float v = s[ks][r] * sc2;
            p[ks * 16 + r] = v;
            mx = fmaxf(mx, v);
          }
      } else {
#pragma unroll
        for (int ks = 0; ks < 2; ks++)
#pragma unroll
          for (int r = 0; r < 16; r++) {
            const int key = k0 + ks * 32 + (r & 3) + 8 * (r >> 2) + 4 * hi;
            const float v = (key <= qq) ? s[ks][r] * sc2 : -1e30f;
            p[ks * 16 + r] = v;
            mx = fmaxf(mx, v);
          }
      }
      mx = fmaxf(mx, __shfl_xor(mx, 32));
      if (!__all(mx <= mrun + 11.0f)) {
        const float nm = fmaxf(mrun, mx);
        const float f = exp2f(mrun - nm);
        lsum *= f;
#pragma unroll
        for (int ds = 0; ds < 4; ds++)
#pragma unroll
          for (int r = 0; r < 16; r++) o[ds][r] *= f;
        mrun = nm;
      }
      float rs = 0.f;
#pragma unroll
      for (int i = 0; i < 32; i++) { p[i] = exp2f(p[i] - mrun); rs += p[i]; }
      rs += __shfl_xor(rs, 32);
      lsum += rs;
      short8 bfr[4];
#pragma unroll
      for (int sub = 0; sub < 2; sub++) {
#pragma unroll
        for (int half = 0; half < 2; half++) {
          const int pb = sub * 16 + half * 8;
          unsigned X1 = cvtpk(p[pb + 0], p[pb + 1]);
          unsigned X2 = cvtpk(p[pb + 2], p[pb + 3]);
          unsigned Y1 = cvtpk(p[pb + 4], p[pb + 5]);
          unsigned Y2 = cvtpk(p[pb + 6], p[pb + 7]);
          plswap(X1, Y1);
          plswap(X2, Y2);
          i32x4 bw;
          bw[0] = (int)X1; bw[1] = (int)X2; bw[2] = (int)Y1; bw[3] = (int)Y2;
          bfr[sub * 2 + half] = __builtin_bit_cast(short8, bw);
        }
      }
      __builtin_amdgcn_s_setprio(1);
#pragma unroll
      for (int ds = 0; ds < 4; ds++) {
        const int d = ds * 32 + ln;
        const char* vb = Vs + d * 128;
        const unsigned swzv = (unsigned)((d & 7) << 4);
#pragma unroll
        for (int slot = 0; slot < 4; slot++) {
          const short8 vf = *reinterpret_cast<const short8*>(
              vb + (((unsigned)(slot * 32 + hi * 16)) ^ swzv));
          o[ds] = MFMA32(vf, bfr[slot], o[ds]);
        }
      }
      __builtin_amdgcn_s_setprio(0);
    }
    __syncthreads();  // protect LDS before next stage
  }

  const float rl = 1.0f / lsum;
#pragma unroll
  for (int ds = 0; ds < 4; ds++) {
#pragma unroll
    for (int rq = 0; rq < 4; rq++) {
      const int d = ds * 32 + 8 * rq + 4 * hi;
      ushort4 pk4;
      pk4.x = f2bf(o[ds][rq * 4 + 0] * rl);
      pk4.y = f2bf(o[ds][rq * 4 + 1] * rl);
      pk4.z = f2bf(o[ds][rq * 4 + 2] * rl);
      pk4.w = f2bf(o[ds][rq * 4 + 3] * rl);
      *reinterpret_cast<ushort4*>(ctx + ((size_t)(b * S_LEN + qq)) * D_DIM + h * HDIM + d) = pk4;
    }
  }
}

extern "C" void kernel_launch(void* const* d_in, const int* in_sizes, int n_in,
                              void* d_out, int out_size, void* d_ws, size_t ws_size,
                              hipStream_t stream) {
  const float* x   = (const float*)d_in[0];
  const float* Wq  = (const float*)d_in[1];
  const float* Wk  = (const float*)d_in[2];
  const float* Wv  = (const float*)d_in[3];
  const float* Wo  = (const float*)d_in[4];
  const float* Wpq = (const float*)d_in[5];
  const float* Wpk = (const float*)d_in[6];

  char* ws = (char*)d_ws;
  u16* xb   = (u16*)(ws + 0);            // 16 MB  x bf16 [4096][2048]
  u16* Wqt  = (u16*)(ws + 16777216);     // 8 MB each, transposed bf16 (Wq,Wk,Wv contiguous)
  u16* Wkt  = (u16*)(ws + 25165824);
  u16* Wvt  = (u16*)(ws + 33554432);
  u16* Wot  = (u16*)(ws + 41943040);
  u16* Qb   = (u16*)(ws + 50331648);     // [b,h,s,d] bf16 (Q,K contiguous)
  u16* Kb   = (u16*)(ws + 67108864);
  u16* Vb   = (u16*)(ws + 83886080);     // ctx buffer
  u16* Vt   = (u16*)(ws + 100663296);    // [b,h,d,s] bf16 (written by k_qkv)
  float* pq = (float*)(ws + 117440512);
  float* pk = (float*)(ws + 117702656);
  float* Ck = (float*)(ws + 117964800);
  float* Sk = (float*)(ws + 117964928);
  float* pm = (float*)(ws + 117965056);

  // fused prep: 4 weight transposes + x convert in one launch
  k_prep<<<dim3(64, 64, 6), 256, 0, stream>>>(Wq, Wk, Wv, Wo, Wqt, Wkt, Wvt, Wot, x, xb);

  // fused QKV: Bt = [Wqt;Wkt;Wvt] = [6144][2048], 128x256 tiles
  // grid 24x32 = 768 blocks -> 3 clean rounds; V written straight to Vt
  k_qkv<<<dim3(24, 32), 512, 0, stream>>>(xb, Wqt, Qb, Vt);

  k_phase_proj<<<dim3(256), 256, 0, stream>>>(xb, Wpq, Wpk, pq, pk);
  k_phase_ck<<<dim3(32), 256, 0, stream>>>(pk, Ck, Sk);
  k_phase_mod<<<dim3(16), 256, 0, stream>>>(pq, Ck, Sk, pm);

  // attention: 512 blocks, per-CU-paired uniform work, serial-staged loop
  k_attn<<<dim3(32, 16), 256, 0, stream>>>(Qb, Kb, Vt, Vb /*ctx*/);

  // O-proj: 128x256 tiles -> grid 8x32 = 256 blocks, one full round
  k_oproj<<<dim3(8, 32), 512, 0, stream>>>(Vb /*ctx*/, Wot, (void*)d_out, pm);
}